// Round 1
// baseline (5097.127 us; speedup 1.0000x reference)
//
#include <hip/hip_runtime.h>
#include <hip/hip_bf16.h>
#include <cmath>

namespace {

constexpr int kL      = 4;
constexpr int kDModel = 768;
constexpr int kDInner = 1536;
constexpr int kDtRank = 48;
constexpr int kDState = 16;
constexpr int kDConv  = 4;
constexpr int kSeq    = 1024;
constexpr int kProj   = kDtRank + 2 * kDState;  // 80

__device__ __forceinline__ float silu_f(float v) {
    return v / (1.f + __expf(-v));
}

// ---------------------------------------------------------------- embedding
__global__ void __launch_bounds__(256) embed_kernel(
    const int* __restrict__ tokens, const float* __restrict__ emb,
    float* __restrict__ x) {
    const int s = blockIdx.x;
    const int t = tokens[s];
    const float* src = emb + (size_t)t * kDModel;
    float* dst = x + (size_t)s * kDModel;
    for (int d = threadIdx.x; d < kDModel; d += blockDim.x) dst[d] = src[d];
}

// ---------------------------------------------------------------- rmsnorm
__global__ void __launch_bounds__(256) rmsnorm_kernel(
    const float* __restrict__ x, const float* __restrict__ w,
    float* __restrict__ out) {
    const int s = blockIdx.x;
    const float* row = x + (size_t)s * kDModel;
    float ss = 0.f;
    for (int d = threadIdx.x; d < kDModel; d += blockDim.x) {
        float v = row[d];
        ss = fmaf(v, v, ss);
    }
    #pragma unroll
    for (int m = 32; m; m >>= 1) ss += __shfl_xor(ss, m);
    __shared__ float red[4];
    if ((threadIdx.x & 63) == 0) red[threadIdx.x >> 6] = ss;
    __syncthreads();
    const float total = red[0] + red[1] + red[2] + red[3];
    const float scale = rsqrtf(total / (float)kDModel + 1e-5f);
    float* dst = out + (size_t)s * kDModel;
    for (int d = threadIdx.x; d < kDModel; d += blockDim.x)
        dst[d] = row[d] * scale * w[d];
}

// ---------------------------------------------------------------- GEMM
// C[m][n] = epi( sum_k A[m][k] * B[n][k] )   (A: M x K lda, B: N x K ldb)
// EPI 0: C = acc    EPI 1: C = softplus(acc + bias[n])    EPI 2: C += acc
template <int EPI>
__global__ void __launch_bounds__(256) gemm_kernel(
    const float* __restrict__ A, int lda,
    const float* __restrict__ B, int ldb,
    float* __restrict__ C, int ldc,
    int M, int N, int K, const float* __restrict__ bias) {
    constexpr int BM = 64, BN = 64, BK = 16, PAD = 4;
    __shared__ float As[BK][BM + PAD];
    __shared__ float Bs[BK][BN + PAD];
    const int tid = threadIdx.x;
    const int tx = tid & 15, ty = tid >> 4;
    const int m0 = blockIdx.y * BM, n0 = blockIdx.x * BN;
    float acc[4][4] = {};
    for (int k0 = 0; k0 < K; k0 += BK) {
        #pragma unroll
        for (int i = 0; i < 4; ++i) {
            const int idx = tid + i * 256;
            const int r = idx >> 4, kk = idx & 15;
            const int gk = k0 + kk;
            const int gm = m0 + r;
            As[kk][r] = (gm < M && gk < K) ? A[(size_t)gm * lda + gk] : 0.f;
            const int gn = n0 + r;
            Bs[kk][r] = (gn < N && gk < K) ? B[(size_t)gn * ldb + gk] : 0.f;
        }
        __syncthreads();
        #pragma unroll
        for (int kk = 0; kk < BK; ++kk) {
            const float4 a4 = *reinterpret_cast<const float4*>(&As[kk][ty * 4]);
            const float4 b4 = *reinterpret_cast<const float4*>(&Bs[kk][tx * 4]);
            const float av[4] = {a4.x, a4.y, a4.z, a4.w};
            const float bv[4] = {b4.x, b4.y, b4.z, b4.w};
            #pragma unroll
            for (int i2 = 0; i2 < 4; ++i2)
                #pragma unroll
                for (int j2 = 0; j2 < 4; ++j2)
                    acc[i2][j2] = fmaf(av[i2], bv[j2], acc[i2][j2]);
        }
        __syncthreads();
    }
    #pragma unroll
    for (int i2 = 0; i2 < 4; ++i2) {
        const int m = m0 + ty * 4 + i2;
        if (m >= M) continue;
        #pragma unroll
        for (int j2 = 0; j2 < 4; ++j2) {
            const int n = n0 + tx * 4 + j2;
            if (n >= N) continue;
            float v = acc[i2][j2];
            if (EPI == 1) {
                v += bias[n];
                v = (v > 20.f) ? v : log1pf(__expf(v));  // softplus
            }
            const size_t off = (size_t)m * ldc + n;
            if (EPI == 2) C[off] += v;
            else          C[off] = v;
        }
    }
}

// ------------------------------------------------- depthwise causal conv+silu
__global__ void __launch_bounds__(256) conv_silu_kernel(
    const float* __restrict__ xz, const float* __restrict__ cw,
    const float* __restrict__ cb, float* __restrict__ xi) {
    const int s = blockIdx.x;
    const int d = blockIdx.y * 256 + threadIdx.x;
    float acc = cb[d];
    #pragma unroll
    for (int k = 0; k < kDConv; ++k) {
        const int sl = s - (kDConv - 1) + k;
        if (sl >= 0)
            acc = fmaf(xz[(size_t)sl * (2 * kDInner) + d], cw[d * kDConv + k], acc);
    }
    xi[(size_t)s * kDInner + d] = silu_f(acc);
}

// ---------------------------------------------------------------- scan
// y[l,d] = sum_n state[l,d,n]*C[l,n] + u[l,d]*Dv[d]
// state = state * exp(exp(dt*A)) + dt*u*B   (exact refactor of the reference
// cumsum/exp formulation; the +1e-12 is < fp32 eps relative since exp(S)>=1)
__global__ void __launch_bounds__(256) scan_kernel(
    const float* __restrict__ dt, const float* __restrict__ u,
    const float* __restrict__ proj, const float* __restrict__ A_log,
    const float* __restrict__ D_skip, float* __restrict__ y) {
    const int n  = threadIdx.x & 15;
    const int dl = threadIdx.x >> 4;
    const int d  = blockIdx.x * 16 + dl;
    const float Adn = -__expf(A_log[d * kDState + n]);
    const float Dv  = D_skip[d];
    float state = 0.f;
    for (int l = 0; l < kSeq; ++l) {
        const float dtv = dt[(size_t)l * kDInner + d];
        const float uv  = u[(size_t)l * kDInner + d];
        const float Bv  = proj[(size_t)l * kProj + kDtRank + n];
        const float Cv  = proj[(size_t)l * kProj + kDtRank + kDState + n];
        const float adelta = __expf(dtv * Adn);   // = exp(dt*A), in (0,1]
        const float mult   = __expf(adelta);      // reference's exp(cumsum) step
        state = fmaf(state, mult, dtv * uv * Bv);
        float contrib = state * Cv;
        contrib += __shfl_xor(contrib, 8);
        contrib += __shfl_xor(contrib, 4);
        contrib += __shfl_xor(contrib, 2);
        contrib += __shfl_xor(contrib, 1);
        if (n == 0) y[(size_t)l * kDInner + d] = fmaf(uv, Dv, contrib);
    }
}

// ---------------------------------------------------------------- y * silu(res)
__global__ void __launch_bounds__(256) mul_silu_kernel(
    const float* __restrict__ y, const float* __restrict__ xz,
    float* __restrict__ g) {
    const int s = blockIdx.x;
    const int d = blockIdx.y * 256 + threadIdx.x;
    const float res = xz[(size_t)s * (2 * kDInner) + kDInner + d];
    g[(size_t)s * kDInner + d] = y[(size_t)s * kDInner + d] * silu_f(res);
}

}  // namespace

extern "C" void kernel_launch(void* const* d_in, const int* in_sizes, int n_in,
                              void* d_out, int out_size, void* d_ws, size_t ws_size,
                              hipStream_t stream) {
    const int*   tokens       = (const int*)d_in[0];
    const float* embedding    = (const float*)d_in[1];
    const float* norm_w       = (const float*)d_in[2];
    const float* in_proj_w    = (const float*)d_in[3];
    const float* conv_w       = (const float*)d_in[4];
    const float* conv_b       = (const float*)d_in[5];
    const float* x_proj_w     = (const float*)d_in[6];
    const float* dt_proj_w    = (const float*)d_in[7];
    const float* dt_proj_b    = (const float*)d_in[8];
    const float* A_log        = (const float*)d_in[9];
    const float* D_skip       = (const float*)d_in[10];
    const float* out_proj_w   = (const float*)d_in[11];
    const float* final_norm_w = (const float*)d_in[12];
    float* out = (float*)d_out;

    char* ws = (char*)d_ws;
    float* x    = (float*)ws;  ws += (size_t)kSeq * kDModel * 4;
    float* h    = (float*)ws;  ws += (size_t)kSeq * kDModel * 4;
    float* xz   = (float*)ws;  ws += (size_t)kSeq * 2 * kDInner * 4;
    float* xi   = (float*)ws;  ws += (size_t)kSeq * kDInner * 4;
    float* proj = (float*)ws;  ws += (size_t)kSeq * kProj * 4;
    float* dt   = (float*)ws;  ws += (size_t)kSeq * kDInner * 4;
    float* y    = (float*)ws;  ws += (size_t)kSeq * kDInner * 4;
    float* g    = (float*)ws;  ws += (size_t)kSeq * kDInner * 4;

    embed_kernel<<<kSeq, 256, 0, stream>>>(tokens, embedding, x);

    for (int i = 0; i < kL; ++i) {
        rmsnorm_kernel<<<kSeq, 256, 0, stream>>>(x, norm_w + (size_t)i * kDModel, h);

        // xz = h @ in_proj_w[i]^T   (1024 x 3072, K=768)
        gemm_kernel<0><<<dim3(2 * kDInner / 64, kSeq / 64), 256, 0, stream>>>(
            h, kDModel, in_proj_w + (size_t)i * 2 * kDInner * kDModel, kDModel,
            xz, 2 * kDInner, kSeq, 2 * kDInner, kDModel, nullptr);

        // xi = silu(conv(xz[:, :1536]) + b)
        conv_silu_kernel<<<dim3(kSeq, kDInner / 256), 256, 0, stream>>>(
            xz, conv_w + (size_t)i * kDInner * kDConv, conv_b + (size_t)i * kDInner, xi);

        // proj = xi @ x_proj_w[i]^T   (1024 x 80, K=1536)
        gemm_kernel<0><<<dim3((kProj + 63) / 64, kSeq / 64), 256, 0, stream>>>(
            xi, kDInner, x_proj_w + (size_t)i * kProj * kDInner, kDInner,
            proj, kProj, kSeq, kProj, kDInner, nullptr);

        // dt = softplus(proj[:, :48] @ dt_proj_w[i]^T + dt_proj_b[i])  (1024 x 1536, K=48)
        gemm_kernel<1><<<dim3(kDInner / 64, kSeq / 64), 256, 0, stream>>>(
            proj, kProj, dt_proj_w + (size_t)i * kDInner * kDtRank, kDtRank,
            dt, kDInner, kSeq, kDInner, kDtRank, dt_proj_b + (size_t)i * kDInner);

        // y = selective_scan(xi, dt, A, B, C, D)
        scan_kernel<<<kDInner / 16, 256, 0, stream>>>(
            dt, xi, proj, A_log + (size_t)i * kDInner * kDState,
            D_skip + (size_t)i * kDInner, y);

        // g = y * silu(res)
        mul_silu_kernel<<<dim3(kSeq, kDInner / 256), 256, 0, stream>>>(y, xz, g);

        // x += g @ out_proj_w[i]^T   (1024 x 768, K=1536)
        gemm_kernel<2><<<dim3(kDModel / 64, kSeq / 64), 256, 0, stream>>>(
            g, kDInner, out_proj_w + (size_t)i * kDModel * kDInner, kDInner,
            x, kDModel, kSeq, kDModel, kDInner, nullptr);
    }

    // out = rmsnorm(x, final_norm_w) @ embedding^T   (1024 x 32000, K=768)
    rmsnorm_kernel<<<kSeq, 256, 0, stream>>>(x, final_norm_w, h);
    gemm_kernel<0><<<dim3(32000 / 64, kSeq / 64), 256, 0, stream>>>(
        h, kDModel, embedding, kDModel, out, 32000, kSeq, 32000, kDModel, nullptr);
}

// Round 3
// 3382.365 us; speedup vs baseline: 1.5070x; 1.5070x over previous
//
#include <hip/hip_runtime.h>
#include <hip/hip_bf16.h>
#include <cmath>

namespace {

constexpr int kL      = 4;
constexpr int kDModel = 768;
constexpr int kDInner = 1536;
constexpr int kDtRank = 48;
constexpr int kDState = 16;
constexpr int kDConv  = 4;
constexpr int kSeq    = 1024;
constexpr int kProj   = kDtRank + 2 * kDState;  // 80
constexpr int kVocab  = 32000;

using short8 = __attribute__((ext_vector_type(8))) short;
using f32x4  = __attribute__((ext_vector_type(4))) float;

__device__ __forceinline__ float silu_f(float v) {
    return v / (1.f + __expf(-v));
}

__device__ __forceinline__ void split_bf16(float v, __hip_bfloat16& hi, __hip_bfloat16& lo) {
    hi = __float2bfloat16(v);
    lo = __float2bfloat16(v - __bfloat162float(hi));
}

// ---------------------------------------------------------------- fp32->bf16
__global__ void __launch_bounds__(256) f2b_kernel(
    const float* __restrict__ src, __hip_bfloat16* __restrict__ dst, int n) {
    int i = (blockIdx.x * 256 + threadIdx.x) * 4;
    const int stride = gridDim.x * 256 * 4;
    for (; i + 3 < n; i += stride) {
        const float4 v = *reinterpret_cast<const float4*>(src + i);
        dst[i + 0] = __float2bfloat16(v.x);
        dst[i + 1] = __float2bfloat16(v.y);
        dst[i + 2] = __float2bfloat16(v.z);
        dst[i + 3] = __float2bfloat16(v.w);
    }
}

// -------------------------------- fp32 -> 3-term split bf16 along K
// MODE 0 (A-side): dst row = [hi | lo | hi]   MODE 1 (B-side): [hi | hi | lo]
// dst is rowsPad x 3*cols; rows >= rowsPad are zero-filled.
template <int MODE>
__global__ void __launch_bounds__(256) split3_kernel(
    const float* __restrict__ src, int ldsrc, int rows, int cols,
    __hip_bfloat16* __restrict__ dst, int rowsPad) {
    const int idx = blockIdx.x * 256 + threadIdx.x;
    if (idx >= rowsPad * cols) return;
    const int r = idx / cols, c = idx % cols;
    const float v = (r < rows) ? src[(size_t)r * ldsrc + c] : 0.f;
    __hip_bfloat16 hi, lo;
    split_bf16(v, hi, lo);
    __hip_bfloat16* row = dst + (size_t)r * 3 * cols;
    if (MODE == 0) { row[c] = hi; row[cols + c] = lo; row[2 * cols + c] = hi; }
    else           { row[c] = hi; row[cols + c] = hi; row[2 * cols + c] = lo; }
}

// ------------------------------------------- fp32->bf16 with 2D zero-padding
__global__ void __launch_bounds__(256) pad_b_kernel(
    const float* __restrict__ src, int ldsrc, int rows, int cols,
    __hip_bfloat16* __restrict__ dst, int lddst, int rowsPad) {
    const int idx = blockIdx.x * 256 + threadIdx.x;
    if (idx >= rowsPad * lddst) return;
    const int r = idx / lddst, c = idx % lddst;
    const float v = (r < rows && c < cols) ? src[(size_t)r * ldsrc + c] : 0.f;
    dst[idx] = __float2bfloat16(v);
}

// ---------------------------------------------------------------- embedding
__global__ void __launch_bounds__(256) embed_kernel(
    const int* __restrict__ tokens, const float* __restrict__ emb,
    float* __restrict__ x) {
    const int s = blockIdx.x;
    const int t = tokens[s];
    const float* src = emb + (size_t)t * kDModel;
    float* dst = x + (size_t)s * kDModel;
    for (int d = threadIdx.x; d < kDModel; d += blockDim.x) dst[d] = src[d];
}

// ----------------------------------- rmsnorm -> bf16 (plain or 3-term split)
template <bool SPLIT>
__global__ void __launch_bounds__(256) rmsnorm_kernel(
    const float* __restrict__ x, const float* __restrict__ w,
    __hip_bfloat16* __restrict__ out) {
    const int s = blockIdx.x;
    const float* row = x + (size_t)s * kDModel;
    float ss = 0.f;
    for (int d = threadIdx.x; d < kDModel; d += blockDim.x) {
        const float v = row[d];
        ss = fmaf(v, v, ss);
    }
    #pragma unroll
    for (int m = 32; m; m >>= 1) ss += __shfl_xor(ss, m);
    __shared__ float red[4];
    if ((threadIdx.x & 63) == 0) red[threadIdx.x >> 6] = ss;
    __syncthreads();
    const float total = red[0] + red[1] + red[2] + red[3];
    const float scale = rsqrtf(total / (float)kDModel + 1e-5f);
    __hip_bfloat16* dst = out + (size_t)s * (SPLIT ? 3 * kDModel : kDModel);
    for (int d = threadIdx.x; d < kDModel; d += blockDim.x) {
        const float v = row[d] * scale * w[d];
        if (SPLIT) {
            __hip_bfloat16 hi, lo;
            split_bf16(v, hi, lo);
            dst[d] = hi; dst[kDModel + d] = lo; dst[2 * kDModel + d] = hi;
        } else {
            dst[d] = __float2bfloat16(v);
        }
    }
}

// ---------------------------------------------------------------- MFMA GEMM
// C[m][n] = epi( sum_k A[m][k] * B[n][k] ), A: M x K bf16, B: N x K bf16.
// EPI 0: C = acc   EPI 1: C = softplus(acc + bias[n])   EPI 2: C += acc
template <int BM, int BN, int EPI>
__global__ void __launch_bounds__(256) mfma_gemm(
    const __hip_bfloat16* __restrict__ A, int lda,
    const __hip_bfloat16* __restrict__ B, int ldb,
    float* __restrict__ C, int ldc,
    int N, int K, const float* __restrict__ bias) {
    constexpr int BK = 32;
    __shared__ unsigned short As[BM * BK];
    __shared__ unsigned short Bs[BN * BK];
    const int tid  = threadIdx.x;
    const int lane = tid & 63;
    const int m0 = blockIdx.y * BM, n0 = blockIdx.x * BN;
    constexpr int WM = BM / 2, WN = BN / 2;   // 2x2 waves
    constexpr int MR = WM / 16, NR = WN / 16;
    const int wave = tid >> 6;
    const int wm = (wave >> 1) * WM, wn = (wave & 1) * WN;
    const int l15 = lane & 15, l4 = lane >> 4;
    f32x4 acc[MR][NR] = {};

    for (int k0 = 0; k0 < K; k0 += BK) {
        for (int idx = tid; idx < BM * 4; idx += 256) {
            const int r = idx >> 2, c = (idx & 3) << 3;
            __builtin_amdgcn_global_load_lds(
                (const __attribute__((address_space(1))) void*)(A + (size_t)(m0 + r) * lda + k0 + c),
                (__attribute__((address_space(3))) void*)(As + (idx - lane) * 8),
                16, 0, 0);
        }
        for (int idx = tid; idx < BN * 4; idx += 256) {
            const int r = idx >> 2, c = (idx & 3) << 3;
            __builtin_amdgcn_global_load_lds(
                (const __attribute__((address_space(1))) void*)(B + (size_t)(n0 + r) * ldb + k0 + c),
                (__attribute__((address_space(3))) void*)(Bs + (idx - lane) * 8),
                16, 0, 0);
        }
        __syncthreads();

        short8 af[MR], bfv[NR];
        #pragma unroll
        for (int mi = 0; mi < MR; ++mi)
            af[mi] = *reinterpret_cast<const short8*>(&As[(wm + mi * 16 + l15) * BK + l4 * 8]);
        #pragma unroll
        for (int ni = 0; ni < NR; ++ni)
            bfv[ni] = *reinterpret_cast<const short8*>(&Bs[(wn + ni * 16 + l15) * BK + l4 * 8]);
        #pragma unroll
        for (int mi = 0; mi < MR; ++mi)
            #pragma unroll
            for (int ni = 0; ni < NR; ++ni)
                acc[mi][ni] = __builtin_amdgcn_mfma_f32_16x16x32_bf16(
                    af[mi], bfv[ni], acc[mi][ni], 0, 0, 0);
        __syncthreads();
    }

    // C/D layout: col = lane&15, row = (lane>>4)*4 + reg  (m89/m91)
    #pragma unroll
    for (int mi = 0; mi < MR; ++mi) {
        const int mrow = m0 + wm + mi * 16 + l4 * 4;
        #pragma unroll
        for (int ni = 0; ni < NR; ++ni) {
            const int ncol = n0 + wn + ni * 16 + l15;
            if (ncol >= N) continue;
            #pragma unroll
            for (int r = 0; r < 4; ++r) {
                float v = acc[mi][ni][r];
                if (EPI == 1) {
                    v += bias[ncol];
                    v = (v > 20.f) ? v : log1pf(__expf(v));  // softplus
                }
                const size_t off = (size_t)(mrow + r) * ldc + ncol;
                if (EPI == 2) C[off] += v; else C[off] = v;
            }
        }
    }
}

// ------------------------------------------- depthwise causal conv+silu
// writes xi (fp32, for scan) and xi2 (3-term split bf16, for x_proj GEMM)
__global__ void __launch_bounds__(256) conv_silu_kernel(
    const float* __restrict__ xz, const float* __restrict__ cw,
    const float* __restrict__ cb, float* __restrict__ xi,
    __hip_bfloat16* __restrict__ xi2) {
    const int s = blockIdx.x;
    const int d = blockIdx.y * 256 + threadIdx.x;
    float acc = cb[d];
    #pragma unroll
    for (int k = 0; k < kDConv; ++k) {
        const int sl = s - (kDConv - 1) + k;
        if (sl >= 0)
            acc = fmaf(xz[(size_t)sl * (2 * kDInner) + d], cw[d * kDConv + k], acc);
    }
    const float v = silu_f(acc);
    xi[(size_t)s * kDInner + d] = v;
    __hip_bfloat16 hi, lo;
    split_bf16(v, hi, lo);
    __hip_bfloat16* row = xi2 + (size_t)s * 3 * kDInner;
    row[d] = hi; row[kDInner + d] = lo; row[2 * kDInner + d] = hi;
}

// ---------------------------------------------------------------- scan
// state = state * exp(exp(dt*A)) + dt*u*B ; y = <state,C> + u*Dv
__global__ void __launch_bounds__(256) scan_kernel(
    const float* __restrict__ dt, const float* __restrict__ u,
    const float* __restrict__ proj, const float* __restrict__ A_log,
    const float* __restrict__ D_skip, float* __restrict__ y) {
    const int n  = threadIdx.x & 15;
    const int dl = threadIdx.x >> 4;
    const int d  = blockIdx.x * 16 + dl;
    const float Adn = -__expf(A_log[d * kDState + n]);
    const float Dv  = D_skip[d];
    float state = 0.f;
    for (int l = 0; l < kSeq; ++l) {
        const float dtv = dt[(size_t)l * kDInner + d];
        const float uv  = u[(size_t)l * kDInner + d];
        const float Bv  = proj[(size_t)l * kProj + kDtRank + n];
        const float Cv  = proj[(size_t)l * kProj + kDtRank + kDState + n];
        const float adelta = __expf(dtv * Adn);
        const float mult   = __expf(adelta);
        state = fmaf(state, mult, dtv * uv * Bv);
        float contrib = state * Cv;
        contrib += __shfl_xor(contrib, 8);
        contrib += __shfl_xor(contrib, 4);
        contrib += __shfl_xor(contrib, 2);
        contrib += __shfl_xor(contrib, 1);
        if (n == 0) y[(size_t)l * kDInner + d] = fmaf(uv, Dv, contrib);
    }
}

// ----------------------------- g = y * silu(res) (3-term split bf16)
__global__ void __launch_bounds__(256) mul_silu_kernel(
    const float* __restrict__ y, const float* __restrict__ xz,
    __hip_bfloat16* __restrict__ g2) {
    const int s = blockIdx.x;
    const int d = blockIdx.y * 256 + threadIdx.x;
    const float res = xz[(size_t)s * (2 * kDInner) + kDInner + d];
    const float v = y[(size_t)s * kDInner + d] * silu_f(res);
    __hip_bfloat16 hi, lo;
    split_bf16(v, hi, lo);
    __hip_bfloat16* row = g2 + (size_t)s * 3 * kDInner;
    row[d] = hi; row[kDInner + d] = lo; row[2 * kDInner + d] = hi;
}

}  // namespace

extern "C" void kernel_launch(void* const* d_in, const int* in_sizes, int n_in,
                              void* d_out, int out_size, void* d_ws, size_t ws_size,
                              hipStream_t stream) {
    const int*   tokens       = (const int*)d_in[0];
    const float* embedding    = (const float*)d_in[1];
    const float* norm_w       = (const float*)d_in[2];
    const float* in_proj_w    = (const float*)d_in[3];
    const float* conv_w       = (const float*)d_in[4];
    const float* conv_b       = (const float*)d_in[5];
    const float* x_proj_w     = (const float*)d_in[6];
    const float* dt_proj_w    = (const float*)d_in[7];
    const float* dt_proj_b    = (const float*)d_in[8];
    const float* A_log        = (const float*)d_in[9];
    const float* D_skip       = (const float*)d_in[10];
    const float* out_proj_w   = (const float*)d_in[11];
    const float* final_norm_w = (const float*)d_in[12];
    float* out = (float*)d_out;

    constexpr int K3m = 3 * kDModel;   // 2304
    constexpr int K3i = 3 * kDInner;   // 4608

    char* ws = (char*)d_ws;
    auto alloc = [&](size_t bytes) { char* p = ws; ws += (bytes + 255) & ~(size_t)255; return p; };
    float* x    = (float*)alloc((size_t)kSeq * kDModel * 4);
    float* xz   = (float*)alloc((size_t)kSeq * 2 * kDInner * 4);
    float* xi   = (float*)alloc((size_t)kSeq * kDInner * 4);
    float* proj = (float*)alloc((size_t)kSeq * kProj * 4);
    float* dt   = (float*)alloc((size_t)kSeq * kDInner * 4);
    float* y    = (float*)alloc((size_t)kSeq * kDInner * 4);
    __hip_bfloat16* h_bf     = (__hip_bfloat16*)alloc((size_t)kSeq * kDModel * 2);     // final rmsnorm, plain
    __hip_bfloat16* h2       = (__hip_bfloat16*)alloc((size_t)kSeq * K3m * 2);
    __hip_bfloat16* xi2      = (__hip_bfloat16*)alloc((size_t)kSeq * K3i * 2);
    __hip_bfloat16* g2       = (__hip_bfloat16*)alloc((size_t)kSeq * K3i * 2);
    __hip_bfloat16* proj_pad = (__hip_bfloat16*)alloc((size_t)kSeq * 64 * 2);
    __hip_bfloat16* emb_bf   = (__hip_bfloat16*)alloc((size_t)kVocab * kDModel * 2);
    __hip_bfloat16* inw2     = (__hip_bfloat16*)alloc((size_t)kL * 2 * kDInner * K3m * 2);
    __hip_bfloat16* outw2    = (__hip_bfloat16*)alloc((size_t)kL * kDModel * K3i * 2);
    __hip_bfloat16* xw2      = (__hip_bfloat16*)alloc((size_t)kL * 96 * K3i * 2);
    __hip_bfloat16* dtw_pad  = (__hip_bfloat16*)alloc((size_t)kL * kDInner * 64 * 2);

    // ---- weight conversions (per call) ----
    {
        f2b_kernel<<<4096, 256, 0, stream>>>(embedding, emb_bf, kVocab * kDModel);
        for (int i = 0; i < kL; ++i) {
            split3_kernel<1><<<(2 * kDInner * kDModel + 255) / 256, 256, 0, stream>>>(
                in_proj_w + (size_t)i * 2 * kDInner * kDModel, kDModel,
                2 * kDInner, kDModel, inw2 + (size_t)i * 2 * kDInner * K3m, 2 * kDInner);
            split3_kernel<1><<<(kDModel * kDInner + 255) / 256, 256, 0, stream>>>(
                out_proj_w + (size_t)i * kDModel * kDInner, kDInner,
                kDModel, kDInner, outw2 + (size_t)i * kDModel * K3i, kDModel);
            split3_kernel<1><<<(96 * kDInner + 255) / 256, 256, 0, stream>>>(
                x_proj_w + (size_t)i * kProj * kDInner, kDInner,
                kProj, kDInner, xw2 + (size_t)i * 96 * K3i, 96);
            pad_b_kernel<<<(kDInner * 64 + 255) / 256, 256, 0, stream>>>(
                dt_proj_w + (size_t)i * kDInner * kDtRank, kDtRank, kDInner, kDtRank,
                dtw_pad + (size_t)i * kDInner * 64, 64, kDInner);
        }
    }

    embed_kernel<<<kSeq, 256, 0, stream>>>(tokens, embedding, x);

    for (int i = 0; i < kL; ++i) {
        rmsnorm_kernel<true><<<kSeq, 256, 0, stream>>>(x, norm_w + (size_t)i * kDModel, h2);

        // xz = h @ in_proj_w[i]^T   (1024 x 3072, K=768 -> split 2304)
        mfma_gemm<128, 128, 0><<<dim3(2 * kDInner / 128, kSeq / 128), 256, 0, stream>>>(
            h2, K3m, inw2 + (size_t)i * 2 * kDInner * K3m, K3m,
            xz, 2 * kDInner, 2 * kDInner, K3m, nullptr);

        // xi = silu(conv(xz[:, :1536]) + b)
        conv_silu_kernel<<<dim3(kSeq, kDInner / 256), 256, 0, stream>>>(
            xz, conv_w + (size_t)i * kDInner * kDConv, conv_b + (size_t)i * kDInner,
            xi, xi2);

        // proj = xi @ x_proj_w[i]^T   (1024 x 80, K=1536 -> split 4608)
        mfma_gemm<128, 96, 0><<<dim3(1, kSeq / 128), 256, 0, stream>>>(
            xi2, K3i, xw2 + (size_t)i * 96 * K3i, K3i,
            proj, kProj, kProj, K3i, nullptr);

        // proj_pad = bf16(proj[:, :48]) zero-padded to K=64
        pad_b_kernel<<<(kSeq * 64 + 255) / 256, 256, 0, stream>>>(
            proj, kProj, kSeq, kDtRank, proj_pad, 64, kSeq);

        // dt = softplus(proj[:, :48] @ dt_proj_w[i]^T + b)   (1024 x 1536, K=64)
        mfma_gemm<128, 128, 1><<<dim3(kDInner / 128, kSeq / 128), 256, 0, stream>>>(
            proj_pad, 64, dtw_pad + (size_t)i * kDInner * 64, 64,
            dt, kDInner, kDInner, 64, dt_proj_b + (size_t)i * kDInner);

        // y = selective_scan(xi, dt, A, B, C, D)
        scan_kernel<<<kDInner / 16, 256, 0, stream>>>(
            dt, xi, proj, A_log + (size_t)i * kDInner * kDState,
            D_skip + (size_t)i * kDInner, y);

        // g = y * silu(res)
        mul_silu_kernel<<<dim3(kSeq, kDInner / 256), 256, 0, stream>>>(y, xz, g2);

        // x += g @ out_proj_w[i]^T   (1024 x 768, K=1536 -> split 4608)
        mfma_gemm<128, 128, 2><<<dim3(kDModel / 128, kSeq / 128), 256, 0, stream>>>(
            g2, K3i, outw2 + (size_t)i * kDModel * K3i, K3i,
            x, kDModel, kDModel, K3i, nullptr);
    }

    // out = rmsnorm(x, final_norm_w) @ embedding^T   (1024 x 32000, K=768)
    rmsnorm_kernel<false><<<kSeq, 256, 0, stream>>>(x, final_norm_w, h_bf);
    mfma_gemm<128, 128, 0><<<dim3(kVocab / 128, kSeq / 128), 256, 0, stream>>>(
        h_bf, kDModel, emb_bf, kDModel, out, kVocab, kVocab, kDModel, nullptr);
}

// Round 4
// 1724.866 us; speedup vs baseline: 2.9551x; 1.9609x over previous
//
#include <hip/hip_runtime.h>
#include <hip/hip_bf16.h>
#include <cmath>

namespace {

constexpr int kL      = 4;
constexpr int kDModel = 768;
constexpr int kDInner = 1536;
constexpr int kDtRank = 48;
constexpr int kDState = 16;
constexpr int kDConv  = 4;
constexpr int kSeq    = 1024;
constexpr int kProj   = kDtRank + 2 * kDState;  // 80
constexpr int kVocab  = 32000;
constexpr int kCH     = 64;    // scan chunk length
constexpr int kNCH    = kSeq / kCH;  // 16 chunks
constexpr int kDN     = kDInner * kDState;  // 24576 (d,n) pairs

using short8 = __attribute__((ext_vector_type(8))) short;
using f32x4  = __attribute__((ext_vector_type(4))) float;

__device__ __forceinline__ float silu_f(float v) {
    return v / (1.f + __expf(-v));
}

__device__ __forceinline__ void split_bf16(float v, __hip_bfloat16& hi, __hip_bfloat16& lo) {
    hi = __float2bfloat16(v);
    lo = __float2bfloat16(v - __bfloat162float(hi));
}

// ---------------------------------------------------------------- fp32->bf16
__global__ void __launch_bounds__(256) f2b_kernel(
    const float* __restrict__ src, __hip_bfloat16* __restrict__ dst, int n) {
    int i = (blockIdx.x * 256 + threadIdx.x) * 4;
    const int stride = gridDim.x * 256 * 4;
    for (; i + 3 < n; i += stride) {
        const float4 v = *reinterpret_cast<const float4*>(src + i);
        dst[i + 0] = __float2bfloat16(v.x);
        dst[i + 1] = __float2bfloat16(v.y);
        dst[i + 2] = __float2bfloat16(v.z);
        dst[i + 3] = __float2bfloat16(v.w);
    }
}

// -------------------------------- fp32 -> 3-term split bf16 along K
// B-side: dst row = [hi | hi | lo]; rows >= `rows` zero-filled.
__global__ void __launch_bounds__(256) split3_kernel(
    const float* __restrict__ src, int ldsrc, int rows, int cols,
    __hip_bfloat16* __restrict__ dst, int rowsPad) {
    const int idx = blockIdx.x * 256 + threadIdx.x;
    if (idx >= rowsPad * cols) return;
    const int r = idx / cols, c = idx % cols;
    const float v = (r < rows) ? src[(size_t)r * ldsrc + c] : 0.f;
    __hip_bfloat16 hi, lo;
    split_bf16(v, hi, lo);
    __hip_bfloat16* row = dst + (size_t)r * 3 * cols;
    row[c] = hi; row[cols + c] = hi; row[2 * cols + c] = lo;
}

// ------------------------------------------- fp32->bf16 with 2D zero-padding
__global__ void __launch_bounds__(256) pad_b_kernel(
    const float* __restrict__ src, int ldsrc, int rows, int cols,
    __hip_bfloat16* __restrict__ dst, int lddst, int rowsPad) {
    const int idx = blockIdx.x * 256 + threadIdx.x;
    if (idx >= rowsPad * lddst) return;
    const int r = idx / lddst, c = idx % lddst;
    const float v = (r < rows && c < cols) ? src[(size_t)r * ldsrc + c] : 0.f;
    dst[idx] = __float2bfloat16(v);
}

// ---------------------------------------------------------------- embedding
__global__ void __launch_bounds__(256) embed_kernel(
    const int* __restrict__ tokens, const float* __restrict__ emb,
    float* __restrict__ x) {
    const int s = blockIdx.x;
    const int t = tokens[s];
    const float* src = emb + (size_t)t * kDModel;
    float* dst = x + (size_t)s * kDModel;
    for (int d = threadIdx.x; d < kDModel; d += blockDim.x) dst[d] = src[d];
}

// ----------------------------------- rmsnorm -> bf16 (plain or 3-term split)
template <bool SPLIT>
__global__ void __launch_bounds__(256) rmsnorm_kernel(
    const float* __restrict__ x, const float* __restrict__ w,
    __hip_bfloat16* __restrict__ out) {
    const int s = blockIdx.x;
    const float* row = x + (size_t)s * kDModel;
    float ss = 0.f;
    for (int d = threadIdx.x; d < kDModel; d += blockDim.x) {
        const float v = row[d];
        ss = fmaf(v, v, ss);
    }
    #pragma unroll
    for (int m = 32; m; m >>= 1) ss += __shfl_xor(ss, m);
    __shared__ float red[4];
    if ((threadIdx.x & 63) == 0) red[threadIdx.x >> 6] = ss;
    __syncthreads();
    const float total = red[0] + red[1] + red[2] + red[3];
    const float scale = rsqrtf(total / (float)kDModel + 1e-5f);
    __hip_bfloat16* dst = out + (size_t)s * (SPLIT ? 3 * kDModel : kDModel);
    for (int d = threadIdx.x; d < kDModel; d += blockDim.x) {
        const float v = row[d] * scale * w[d];
        if (SPLIT) {
            __hip_bfloat16 hi, lo;
            split_bf16(v, hi, lo);
            dst[d] = hi; dst[kDModel + d] = lo; dst[2 * kDModel + d] = hi;
        } else {
            dst[d] = __float2bfloat16(v);
        }
    }
}

// ---------------------------------------------------------------- MFMA GEMM
// C[m][n] = epi( sum_k A[m][k] * B[n][k] ), A: M x K bf16, B: N x K bf16.
// EPI 0: C = acc   EPI 1: C = softplus(acc + bias[n])   EPI 2: C += acc
template <int BM, int BN, int EPI>
__global__ void __launch_bounds__(256) mfma_gemm(
    const __hip_bfloat16* __restrict__ A, int lda,
    const __hip_bfloat16* __restrict__ B, int ldb,
    float* __restrict__ C, int ldc,
    int N, int K, const float* __restrict__ bias) {
    constexpr int BK = 32;
    __shared__ unsigned short As[BM * BK];
    __shared__ unsigned short Bs[BN * BK];
    const int tid  = threadIdx.x;
    const int lane = tid & 63;
    const int m0 = blockIdx.y * BM, n0 = blockIdx.x * BN;
    constexpr int WM = BM / 2, WN = BN / 2;   // 2x2 waves
    constexpr int MR = WM / 16, NR = WN / 16;
    const int wave = tid >> 6;
    const int wm = (wave >> 1) * WM, wn = (wave & 1) * WN;
    const int l15 = lane & 15, l4 = lane >> 4;
    f32x4 acc[MR][NR] = {};

    for (int k0 = 0; k0 < K; k0 += BK) {
        for (int idx = tid; idx < BM * 4; idx += 256) {
            const int r = idx >> 2, c = (idx & 3) << 3;
            __builtin_amdgcn_global_load_lds(
                (const __attribute__((address_space(1))) void*)(A + (size_t)(m0 + r) * lda + k0 + c),
                (__attribute__((address_space(3))) void*)(As + (idx - lane) * 8),
                16, 0, 0);
        }
        for (int idx = tid; idx < BN * 4; idx += 256) {
            const int r = idx >> 2, c = (idx & 3) << 3;
            __builtin_amdgcn_global_load_lds(
                (const __attribute__((address_space(1))) void*)(B + (size_t)(n0 + r) * ldb + k0 + c),
                (__attribute__((address_space(3))) void*)(Bs + (idx - lane) * 8),
                16, 0, 0);
        }
        __syncthreads();

        short8 af[MR], bfv[NR];
        #pragma unroll
        for (int mi = 0; mi < MR; ++mi)
            af[mi] = *reinterpret_cast<const short8*>(&As[(wm + mi * 16 + l15) * BK + l4 * 8]);
        #pragma unroll
        for (int ni = 0; ni < NR; ++ni)
            bfv[ni] = *reinterpret_cast<const short8*>(&Bs[(wn + ni * 16 + l15) * BK + l4 * 8]);
        #pragma unroll
        for (int mi = 0; mi < MR; ++mi)
            #pragma unroll
            for (int ni = 0; ni < NR; ++ni)
                acc[mi][ni] = __builtin_amdgcn_mfma_f32_16x16x32_bf16(
                    af[mi], bfv[ni], acc[mi][ni], 0, 0, 0);
        __syncthreads();
    }

    // C/D layout: col = lane&15, row = (lane>>4)*4 + reg  (m89/m91)
    #pragma unroll
    for (int mi = 0; mi < MR; ++mi) {
        const int mrow = m0 + wm + mi * 16 + l4 * 4;
        #pragma unroll
        for (int ni = 0; ni < NR; ++ni) {
            const int ncol = n0 + wn + ni * 16 + l15;
            if (ncol >= N) continue;
            #pragma unroll
            for (int r = 0; r < 4; ++r) {
                float v = acc[mi][ni][r];
                if (EPI == 1) {
                    v += bias[ncol];
                    v = (v > 20.f) ? v : log1pf(__expf(v));  // softplus
                }
                const size_t off = (size_t)(mrow + r) * ldc + ncol;
                if (EPI == 2) C[off] += v; else C[off] = v;
            }
        }
    }
}

// ------------------------------------------- depthwise causal conv+silu
__global__ void __launch_bounds__(256) conv_silu_kernel(
    const float* __restrict__ xz, const float* __restrict__ cw,
    const float* __restrict__ cb, float* __restrict__ xi,
    __hip_bfloat16* __restrict__ xi2) {
    const int s = blockIdx.x;
    const int d = blockIdx.y * 256 + threadIdx.x;
    float acc = cb[d];
    #pragma unroll
    for (int k = 0; k < kDConv; ++k) {
        const int sl = s - (kDConv - 1) + k;
        if (sl >= 0)
            acc = fmaf(xz[(size_t)sl * (2 * kDInner) + d], cw[d * kDConv + k], acc);
    }
    const float v = silu_f(acc);
    xi[(size_t)s * kDInner + d] = v;
    __hip_bfloat16 hi, lo;
    split_bf16(v, hi, lo);
    __hip_bfloat16* row = xi2 + (size_t)s * 3 * kDInner;
    row[d] = hi; row[kDInner + d] = lo; row[2 * kDInner + d] = hi;
}

// ------------------------------------------------- chunked selective scan
// recurrence: state = state * exp(exp(dt*A)) + dt*u*B ; y = <state,C> + u*Dv
// Phase 1: per chunk j, local scan from 0 -> S[j][dn], multiplier P[j][dn].
__global__ void __launch_bounds__(256) scan_part1(
    const float* __restrict__ dt, const float* __restrict__ u,
    const float* __restrict__ proj, const float* __restrict__ A_log,
    float* __restrict__ P, float* __restrict__ S) {
    __shared__ float sdt[kCH][16], su[kCH][16], sB[kCH][16];
    const int tid = threadIdx.x;
    const int n = tid & 15, dl = tid >> 4;
    const int d0 = blockIdx.x * 16;
    const int l0 = blockIdx.y * kCH;
    for (int idx = tid; idx < kCH * 16; idx += 256) {
        const int r = idx >> 4, c = idx & 15;
        sdt[r][c] = dt[(size_t)(l0 + r) * kDInner + d0 + c];
        su [r][c] = u [(size_t)(l0 + r) * kDInner + d0 + c];
        sB [r][c] = proj[(size_t)(l0 + r) * kProj + kDtRank + c];
    }
    __syncthreads();
    const int d = d0 + dl;
    const float Adn = -__expf(A_log[d * kDState + n]);
    float state = 0.f, sumA = 0.f;
    #pragma unroll 8
    for (int l = 0; l < kCH; ++l) {
        const float dtv = sdt[l][dl];
        const float adelta = __expf(dtv * Adn);
        const float mult = __expf(adelta);
        state = fmaf(state, mult, dtv * su[l][dl] * sB[l][n]);
        sumA += adelta;
    }
    const int dn = d * kDState + n;
    P[(size_t)blockIdx.y * kDN + dn] = __expf(sumA);
    S[(size_t)blockIdx.y * kDN + dn] = state;
}

// Phase 2: serial prefix over chunks -> SI[j][dn] = state entering chunk j.
__global__ void __launch_bounds__(256) scan_combine(
    const float* __restrict__ P, const float* __restrict__ S,
    float* __restrict__ SI) {
    const int dn = blockIdx.x * 256 + threadIdx.x;
    float s = 0.f;
    #pragma unroll
    for (int j = 0; j < kNCH; ++j) {
        const size_t idx = (size_t)j * kDN + dn;
        SI[idx] = s;
        s = fmaf(s, P[idx], S[idx]);
    }
}

// Phase 3: re-run chunk scan seeded with SI, produce y.
__global__ void __launch_bounds__(256) scan_part2(
    const float* __restrict__ dt, const float* __restrict__ u,
    const float* __restrict__ proj, const float* __restrict__ A_log,
    const float* __restrict__ D_skip, const float* __restrict__ SI,
    float* __restrict__ y) {
    __shared__ float sdt[kCH][16], su[kCH][16], sB[kCH][16], sC[kCH][16];
    __shared__ float sy[kCH][16];
    const int tid = threadIdx.x;
    const int n = tid & 15, dl = tid >> 4;
    const int d0 = blockIdx.x * 16;
    const int l0 = blockIdx.y * kCH;
    for (int idx = tid; idx < kCH * 16; idx += 256) {
        const int r = idx >> 4, c = idx & 15;
        sdt[r][c] = dt[(size_t)(l0 + r) * kDInner + d0 + c];
        su [r][c] = u [(size_t)(l0 + r) * kDInner + d0 + c];
        sB [r][c] = proj[(size_t)(l0 + r) * kProj + kDtRank + c];
        sC [r][c] = proj[(size_t)(l0 + r) * kProj + kDtRank + kDState + c];
    }
    __syncthreads();
    const int d = d0 + dl;
    const float Adn = -__expf(A_log[d * kDState + n]);
    const float Dv  = D_skip[d];
    float state = SI[(size_t)blockIdx.y * kDN + d * kDState + n];
    for (int l = 0; l < kCH; ++l) {
        const float dtv = sdt[l][dl];
        const float uv  = su[l][dl];
        const float mult = __expf(__expf(dtv * Adn));
        state = fmaf(state, mult, dtv * uv * sB[l][n]);
        float contrib = state * sC[l][n];
        contrib += __shfl_xor(contrib, 8);
        contrib += __shfl_xor(contrib, 4);
        contrib += __shfl_xor(contrib, 2);
        contrib += __shfl_xor(contrib, 1);
        if (n == 0) sy[l][dl] = fmaf(uv, Dv, contrib);
    }
    __syncthreads();
    for (int idx = tid; idx < kCH * 16; idx += 256) {
        const int r = idx >> 4, c = idx & 15;
        y[(size_t)(l0 + r) * kDInner + d0 + c] = sy[r][c];
    }
}

// ----------------------------- g = y * silu(res) (3-term split bf16)
__global__ void __launch_bounds__(256) mul_silu_kernel(
    const float* __restrict__ y, const float* __restrict__ xz,
    __hip_bfloat16* __restrict__ g2) {
    const int s = blockIdx.x;
    const int d = blockIdx.y * 256 + threadIdx.x;
    const float res = xz[(size_t)s * (2 * kDInner) + kDInner + d];
    const float v = y[(size_t)s * kDInner + d] * silu_f(res);
    __hip_bfloat16 hi, lo;
    split_bf16(v, hi, lo);
    __hip_bfloat16* row = g2 + (size_t)s * 3 * kDInner;
    row[d] = hi; row[kDInner + d] = lo; row[2 * kDInner + d] = hi;
}

}  // namespace

extern "C" void kernel_launch(void* const* d_in, const int* in_sizes, int n_in,
                              void* d_out, int out_size, void* d_ws, size_t ws_size,
                              hipStream_t stream) {
    const int*   tokens       = (const int*)d_in[0];
    const float* embedding    = (const float*)d_in[1];
    const float* norm_w       = (const float*)d_in[2];
    const float* in_proj_w    = (const float*)d_in[3];
    const float* conv_w       = (const float*)d_in[4];
    const float* conv_b       = (const float*)d_in[5];
    const float* x_proj_w     = (const float*)d_in[6];
    const float* dt_proj_w    = (const float*)d_in[7];
    const float* dt_proj_b    = (const float*)d_in[8];
    const float* A_log        = (const float*)d_in[9];
    const float* D_skip       = (const float*)d_in[10];
    const float* out_proj_w   = (const float*)d_in[11];
    const float* final_norm_w = (const float*)d_in[12];
    float* out = (float*)d_out;

    constexpr int K3m = 3 * kDModel;   // 2304
    constexpr int K3i = 3 * kDInner;   // 4608

    char* ws = (char*)d_ws;
    auto alloc = [&](size_t bytes) { char* p = ws; ws += (bytes + 255) & ~(size_t)255; return p; };
    float* x    = (float*)alloc((size_t)kSeq * kDModel * 4);
    float* xz   = (float*)alloc((size_t)kSeq * 2 * kDInner * 4);
    float* xi   = (float*)alloc((size_t)kSeq * kDInner * 4);
    float* proj = (float*)alloc((size_t)kSeq * kProj * 4);
    float* dt   = (float*)alloc((size_t)kSeq * kDInner * 4);
    float* y    = (float*)alloc((size_t)kSeq * kDInner * 4);
    float* scanP  = (float*)alloc((size_t)kNCH * kDN * 4);
    float* scanS  = (float*)alloc((size_t)kNCH * kDN * 4);
    float* scanSI = (float*)alloc((size_t)kNCH * kDN * 4);
    __hip_bfloat16* h_bf     = (__hip_bfloat16*)alloc((size_t)kSeq * kDModel * 2);
    __hip_bfloat16* h2       = (__hip_bfloat16*)alloc((size_t)kSeq * K3m * 2);
    __hip_bfloat16* xi2      = (__hip_bfloat16*)alloc((size_t)kSeq * K3i * 2);
    __hip_bfloat16* g2       = (__hip_bfloat16*)alloc((size_t)kSeq * K3i * 2);
    __hip_bfloat16* proj_pad = (__hip_bfloat16*)alloc((size_t)kSeq * 64 * 2);
    __hip_bfloat16* emb_bf   = (__hip_bfloat16*)alloc((size_t)kVocab * kDModel * 2);
    __hip_bfloat16* inw2     = (__hip_bfloat16*)alloc((size_t)kL * 2 * kDInner * K3m * 2);
    __hip_bfloat16* outw2    = (__hip_bfloat16*)alloc((size_t)kL * kDModel * K3i * 2);
    __hip_bfloat16* xw2      = (__hip_bfloat16*)alloc((size_t)kL * 96 * K3i * 2);
    __hip_bfloat16* dtw_pad  = (__hip_bfloat16*)alloc((size_t)kL * kDInner * 64 * 2);

    // ---- weight conversions (per call) ----
    {
        f2b_kernel<<<4096, 256, 0, stream>>>(embedding, emb_bf, kVocab * kDModel);
        for (int i = 0; i < kL; ++i) {
            split3_kernel<<<(2 * kDInner * kDModel + 255) / 256, 256, 0, stream>>>(
                in_proj_w + (size_t)i * 2 * kDInner * kDModel, kDModel,
                2 * kDInner, kDModel, inw2 + (size_t)i * 2 * kDInner * K3m, 2 * kDInner);
            split3_kernel<<<(kDModel * kDInner + 255) / 256, 256, 0, stream>>>(
                out_proj_w + (size_t)i * kDModel * kDInner, kDInner,
                kDModel, kDInner, outw2 + (size_t)i * kDModel * K3i, kDModel);
            split3_kernel<<<(96 * kDInner + 255) / 256, 256, 0, stream>>>(
                x_proj_w + (size_t)i * kProj * kDInner, kDInner,
                kProj, kDInner, xw2 + (size_t)i * 96 * K3i, 96);
            pad_b_kernel<<<(kDInner * 64 + 255) / 256, 256, 0, stream>>>(
                dt_proj_w + (size_t)i * kDInner * kDtRank, kDtRank, kDInner, kDtRank,
                dtw_pad + (size_t)i * kDInner * 64, 64, kDInner);
        }
    }

    embed_kernel<<<kSeq, 256, 0, stream>>>(tokens, embedding, x);

    for (int i = 0; i < kL; ++i) {
        rmsnorm_kernel<true><<<kSeq, 256, 0, stream>>>(x, norm_w + (size_t)i * kDModel, h2);

        // xz = h @ in_proj_w[i]^T   (1024 x 3072, K=768 -> split 2304)
        mfma_gemm<128, 128, 0><<<dim3(2 * kDInner / 128, kSeq / 128), 256, 0, stream>>>(
            h2, K3m, inw2 + (size_t)i * 2 * kDInner * K3m, K3m,
            xz, 2 * kDInner, 2 * kDInner, K3m, nullptr);

        // xi = silu(conv(xz[:, :1536]) + b)
        conv_silu_kernel<<<dim3(kSeq, kDInner / 256), 256, 0, stream>>>(
            xz, conv_w + (size_t)i * kDInner * kDConv, conv_b + (size_t)i * kDInner,
            xi, xi2);

        // proj = xi @ x_proj_w[i]^T   (1024 x 80, K=1536 -> split 4608)
        mfma_gemm<128, 96, 0><<<dim3(1, kSeq / 128), 256, 0, stream>>>(
            xi2, K3i, xw2 + (size_t)i * 96 * K3i, K3i,
            proj, kProj, kProj, K3i, nullptr);

        // proj_pad = bf16(proj[:, :48]) zero-padded to K=64
        pad_b_kernel<<<(kSeq * 64 + 255) / 256, 256, 0, stream>>>(
            proj, kProj, kSeq, kDtRank, proj_pad, 64, kSeq);

        // dt = softplus(proj[:, :48] @ dt_proj_w[i]^T + b)   (1024 x 1536, K=64)
        mfma_gemm<128, 128, 1><<<dim3(kDInner / 128, kSeq / 128), 256, 0, stream>>>(
            proj_pad, 64, dtw_pad + (size_t)i * kDInner * 64, 64,
            dt, kDInner, kDInner, 64, dt_proj_b + (size_t)i * kDInner);

        // y = selective_scan(xi, dt, A, B, C, D) — chunked 3-phase
        const float* A_l = A_log + (size_t)i * kDInner * kDState;
        scan_part1<<<dim3(kDInner / 16, kNCH), 256, 0, stream>>>(
            dt, xi, proj, A_l, scanP, scanS);
        scan_combine<<<kDN / 256, 256, 0, stream>>>(scanP, scanS, scanSI);
        scan_part2<<<dim3(kDInner / 16, kNCH), 256, 0, stream>>>(
            dt, xi, proj, A_l, D_skip + (size_t)i * kDInner, scanSI, y);

        // g = y * silu(res)
        mul_silu_kernel<<<dim3(kSeq, kDInner / 256), 256, 0, stream>>>(y, xz, g2);

        // x += g @ out_proj_w[i]^T   (1024 x 768, K=1536 -> split 4608)
        mfma_gemm<128, 128, 2><<<dim3(kDModel / 128, kSeq / 128), 256, 0, stream>>>(
            g2, K3i, outw2 + (size_t)i * kDModel * K3i, K3i,
            x, kDModel, kDModel, K3i, nullptr);
    }

    // out = rmsnorm(x, final_norm_w) @ embedding^T   (1024 x 32000, K=768)
    rmsnorm_kernel<false><<<kSeq, 256, 0, stream>>>(x, final_norm_w, h_bf);
    mfma_gemm<128, 128, 0><<<dim3(kVocab / 128, kSeq / 128), 256, 0, stream>>>(
        h_bf, kDModel, emb_bf, kDModel, out, kVocab, kVocab, kDModel, nullptr);
}

// Round 5
// 936.966 us; speedup vs baseline: 5.4400x; 1.8409x over previous
//
#include <hip/hip_runtime.h>
#include <hip/hip_bf16.h>
#include <cmath>

namespace {

constexpr int kL      = 4;
constexpr int kDModel = 768;
constexpr int kDInner = 1536;
constexpr int kDtRank = 48;
constexpr int kDState = 16;
constexpr int kDConv  = 4;
constexpr int kSeq    = 1024;
constexpr int kPLd    = 96;    // padded proj row stride (80 used)
constexpr int kVocab  = 32000;
constexpr int kCH     = 64;    // scan chunk length
constexpr int kNCH    = kSeq / kCH;  // 16 chunks
constexpr int kDN     = kDInner * kDState;  // 24576 (d,n) pairs

using short8 = __attribute__((ext_vector_type(8))) short;
using f32x4  = __attribute__((ext_vector_type(4))) float;

__device__ __forceinline__ float silu_f(float v) {
    return v / (1.f + __expf(-v));
}

__device__ __forceinline__ void split_bf16(float v, __hip_bfloat16& hi, __hip_bfloat16& lo) {
    hi = __float2bfloat16(v);
    lo = __float2bfloat16(v - __bfloat162float(hi));
}

// ---------------------------------------------------------------- fp32->bf16
__global__ void __launch_bounds__(256) f2b_kernel(
    const float* __restrict__ src, __hip_bfloat16* __restrict__ dst, int n) {
    int i = (blockIdx.x * 256 + threadIdx.x) * 4;
    const int stride = gridDim.x * 256 * 4;
    for (; i + 3 < n; i += stride) {
        const float4 v = *reinterpret_cast<const float4*>(src + i);
        dst[i + 0] = __float2bfloat16(v.x);
        dst[i + 1] = __float2bfloat16(v.y);
        dst[i + 2] = __float2bfloat16(v.z);
        dst[i + 3] = __float2bfloat16(v.w);
    }
}

// -------------------------------- fp32 -> 3-term split bf16 along K
// B-side: dst row = [hi | hi | lo]; rows >= `rows` zero-filled.
__global__ void __launch_bounds__(256) split3_kernel(
    const float* __restrict__ src, int ldsrc, int rows, int cols,
    __hip_bfloat16* __restrict__ dst, int rowsPad) {
    const int idx = blockIdx.x * 256 + threadIdx.x;
    if (idx >= rowsPad * cols) return;
    const int r = idx / cols, c = idx % cols;
    const float v = (r < rows) ? src[(size_t)r * ldsrc + c] : 0.f;
    __hip_bfloat16 hi, lo;
    split_bf16(v, hi, lo);
    __hip_bfloat16* row = dst + (size_t)r * 3 * cols;
    row[c] = hi; row[cols + c] = hi; row[2 * cols + c] = lo;
}

// ---------------------------------------------------------------- embedding
__global__ void __launch_bounds__(256) embed_kernel(
    const int* __restrict__ tokens, const float* __restrict__ emb,
    float* __restrict__ x) {
    const int s = blockIdx.x;
    const int t = tokens[s];
    const float* src = emb + (size_t)t * kDModel;
    float* dst = x + (size_t)s * kDModel;
    for (int d = threadIdx.x; d < kDModel; d += blockDim.x) dst[d] = src[d];
}

// ----------------------------------- rmsnorm -> bf16 (plain or 3-term split)
template <bool SPLIT>
__global__ void __launch_bounds__(256) rmsnorm_kernel(
    const float* __restrict__ x, const float* __restrict__ w,
    __hip_bfloat16* __restrict__ out) {
    const int s = blockIdx.x;
    const float* row = x + (size_t)s * kDModel;
    float ss = 0.f;
    for (int d = threadIdx.x; d < kDModel; d += blockDim.x) {
        const float v = row[d];
        ss = fmaf(v, v, ss);
    }
    #pragma unroll
    for (int m = 32; m; m >>= 1) ss += __shfl_xor(ss, m);
    __shared__ float red[4];
    if ((threadIdx.x & 63) == 0) red[threadIdx.x >> 6] = ss;
    __syncthreads();
    const float total = red[0] + red[1] + red[2] + red[3];
    const float scale = rsqrtf(total / (float)kDModel + 1e-5f);
    __hip_bfloat16* dst = out + (size_t)s * (SPLIT ? 3 * kDModel : kDModel);
    for (int d = threadIdx.x; d < kDModel; d += blockDim.x) {
        const float v = row[d] * scale * w[d];
        if (SPLIT) {
            __hip_bfloat16 hi, lo;
            split_bf16(v, hi, lo);
            dst[d] = hi; dst[kDModel + d] = lo; dst[2 * kDModel + d] = hi;
        } else {
            dst[d] = __float2bfloat16(v);
        }
    }
}

// ---------------------------------------------------------------- MFMA GEMM
// Writes C[m][n] = sum_{k in this split part} A[m][k]*B[n][k].
// KSPLIT>1: blockIdx.z = part index; part p writes to C + p*partStride.
// Grid: (m-tiles, n-tiles, KSPLIT)  -- m is the fast dim (B-panel L2 reuse).
template <int BM, int BN, int KSPLIT>
__global__ void __launch_bounds__(256) mfma_gemm(
    const __hip_bfloat16* __restrict__ A, int lda,
    const __hip_bfloat16* __restrict__ B, int ldb,
    float* __restrict__ C, int ldc,
    int N, int K, size_t partStride) {
    constexpr int BK = 32;
    __shared__ unsigned short As[BM * BK];
    __shared__ unsigned short Bs[BN * BK];
    const int tid  = threadIdx.x;
    const int lane = tid & 63;
    const int m0 = blockIdx.x * BM, n0 = blockIdx.y * BN;
    const int Kp = K / KSPLIT;
    const int kbeg = (KSPLIT > 1) ? blockIdx.z * Kp : 0;
    float* Cw = (KSPLIT > 1) ? C + (size_t)blockIdx.z * partStride : C;
    constexpr int WM = BM / 2, WN = BN / 2;   // 2x2 waves
    constexpr int MR = WM / 16, NR = WN / 16;
    const int wave = tid >> 6;
    const int wm = (wave >> 1) * WM, wn = (wave & 1) * WN;
    const int l15 = lane & 15, l4 = lane >> 4;
    f32x4 acc[MR][NR] = {};

    for (int kk = 0; kk < Kp; kk += BK) {
        const int k0 = kbeg + kk;
        for (int idx = tid; idx < BM * 4; idx += 256) {
            const int r = idx >> 2, c = (idx & 3) << 3;
            __builtin_amdgcn_global_load_lds(
                (const __attribute__((address_space(1))) void*)(A + (size_t)(m0 + r) * lda + k0 + c),
                (__attribute__((address_space(3))) void*)(As + (idx - lane) * 8),
                16, 0, 0);
        }
        for (int idx = tid; idx < BN * 4; idx += 256) {
            const int r = idx >> 2, c = (idx & 3) << 3;
            __builtin_amdgcn_global_load_lds(
                (const __attribute__((address_space(1))) void*)(B + (size_t)(n0 + r) * ldb + k0 + c),
                (__attribute__((address_space(3))) void*)(Bs + (idx - lane) * 8),
                16, 0, 0);
        }
        __syncthreads();

        short8 af[MR], bfv[NR];
        #pragma unroll
        for (int mi = 0; mi < MR; ++mi)
            af[mi] = *reinterpret_cast<const short8*>(&As[(wm + mi * 16 + l15) * BK + l4 * 8]);
        #pragma unroll
        for (int ni = 0; ni < NR; ++ni)
            bfv[ni] = *reinterpret_cast<const short8*>(&Bs[(wn + ni * 16 + l15) * BK + l4 * 8]);
        #pragma unroll
        for (int mi = 0; mi < MR; ++mi)
            #pragma unroll
            for (int ni = 0; ni < NR; ++ni)
                acc[mi][ni] = __builtin_amdgcn_mfma_f32_16x16x32_bf16(
                    af[mi], bfv[ni], acc[mi][ni], 0, 0, 0);
        __syncthreads();
    }

    // C/D layout: col = lane&15, row = (lane>>4)*4 + reg  (m89/m91)
    #pragma unroll
    for (int mi = 0; mi < MR; ++mi) {
        const int mrow = m0 + wm + mi * 16 + l4 * 4;
        #pragma unroll
        for (int ni = 0; ni < NR; ++ni) {
            const int ncol = n0 + wn + ni * 16 + l15;
            if (ncol >= N) continue;
            #pragma unroll
            for (int r = 0; r < 4; ++r)
                Cw[(size_t)(mrow + r) * ldc + ncol] = acc[mi][ni][r];
        }
    }
}

// ------------------------- reduce NP split-K partials: dst = / += sum(parts)
template <int NP, bool ADD>
__global__ void __launch_bounds__(256) reduce_parts(
    const float* __restrict__ parts, size_t stride,
    float* __restrict__ dst, int count) {
    const int i = (blockIdx.x * 256 + threadIdx.x) * 4;
    if (i >= count) return;
    float4 s = *reinterpret_cast<const float4*>(parts + i);
    #pragma unroll
    for (int p = 1; p < NP; ++p) {
        const float4 v = *reinterpret_cast<const float4*>(parts + (size_t)p * stride + i);
        s.x += v.x; s.y += v.y; s.z += v.z; s.w += v.w;
    }
    float4* d = reinterpret_cast<float4*>(dst + i);
    if (ADD) {
        float4 o = *d;
        o.x += s.x; o.y += s.y; o.z += s.z; o.w += s.w;
        *d = o;
    } else {
        *d = s;
    }
}

// ---------------------------- dt = softplus(proj[:, :48] @ dtw^T + bias)
// fp32-exact, K=48. Block: 256 n-cols x 8 m-rows; dtw tile staged in LDS.
__global__ void __launch_bounds__(256) dt_kernel(
    const float* __restrict__ proj, const float* __restrict__ dtw,
    const float* __restrict__ bias, float* __restrict__ dt) {
    __shared__ float sw[kDtRank][257];
    const int tid = threadIdx.x;
    const int n0 = blockIdx.x * 256;
    const int m0 = blockIdx.y * 8;
    for (int idx = tid; idx < 256 * kDtRank; idx += 256) {
        const int nn = idx / kDtRank, k = idx % kDtRank;
        sw[k][nn] = dtw[(size_t)(n0 + nn) * kDtRank + k];
    }
    __syncthreads();
    const int n = n0 + tid;
    const float b = bias[n];
    #pragma unroll
    for (int mi = 0; mi < 8; ++mi) {
        const float* pr = proj + (size_t)(m0 + mi) * kPLd;
        float acc = b;
        #pragma unroll
        for (int k = 0; k < kDtRank; ++k)
            acc = fmaf(pr[k], sw[k][tid], acc);
        acc = (acc > 20.f) ? acc : log1pf(__expf(acc));  // softplus
        dt[(size_t)(m0 + mi) * kDInner + n] = acc;
    }
}

// ------------------------------------------- depthwise causal conv+silu
__global__ void __launch_bounds__(256) conv_silu_kernel(
    const float* __restrict__ xz, const float* __restrict__ cw,
    const float* __restrict__ cb, float* __restrict__ xi,
    __hip_bfloat16* __restrict__ xi2) {
    const int s = blockIdx.x;
    const int d = blockIdx.y * 256 + threadIdx.x;
    float acc = cb[d];
    #pragma unroll
    for (int k = 0; k < kDConv; ++k) {
        const int sl = s - (kDConv - 1) + k;
        if (sl >= 0)
            acc = fmaf(xz[(size_t)sl * (2 * kDInner) + d], cw[d * kDConv + k], acc);
    }
    const float v = silu_f(acc);
    xi[(size_t)s * kDInner + d] = v;
    __hip_bfloat16 hi, lo;
    split_bf16(v, hi, lo);
    __hip_bfloat16* row = xi2 + (size_t)s * 3 * kDInner;
    row[d] = hi; row[kDInner + d] = lo; row[2 * kDInner + d] = hi;
}

// ------------------------------------------------- chunked selective scan
// recurrence: state = state * exp(exp(dt*A)) + dt*u*B ; y = <state,C> + u*Dv
__global__ void __launch_bounds__(256) scan_part1(
    const float* __restrict__ dt, const float* __restrict__ u,
    const float* __restrict__ proj, const float* __restrict__ A_log,
    float* __restrict__ P, float* __restrict__ S) {
    __shared__ float sdt[kCH][16], su[kCH][16], sB[kCH][16];
    const int tid = threadIdx.x;
    const int n = tid & 15, dl = tid >> 4;
    const int d0 = blockIdx.x * 16;
    const int l0 = blockIdx.y * kCH;
    for (int idx = tid; idx < kCH * 16; idx += 256) {
        const int r = idx >> 4, c = idx & 15;
        sdt[r][c] = dt[(size_t)(l0 + r) * kDInner + d0 + c];
        su [r][c] = u [(size_t)(l0 + r) * kDInner + d0 + c];
        sB [r][c] = proj[(size_t)(l0 + r) * kPLd + kDtRank + c];
    }
    __syncthreads();
    const int d = d0 + dl;
    const float Adn = -__expf(A_log[d * kDState + n]);
    float state = 0.f, sumA = 0.f;
    #pragma unroll 8
    for (int l = 0; l < kCH; ++l) {
        const float dtv = sdt[l][dl];
        const float adelta = __expf(dtv * Adn);
        const float mult = __expf(adelta);
        state = fmaf(state, mult, dtv * su[l][dl] * sB[l][n]);
        sumA += adelta;
    }
    const int dn = d * kDState + n;
    P[(size_t)blockIdx.y * kDN + dn] = __expf(sumA);
    S[(size_t)blockIdx.y * kDN + dn] = state;
}

__global__ void __launch_bounds__(256) scan_combine(
    const float* __restrict__ P, const float* __restrict__ S,
    float* __restrict__ SI) {
    const int dn = blockIdx.x * 256 + threadIdx.x;
    float s = 0.f;
    #pragma unroll
    for (int j = 0; j < kNCH; ++j) {
        const size_t idx = (size_t)j * kDN + dn;
        SI[idx] = s;
        s = fmaf(s, P[idx], S[idx]);
    }
}

__global__ void __launch_bounds__(256) scan_part2(
    const float* __restrict__ dt, const float* __restrict__ u,
    const float* __restrict__ proj, const float* __restrict__ A_log,
    const float* __restrict__ D_skip, const float* __restrict__ SI,
    float* __restrict__ y) {
    __shared__ float sdt[kCH][16], su[kCH][16], sB[kCH][16], sC[kCH][16];
    __shared__ float sy[kCH][16];
    const int tid = threadIdx.x;
    const int n = tid & 15, dl = tid >> 4;
    const int d0 = blockIdx.x * 16;
    const int l0 = blockIdx.y * kCH;
    for (int idx = tid; idx < kCH * 16; idx += 256) {
        const int r = idx >> 4, c = idx & 15;
        sdt[r][c] = dt[(size_t)(l0 + r) * kDInner + d0 + c];
        su [r][c] = u [(size_t)(l0 + r) * kDInner + d0 + c];
        sB [r][c] = proj[(size_t)(l0 + r) * kPLd + kDtRank + c];
        sC [r][c] = proj[(size_t)(l0 + r) * kPLd + kDtRank + kDState + c];
    }
    __syncthreads();
    const int d = d0 + dl;
    const float Adn = -__expf(A_log[d * kDState + n]);
    const float Dv  = D_skip[d];
    float state = SI[(size_t)blockIdx.y * kDN + d * kDState + n];
    for (int l = 0; l < kCH; ++l) {
        const float dtv = sdt[l][dl];
        const float uv  = su[l][dl];
        const float mult = __expf(__expf(dtv * Adn));
        state = fmaf(state, mult, dtv * uv * sB[l][n]);
        float contrib = state * sC[l][n];
        contrib += __shfl_xor(contrib, 8);
        contrib += __shfl_xor(contrib, 4);
        contrib += __shfl_xor(contrib, 2);
        contrib += __shfl_xor(contrib, 1);
        if (n == 0) sy[l][dl] = fmaf(uv, Dv, contrib);
    }
    __syncthreads();
    for (int idx = tid; idx < kCH * 16; idx += 256) {
        const int r = idx >> 4, c = idx & 15;
        y[(size_t)(l0 + r) * kDInner + d0 + c] = sy[r][c];
    }
}

// ----------------------------- g = y * silu(res) (3-term split bf16)
__global__ void __launch_bounds__(256) mul_silu_kernel(
    const float* __restrict__ y, const float* __restrict__ xz,
    __hip_bfloat16* __restrict__ g2) {
    const int s = blockIdx.x;
    const int d = blockIdx.y * 256 + threadIdx.x;
    const float res = xz[(size_t)s * (2 * kDInner) + kDInner + d];
    const float v = y[(size_t)s * kDInner + d] * silu_f(res);
    __hip_bfloat16 hi, lo;
    split_bf16(v, hi, lo);
    __hip_bfloat16* row = g2 + (size_t)s * 3 * kDInner;
    row[d] = hi; row[kDInner + d] = lo; row[2 * kDInner + d] = hi;
}

}  // namespace

extern "C" void kernel_launch(void* const* d_in, const int* in_sizes, int n_in,
                              void* d_out, int out_size, void* d_ws, size_t ws_size,
                              hipStream_t stream) {
    const int*   tokens       = (const int*)d_in[0];
    const float* embedding    = (const float*)d_in[1];
    const float* norm_w       = (const float*)d_in[2];
    const float* in_proj_w    = (const float*)d_in[3];
    const float* conv_w       = (const float*)d_in[4];
    const float* conv_b       = (const float*)d_in[5];
    const float* x_proj_w     = (const float*)d_in[6];
    const float* dt_proj_w    = (const float*)d_in[7];
    const float* dt_proj_b    = (const float*)d_in[8];
    const float* A_log        = (const float*)d_in[9];
    const float* D_skip       = (const float*)d_in[10];
    const float* out_proj_w   = (const float*)d_in[11];
    const float* final_norm_w = (const float*)d_in[12];
    float* out = (float*)d_out;

    constexpr int K3m = 3 * kDModel;   // 2304
    constexpr int K3i = 3 * kDInner;   // 4608

    char* ws = (char*)d_ws;
    auto alloc = [&](size_t bytes) { char* p = ws; ws += (bytes + 255) & ~(size_t)255; return p; };
    float* x    = (float*)alloc((size_t)kSeq * kDModel * 4);
    float* xz   = (float*)alloc((size_t)kSeq * 2 * kDInner * 4);
    float* xi   = (float*)alloc((size_t)kSeq * kDInner * 4);
    float* proj = (float*)alloc((size_t)kSeq * kPLd * 4);
    float* dt   = (float*)alloc((size_t)kSeq * kDInner * 4);
    float* y    = (float*)alloc((size_t)kSeq * kDInner * 4);
    float* scanP  = (float*)alloc((size_t)kNCH * kDN * 4);
    float* scanS  = (float*)alloc((size_t)kNCH * kDN * 4);
    float* scanSI = (float*)alloc((size_t)kNCH * kDN * 4);
    float* parts  = (float*)alloc((size_t)2 * kSeq * 2 * kDInner * 4);  // 25.2 MB, reused
    __hip_bfloat16* h_bf     = (__hip_bfloat16*)alloc((size_t)kSeq * kDModel * 2);
    __hip_bfloat16* h2       = (__hip_bfloat16*)alloc((size_t)kSeq * K3m * 2);
    __hip_bfloat16* xi2      = (__hip_bfloat16*)alloc((size_t)kSeq * K3i * 2);
    __hip_bfloat16* g2       = (__hip_bfloat16*)alloc((size_t)kSeq * K3i * 2);
    __hip_bfloat16* emb_bf   = (__hip_bfloat16*)alloc((size_t)kVocab * kDModel * 2);
    __hip_bfloat16* inw2     = (__hip_bfloat16*)alloc((size_t)kL * 2 * kDInner * K3m * 2);
    __hip_bfloat16* outw2    = (__hip_bfloat16*)alloc((size_t)kL * kDModel * K3i * 2);
    __hip_bfloat16* xw2      = (__hip_bfloat16*)alloc((size_t)kL * kPLd * K3i * 2);

    // ---- weight conversions (per call) ----
    f2b_kernel<<<4096, 256, 0, stream>>>(embedding, emb_bf, kVocab * kDModel);
    for (int i = 0; i < kL; ++i) {
        split3_kernel<<<(2 * kDInner * kDModel + 255) / 256, 256, 0, stream>>>(
            in_proj_w + (size_t)i * 2 * kDInner * kDModel, kDModel,
            2 * kDInner, kDModel, inw2 + (size_t)i * 2 * kDInner * K3m, 2 * kDInner);
        split3_kernel<<<(kDModel * kDInner + 255) / 256, 256, 0, stream>>>(
            out_proj_w + (size_t)i * kDModel * kDInner, kDInner,
            kDModel, kDInner, outw2 + (size_t)i * kDModel * K3i, kDModel);
        split3_kernel<<<(kPLd * kDInner + 255) / 256, 256, 0, stream>>>(
            x_proj_w + (size_t)i * (kDtRank + 2 * kDState) * kDInner, kDInner,
            kDtRank + 2 * kDState, kDInner, xw2 + (size_t)i * kPLd * K3i, kPLd);
    }

    embed_kernel<<<kSeq, 256, 0, stream>>>(tokens, embedding, x);

    for (int i = 0; i < kL; ++i) {
        rmsnorm_kernel<true><<<kSeq, 256, 0, stream>>>(x, norm_w + (size_t)i * kDModel, h2);

        // xz = h @ in_proj_w[i]^T   (1024 x 3072, K=2304 split), KSPLIT=2
        mfma_gemm<128, 128, 2><<<dim3(kSeq / 128, 2 * kDInner / 128, 2), 256, 0, stream>>>(
            h2, K3m, inw2 + (size_t)i * 2 * kDInner * K3m, K3m,
            parts, 2 * kDInner, 2 * kDInner, K3m, (size_t)kSeq * 2 * kDInner);
        reduce_parts<2, false><<<(kSeq * 2 * kDInner / 4 + 255) / 256, 256, 0, stream>>>(
            parts, (size_t)kSeq * 2 * kDInner, xz, kSeq * 2 * kDInner);

        // xi = silu(conv(xz[:, :1536]) + b)
        conv_silu_kernel<<<dim3(kSeq, kDInner / 256), 256, 0, stream>>>(
            xz, conv_w + (size_t)i * kDInner * kDConv, conv_b + (size_t)i * kDInner,
            xi, xi2);

        // proj = xi @ x_proj_w[i]^T   (1024 x 96pad, K=4608 split), KSPLIT=8
        mfma_gemm<128, 96, 8><<<dim3(kSeq / 128, 1, 8), 256, 0, stream>>>(
            xi2, K3i, xw2 + (size_t)i * kPLd * K3i, K3i,
            parts, kPLd, kPLd, K3i, (size_t)kSeq * kPLd);
        reduce_parts<8, false><<<(kSeq * kPLd / 4 + 255) / 256, 256, 0, stream>>>(
            parts, (size_t)kSeq * kPLd, proj, kSeq * kPLd);

        // dt = softplus(proj[:, :48] @ dt_proj_w^T + b)  -- fp32 exact
        dt_kernel<<<dim3(kDInner / 256, kSeq / 8), 256, 0, stream>>>(
            proj, dt_proj_w + (size_t)i * kDInner * kDtRank,
            dt_proj_b + (size_t)i * kDInner, dt);

        // y = selective_scan(xi, dt, A, B, C, D) — chunked 3-phase
        const float* A_l = A_log + (size_t)i * kDInner * kDState;
        scan_part1<<<dim3(kDInner / 16, kNCH), 256, 0, stream>>>(
            dt, xi, proj, A_l, scanP, scanS);
        scan_combine<<<kDN / 256, 256, 0, stream>>>(scanP, scanS, scanSI);
        scan_part2<<<dim3(kDInner / 16, kNCH), 256, 0, stream>>>(
            dt, xi, proj, A_l, D_skip + (size_t)i * kDInner, scanSI, y);

        // g = y * silu(res)
        mul_silu_kernel<<<dim3(kSeq, kDInner / 256), 256, 0, stream>>>(y, xz, g2);

        // x += g @ out_proj_w[i]^T   (1024 x 768, K=4608 split), KSPLIT=4
        mfma_gemm<128, 128, 4><<<dim3(kSeq / 128, kDModel / 128, 4), 256, 0, stream>>>(
            g2, K3i, outw2 + (size_t)i * kDModel * K3i, K3i,
            parts, kDModel, kDModel, K3i, (size_t)kSeq * kDModel);
        reduce_parts<4, true><<<(kSeq * kDModel / 4 + 255) / 256, 256, 0, stream>>>(
            parts, (size_t)kSeq * kDModel, x, kSeq * kDModel);
    }

    // out = rmsnorm(x, final_norm_w) @ embedding^T   (1024 x 32000, K=768)
    rmsnorm_kernel<false><<<kSeq, 256, 0, stream>>>(x, final_norm_w, h_bf);
    mfma_gemm<128, 128, 1><<<dim3(kSeq / 128, kVocab / 128, 1), 256, 0, stream>>>(
        h_bf, kDModel, emb_bf, kDModel, out, kVocab, kVocab, kDModel, 0);
}

// Round 6
// 901.099 us; speedup vs baseline: 5.6566x; 1.0398x over previous
//
#include <hip/hip_runtime.h>
#include <hip/hip_bf16.h>
#include <cmath>

namespace {

constexpr int kL      = 4;
constexpr int kDModel = 768;
constexpr int kDInner = 1536;
constexpr int kDtRank = 48;
constexpr int kDState = 16;
constexpr int kDConv  = 4;
constexpr int kSeq    = 1024;
constexpr int kPLd    = 96;    // padded proj row stride (80 used)
constexpr int kVocab  = 32000;
constexpr int kCH     = 64;    // scan chunk length
constexpr int kNCH    = kSeq / kCH;  // 16 chunks
constexpr int kDN     = kDInner * kDState;  // 24576 (d,n) pairs

using short8 = __attribute__((ext_vector_type(8))) short;
using f32x4  = __attribute__((ext_vector_type(4))) float;

__device__ __forceinline__ float silu_f(float v) {
    return v / (1.f + __expf(-v));
}

__device__ __forceinline__ void split_bf16(float v, __hip_bfloat16& hi, __hip_bfloat16& lo) {
    hi = __float2bfloat16(v);
    lo = __float2bfloat16(v - __bfloat162float(hi));
}

// ---------------------------------------------------------------- fp32->bf16
__global__ void __launch_bounds__(256) f2b_kernel(
    const float* __restrict__ src, __hip_bfloat16* __restrict__ dst, int n) {
    int i = (blockIdx.x * 256 + threadIdx.x) * 4;
    const int stride = gridDim.x * 256 * 4;
    for (; i + 3 < n; i += stride) {
        const float4 v = *reinterpret_cast<const float4*>(src + i);
        dst[i + 0] = __float2bfloat16(v.x);
        dst[i + 1] = __float2bfloat16(v.y);
        dst[i + 2] = __float2bfloat16(v.z);
        dst[i + 3] = __float2bfloat16(v.w);
    }
}

// -------------------------------- fp32 -> 3-term split bf16 along K
// B-side: dst row = [hi | hi | lo]; rows >= `rows` zero-filled.
__global__ void __launch_bounds__(256) split3_kernel(
    const float* __restrict__ src, int ldsrc, int rows, int cols,
    __hip_bfloat16* __restrict__ dst, int rowsPad) {
    const int idx = blockIdx.x * 256 + threadIdx.x;
    if (idx >= rowsPad * cols) return;
    const int r = idx / cols, c = idx % cols;
    const float v = (r < rows) ? src[(size_t)r * ldsrc + c] : 0.f;
    __hip_bfloat16 hi, lo;
    split_bf16(v, hi, lo);
    __hip_bfloat16* row = dst + (size_t)r * 3 * cols;
    row[c] = hi; row[cols + c] = hi; row[2 * cols + c] = lo;
}

// ---------------------------------------------------------------- embedding
__global__ void __launch_bounds__(256) embed_kernel(
    const int* __restrict__ tokens, const float* __restrict__ emb,
    float* __restrict__ x) {
    const int s = blockIdx.x;
    const int t = tokens[s];
    const float* src = emb + (size_t)t * kDModel;
    float* dst = x + (size_t)s * kDModel;
    for (int d = threadIdx.x; d < kDModel; d += blockDim.x) dst[d] = src[d];
}

// ----------------------------------- rmsnorm -> bf16 (plain or 3-term split)
template <bool SPLIT>
__global__ void __launch_bounds__(256) rmsnorm_kernel(
    const float* __restrict__ x, const float* __restrict__ w,
    __hip_bfloat16* __restrict__ out) {
    const int s = blockIdx.x;
    const float* row = x + (size_t)s * kDModel;
    float ss = 0.f;
    for (int d = threadIdx.x; d < kDModel; d += blockDim.x) {
        const float v = row[d];
        ss = fmaf(v, v, ss);
    }
    #pragma unroll
    for (int m = 32; m; m >>= 1) ss += __shfl_xor(ss, m);
    __shared__ float red[4];
    if ((threadIdx.x & 63) == 0) red[threadIdx.x >> 6] = ss;
    __syncthreads();
    const float total = red[0] + red[1] + red[2] + red[3];
    const float scale = rsqrtf(total / (float)kDModel + 1e-5f);
    __hip_bfloat16* dst = out + (size_t)s * (SPLIT ? 3 * kDModel : kDModel);
    for (int d = threadIdx.x; d < kDModel; d += blockDim.x) {
        const float v = row[d] * scale * w[d];
        if (SPLIT) {
            __hip_bfloat16 hi, lo;
            split_bf16(v, hi, lo);
            dst[d] = hi; dst[kDModel + d] = lo; dst[2 * kDModel + d] = hi;
        } else {
            dst[d] = __float2bfloat16(v);
        }
    }
}

// ---------------------------------------------------------------- MFMA GEMM
// C[m][n] = sum_{k in split part} A[m][k]*B[n][k].  A: MxK bf16, B: NxK bf16.
// LDS granule swizzle: granule (row, q) holds global K-chunk q ^ ((row>>1)&3)
// (within-row permutation: global coalescing preserved, LDS dest linear,
//  fragment reads land 2 lanes/bank = conflict-free).
// XCD swizzle: bijective chunked remap of flattened (x,y) block id.
template <int BM, int BN, int KSPLIT>
__global__ void __launch_bounds__(256) mfma_gemm(
    const __hip_bfloat16* __restrict__ A, int lda,
    const __hip_bfloat16* __restrict__ B, int ldb,
    float* __restrict__ C, int ldc,
    int N, int K, size_t partStride) {
    constexpr int BK = 32;
    __shared__ unsigned short As[BM * BK];
    __shared__ unsigned short Bs[BN * BK];
    const int tid  = threadIdx.x;
    const int lane = tid & 63;

    // ---- bijective chunked XCD swizzle (m204) over the (x,y) grid ----
    const int nwg = gridDim.x * gridDim.y;
    int bid = blockIdx.y * gridDim.x + blockIdx.x;
    {
        const int q = nwg >> 3, r = nwg & 7;
        const int xcd = bid & 7, pos = bid >> 3;
        bid = (xcd < r ? xcd * (q + 1) : r * (q + 1) + (xcd - r) * q) + pos;
    }
    const int m0 = (bid % gridDim.x) * BM;   // m fast: same-n blocks adjacent
    const int n0 = (bid / gridDim.x) * BN;

    const int Kp = K / KSPLIT;
    const int kbeg = (KSPLIT > 1) ? blockIdx.z * Kp : 0;
    float* Cw = (KSPLIT > 1) ? C + (size_t)blockIdx.z * partStride : C;
    constexpr int WM = BM / 2, WN = BN / 2;   // 2x2 waves
    constexpr int MR = WM / 16, NR = WN / 16;
    const int wave = tid >> 6;
    const int wm = (wave >> 1) * WM, wn = (wave & 1) * WN;
    const int l15 = lane & 15, l4 = lane >> 4;
    f32x4 acc[MR][NR] = {};

    for (int kk = 0; kk < Kp; kk += BK) {
        const int k0 = kbeg + kk;
        for (int idx = tid; idx < BM * 4; idx += 256) {
            const int r = idx >> 2, q = idx & 3;
            const int qs = q ^ ((r >> 1) & 3);
            __builtin_amdgcn_global_load_lds(
                (const __attribute__((address_space(1))) void*)(A + (size_t)(m0 + r) * lda + k0 + qs * 8),
                (__attribute__((address_space(3))) void*)(As + (idx - lane) * 8),
                16, 0, 0);
        }
        for (int idx = tid; idx < BN * 4; idx += 256) {
            const int r = idx >> 2, q = idx & 3;
            const int qs = q ^ ((r >> 1) & 3);
            __builtin_amdgcn_global_load_lds(
                (const __attribute__((address_space(1))) void*)(B + (size_t)(n0 + r) * ldb + k0 + qs * 8),
                (__attribute__((address_space(3))) void*)(Bs + (idx - lane) * 8),
                16, 0, 0);
        }
        __syncthreads();

        short8 af[MR], bfv[NR];
        #pragma unroll
        for (int mi = 0; mi < MR; ++mi) {
            const int R = wm + mi * 16 + l15;
            af[mi] = *reinterpret_cast<const short8*>(&As[(R * 4 + (l4 ^ ((R >> 1) & 3))) * 8]);
        }
        #pragma unroll
        for (int ni = 0; ni < NR; ++ni) {
            const int R = wn + ni * 16 + l15;
            bfv[ni] = *reinterpret_cast<const short8*>(&Bs[(R * 4 + (l4 ^ ((R >> 1) & 3))) * 8]);
        }
        #pragma unroll
        for (int mi = 0; mi < MR; ++mi)
            #pragma unroll
            for (int ni = 0; ni < NR; ++ni)
                acc[mi][ni] = __builtin_amdgcn_mfma_f32_16x16x32_bf16(
                    af[mi], bfv[ni], acc[mi][ni], 0, 0, 0);
        __syncthreads();
    }

    // C/D layout: col = lane&15, row = (lane>>4)*4 + reg  (m89/m91)
    #pragma unroll
    for (int mi = 0; mi < MR; ++mi) {
        const int mrow = m0 + wm + mi * 16 + l4 * 4;
        #pragma unroll
        for (int ni = 0; ni < NR; ++ni) {
            const int ncol = n0 + wn + ni * 16 + l15;
            if (ncol >= N) continue;
            #pragma unroll
            for (int r = 0; r < 4; ++r)
                Cw[(size_t)(mrow + r) * ldc + ncol] = acc[mi][ni][r];
        }
    }
}

// ------------------------- reduce NP split-K partials: dst = / += sum(parts)
template <int NP, bool ADD>
__global__ void __launch_bounds__(256) reduce_parts(
    const float* __restrict__ parts, size_t stride,
    float* __restrict__ dst, int count) {
    const int i = (blockIdx.x * 256 + threadIdx.x) * 4;
    if (i >= count) return;
    float4 s = *reinterpret_cast<const float4*>(parts + i);
    #pragma unroll
    for (int p = 1; p < NP; ++p) {
        const float4 v = *reinterpret_cast<const float4*>(parts + (size_t)p * stride + i);
        s.x += v.x; s.y += v.y; s.z += v.z; s.w += v.w;
    }
    float4* d = reinterpret_cast<float4*>(dst + i);
    if (ADD) {
        float4 o = *d;
        o.x += s.x; o.y += s.y; o.z += s.z; o.w += s.w;
        *d = o;
    } else {
        *d = s;
    }
}

// ---------------------------- dt = softplus(proj[:, :48] @ dtw^T + bias)
// fp32-exact, K=48. Block: 256 n-cols x 8 m-rows; dtw tile staged in LDS.
__global__ void __launch_bounds__(256) dt_kernel(
    const float* __restrict__ proj, const float* __restrict__ dtw,
    const float* __restrict__ bias, float* __restrict__ dt) {
    __shared__ float sw[kDtRank][257];
    const int tid = threadIdx.x;
    const int n0 = blockIdx.x * 256;
    const int m0 = blockIdx.y * 8;
    for (int idx = tid; idx < 256 * kDtRank; idx += 256) {
        const int nn = idx / kDtRank, k = idx % kDtRank;
        sw[k][nn] = dtw[(size_t)(n0 + nn) * kDtRank + k];
    }
    __syncthreads();
    const int n = n0 + tid;
    const float b = bias[n];
    #pragma unroll
    for (int mi = 0; mi < 8; ++mi) {
        const float* pr = proj + (size_t)(m0 + mi) * kPLd;
        float acc = b;
        #pragma unroll
        for (int k = 0; k < kDtRank; ++k)
            acc = fmaf(pr[k], sw[k][tid], acc);
        acc = (acc > 20.f) ? acc : log1pf(__expf(acc));  // softplus
        dt[(size_t)(m0 + mi) * kDInner + n] = acc;
    }
}

// ---------------- depthwise causal conv+silu, fused 2-part split-K reduce
__global__ void __launch_bounds__(256) conv_silu_kernel(
    const float* __restrict__ p0, const float* __restrict__ p1,
    const float* __restrict__ cw, const float* __restrict__ cb,
    float* __restrict__ xi, __hip_bfloat16* __restrict__ xi2) {
    const int s = blockIdx.x;
    const int d = blockIdx.y * 256 + threadIdx.x;
    float acc = cb[d];
    #pragma unroll
    for (int k = 0; k < kDConv; ++k) {
        const int sl = s - (kDConv - 1) + k;
        if (sl >= 0) {
            const size_t off = (size_t)sl * (2 * kDInner) + d;
            acc = fmaf(p0[off] + p1[off], cw[d * kDConv + k], acc);
        }
    }
    const float v = silu_f(acc);
    xi[(size_t)s * kDInner + d] = v;
    __hip_bfloat16 hi, lo;
    split_bf16(v, hi, lo);
    __hip_bfloat16* row = xi2 + (size_t)s * 3 * kDInner;
    row[d] = hi; row[kDInner + d] = lo; row[2 * kDInner + d] = hi;
}

// ------------------------------------------------- chunked selective scan
// recurrence: state = state * exp(exp(dt*A)) + dt*u*B ; y = <state,C> + u*Dv
__global__ void __launch_bounds__(256) scan_part1(
    const float* __restrict__ dt, const float* __restrict__ u,
    const float* __restrict__ proj, const float* __restrict__ A_log,
    float* __restrict__ P, float* __restrict__ S) {
    __shared__ float sdt[kCH][16], su[kCH][16], sB[kCH][16];
    const int tid = threadIdx.x;
    const int n = tid & 15, dl = tid >> 4;
    const int d0 = blockIdx.x * 16;
    const int l0 = blockIdx.y * kCH;
    for (int idx = tid; idx < kCH * 16; idx += 256) {
        const int r = idx >> 4, c = idx & 15;
        sdt[r][c] = dt[(size_t)(l0 + r) * kDInner + d0 + c];
        su [r][c] = u [(size_t)(l0 + r) * kDInner + d0 + c];
        sB [r][c] = proj[(size_t)(l0 + r) * kPLd + kDtRank + c];
    }
    __syncthreads();
    const int d = d0 + dl;
    const float Adn = -__expf(A_log[d * kDState + n]);
    float state = 0.f, sumA = 0.f;
    #pragma unroll 8
    for (int l = 0; l < kCH; ++l) {
        const float dtv = sdt[l][dl];
        const float adelta = __expf(dtv * Adn);
        const float mult = __expf(adelta);
        state = fmaf(state, mult, dtv * su[l][dl] * sB[l][n]);
        sumA += adelta;
    }
    const int dn = d * kDState + n;
    P[(size_t)blockIdx.y * kDN + dn] = __expf(sumA);
    S[(size_t)blockIdx.y * kDN + dn] = state;
}

__global__ void __launch_bounds__(256) scan_combine(
    const float* __restrict__ P, const float* __restrict__ S,
    float* __restrict__ SI) {
    const int dn = blockIdx.x * 256 + threadIdx.x;
    float s = 0.f;
    #pragma unroll
    for (int j = 0; j < kNCH; ++j) {
        const size_t idx = (size_t)j * kDN + dn;
        SI[idx] = s;
        s = fmaf(s, P[idx], S[idx]);
    }
}

__global__ void __launch_bounds__(256) scan_part2(
    const float* __restrict__ dt, const float* __restrict__ u,
    const float* __restrict__ proj, const float* __restrict__ A_log,
    const float* __restrict__ D_skip, const float* __restrict__ SI,
    float* __restrict__ y) {
    __shared__ float sdt[kCH][16], su[kCH][16], sB[kCH][16], sC[kCH][16];
    __shared__ float sy[kCH][16];
    const int tid = threadIdx.x;
    const int n = tid & 15, dl = tid >> 4;
    const int d0 = blockIdx.x * 16;
    const int l0 = blockIdx.y * kCH;
    for (int idx = tid; idx < kCH * 16; idx += 256) {
        const int r = idx >> 4, c = idx & 15;
        sdt[r][c] = dt[(size_t)(l0 + r) * kDInner + d0 + c];
        su [r][c] = u [(size_t)(l0 + r) * kDInner + d0 + c];
        sB [r][c] = proj[(size_t)(l0 + r) * kPLd + kDtRank + c];
        sC [r][c] = proj[(size_t)(l0 + r) * kPLd + kDtRank + kDState + c];
    }
    __syncthreads();
    const int d = d0 + dl;
    const float Adn = -__expf(A_log[d * kDState + n]);
    const float Dv  = D_skip[d];
    float state = SI[(size_t)blockIdx.y * kDN + d * kDState + n];
    for (int l = 0; l < kCH; ++l) {
        const float dtv = sdt[l][dl];
        const float uv  = su[l][dl];
        const float mult = __expf(__expf(dtv * Adn));
        state = fmaf(state, mult, dtv * uv * sB[l][n]);
        float contrib = state * sC[l][n];
        contrib += __shfl_xor(contrib, 8);
        contrib += __shfl_xor(contrib, 4);
        contrib += __shfl_xor(contrib, 2);
        contrib += __shfl_xor(contrib, 1);
        if (n == 0) sy[l][dl] = fmaf(uv, Dv, contrib);
    }
    __syncthreads();
    for (int idx = tid; idx < kCH * 16; idx += 256) {
        const int r = idx >> 4, c = idx & 15;
        y[(size_t)(l0 + r) * kDInner + d0 + c] = sy[r][c];
    }
}

// ------------- g = y * silu(res), res summed from 2 partials (split bf16)
__global__ void __launch_bounds__(256) mul_silu_kernel(
    const float* __restrict__ y, const float* __restrict__ p0,
    const float* __restrict__ p1, __hip_bfloat16* __restrict__ g2) {
    const int s = blockIdx.x;
    const int d = blockIdx.y * 256 + threadIdx.x;
    const size_t off = (size_t)s * (2 * kDInner) + kDInner + d;
    const float res = p0[off] + p1[off];
    const float v = y[(size_t)s * kDInner + d] * silu_f(res);
    __hip_bfloat16 hi, lo;
    split_bf16(v, hi, lo);
    __hip_bfloat16* row = g2 + (size_t)s * 3 * kDInner;
    row[d] = hi; row[kDInner + d] = lo; row[2 * kDInner + d] = hi;
}

}  // namespace

extern "C" void kernel_launch(void* const* d_in, const int* in_sizes, int n_in,
                              void* d_out, int out_size, void* d_ws, size_t ws_size,
                              hipStream_t stream) {
    const int*   tokens       = (const int*)d_in[0];
    const float* embedding    = (const float*)d_in[1];
    const float* norm_w       = (const float*)d_in[2];
    const float* in_proj_w    = (const float*)d_in[3];
    const float* conv_w       = (const float*)d_in[4];
    const float* conv_b       = (const float*)d_in[5];
    const float* x_proj_w     = (const float*)d_in[6];
    const float* dt_proj_w    = (const float*)d_in[7];
    const float* dt_proj_b    = (const float*)d_in[8];
    const float* A_log        = (const float*)d_in[9];
    const float* D_skip       = (const float*)d_in[10];
    const float* out_proj_w   = (const float*)d_in[11];
    const float* final_norm_w = (const float*)d_in[12];
    float* out = (float*)d_out;

    constexpr int K3m = 3 * kDModel;   // 2304
    constexpr int K3i = 3 * kDInner;   // 4608

    char* ws = (char*)d_ws;
    auto alloc = [&](size_t bytes) { char* p = ws; ws += (bytes + 255) & ~(size_t)255; return p; };
    float* x    = (float*)alloc((size_t)kSeq * kDModel * 4);
    float* xi   = (float*)alloc((size_t)kSeq * kDInner * 4);
    float* proj = (float*)alloc((size_t)kSeq * kPLd * 4);
    float* dt   = (float*)alloc((size_t)kSeq * kDInner * 4);
    float* y    = (float*)alloc((size_t)kSeq * kDInner * 4);
    float* scanP  = (float*)alloc((size_t)kNCH * kDN * 4);
    float* scanS  = (float*)alloc((size_t)kNCH * kDN * 4);
    float* scanSI = (float*)alloc((size_t)kNCH * kDN * 4);
    float* partsXZ = (float*)alloc((size_t)2 * kSeq * 2 * kDInner * 4);  // in_proj partials (live to mul_silu)
    float* partsP  = (float*)alloc((size_t)8 * kSeq * kPLd * 4);         // x_proj partials
    float* partsO  = (float*)alloc((size_t)4 * kSeq * kDModel * 4);      // out_proj partials
    __hip_bfloat16* h_bf   = (__hip_bfloat16*)alloc((size_t)kSeq * kDModel * 2);
    __hip_bfloat16* h2     = (__hip_bfloat16*)alloc((size_t)kSeq * K3m * 2);
    __hip_bfloat16* xi2    = (__hip_bfloat16*)alloc((size_t)kSeq * K3i * 2);
    __hip_bfloat16* g2     = (__hip_bfloat16*)alloc((size_t)kSeq * K3i * 2);
    __hip_bfloat16* emb_bf = (__hip_bfloat16*)alloc((size_t)kVocab * kDModel * 2);
    __hip_bfloat16* inw2   = (__hip_bfloat16*)alloc((size_t)kL * 2 * kDInner * K3m * 2);
    __hip_bfloat16* outw2  = (__hip_bfloat16*)alloc((size_t)kL * kDModel * K3i * 2);
    __hip_bfloat16* xw2    = (__hip_bfloat16*)alloc((size_t)kL * kPLd * K3i * 2);

    // ---- weight conversions (per call; layer dims are contiguous) ----
    f2b_kernel<<<4096, 256, 0, stream>>>(embedding, emb_bf, kVocab * kDModel);
    split3_kernel<<<(kL * 2 * kDInner * kDModel + 255) / 256, 256, 0, stream>>>(
        in_proj_w, kDModel, kL * 2 * kDInner, kDModel, inw2, kL * 2 * kDInner);
    split3_kernel<<<(kL * kDModel * kDInner + 255) / 256, 256, 0, stream>>>(
        out_proj_w, kDInner, kL * kDModel, kDInner, outw2, kL * kDModel);
    for (int i = 0; i < kL; ++i)
        split3_kernel<<<(kPLd * kDInner + 255) / 256, 256, 0, stream>>>(
            x_proj_w + (size_t)i * (kDtRank + 2 * kDState) * kDInner, kDInner,
            kDtRank + 2 * kDState, kDInner, xw2 + (size_t)i * kPLd * K3i, kPLd);

    embed_kernel<<<kSeq, 256, 0, stream>>>(tokens, embedding, x);

    for (int i = 0; i < kL; ++i) {
        rmsnorm_kernel<true><<<kSeq, 256, 0, stream>>>(x, norm_w + (size_t)i * kDModel, h2);

        // xz partials = h @ in_proj_w[i]^T  (1024 x 3072, K=2304, KSPLIT=2)
        mfma_gemm<128, 128, 2><<<dim3(kSeq / 128, 2 * kDInner / 128, 2), 256, 0, stream>>>(
            h2, K3m, inw2 + (size_t)i * 2 * kDInner * K3m, K3m,
            partsXZ, 2 * kDInner, 2 * kDInner, K3m, (size_t)kSeq * 2 * kDInner);

        // xi = silu(conv(sum(parts)[:, :1536]) + b)   (reduce fused)
        conv_silu_kernel<<<dim3(kSeq, kDInner / 256), 256, 0, stream>>>(
            partsXZ, partsXZ + (size_t)kSeq * 2 * kDInner,
            conv_w + (size_t)i * kDInner * kDConv, conv_b + (size_t)i * kDInner,
            xi, xi2);

        // proj = xi @ x_proj_w[i]^T   (1024 x 96pad, K=4608, KSPLIT=8)
        mfma_gemm<128, 96, 8><<<dim3(kSeq / 128, 1, 8), 256, 0, stream>>>(
            xi2, K3i, xw2 + (size_t)i * kPLd * K3i, K3i,
            partsP, kPLd, kPLd, K3i, (size_t)kSeq * kPLd);
        reduce_parts<8, false><<<(kSeq * kPLd / 4 + 255) / 256, 256, 0, stream>>>(
            partsP, (size_t)kSeq * kPLd, proj, kSeq * kPLd);

        // dt = softplus(proj[:, :48] @ dt_proj_w^T + b)  -- fp32 exact
        dt_kernel<<<dim3(kDInner / 256, kSeq / 8), 256, 0, stream>>>(
            proj, dt_proj_w + (size_t)i * kDInner * kDtRank,
            dt_proj_b + (size_t)i * kDInner, dt);

        // y = selective_scan(xi, dt, A, B, C, D) — chunked 3-phase
        const float* A_l = A_log + (size_t)i * kDInner * kDState;
        scan_part1<<<dim3(kDInner / 16, kNCH), 256, 0, stream>>>(
            dt, xi, proj, A_l, scanP, scanS);
        scan_combine<<<kDN / 256, 256, 0, stream>>>(scanP, scanS, scanSI);
        scan_part2<<<dim3(kDInner / 16, kNCH), 256, 0, stream>>>(
            dt, xi, proj, A_l, D_skip + (size_t)i * kDInner, scanSI, y);

        // g = y * silu(res)   (res reduce fused)
        mul_silu_kernel<<<dim3(kSeq, kDInner / 256), 256, 0, stream>>>(
            y, partsXZ, partsXZ + (size_t)kSeq * 2 * kDInner, g2);

        // x += g @ out_proj_w[i]^T   (1024 x 768, K=4608, KSPLIT=4)
        mfma_gemm<128, 128, 4><<<dim3(kSeq / 128, kDModel / 128, 4), 256, 0, stream>>>(
            g2, K3i, outw2 + (size_t)i * kDModel * K3i, K3i,
            partsO, kDModel, kDModel, K3i, (size_t)kSeq * kDModel);
        reduce_parts<4, true><<<(kSeq * kDModel / 4 + 255) / 256, 256, 0, stream>>>(
            partsO, (size_t)kSeq * kDModel, x, kSeq * kDModel);
    }

    // out = rmsnorm(x, final_norm_w) @ embedding^T   (1024 x 32000, K=768)
    rmsnorm_kernel<false><<<kSeq, 256, 0, stream>>>(x, final_norm_w, h_bf);
    mfma_gemm<128, 128, 1><<<dim3(kSeq / 128, kVocab / 128, 1), 256, 0, stream>>>(
        h_bf, kDModel, emb_bf, kDModel, out, kVocab, kVocab, kDModel, 0);
}

// Round 7
// 851.696 us; speedup vs baseline: 5.9847x; 1.0580x over previous
//
#include <hip/hip_runtime.h>
#include <hip/hip_bf16.h>
#include <cmath>

namespace {

constexpr int kL      = 4;
constexpr int kDModel = 768;
constexpr int kDInner = 1536;
constexpr int kDtRank = 48;
constexpr int kDState = 16;
constexpr int kDConv  = 4;
constexpr int kSeq    = 1024;
constexpr int kPLd    = 96;    // proj row stride (80 used)
constexpr int kPB     = 128;   // x_proj weight rows padded for BN=128
constexpr int kVocab  = 32000;
constexpr int kCH     = 64;    // scan chunk length
constexpr int kNCH    = kSeq / kCH;  // 16 chunks
constexpr int kDN     = kDInner * kDState;  // 24576 (d,n) pairs

using short8 = __attribute__((ext_vector_type(8))) short;
using f32x4  = __attribute__((ext_vector_type(4))) float;

__device__ __forceinline__ float silu_f(float v) {
    return v / (1.f + __expf(-v));
}

__device__ __forceinline__ void split_bf16(float v, __hip_bfloat16& hi, __hip_bfloat16& lo) {
    hi = __float2bfloat16(v);
    lo = __float2bfloat16(v - __bfloat162float(hi));
}

// ---------------------------------------------------------------- fp32->bf16
__global__ void __launch_bounds__(256) f2b_kernel(
    const float* __restrict__ src, __hip_bfloat16* __restrict__ dst, int n) {
    int i = (blockIdx.x * 256 + threadIdx.x) * 4;
    const int stride = gridDim.x * 256 * 4;
    for (; i + 3 < n; i += stride) {
        const float4 v = *reinterpret_cast<const float4*>(src + i);
        dst[i + 0] = __float2bfloat16(v.x);
        dst[i + 1] = __float2bfloat16(v.y);
        dst[i + 2] = __float2bfloat16(v.z);
        dst[i + 3] = __float2bfloat16(v.w);
    }
}

// -------------------------------- fp32 -> 3-term split bf16 along K
// B-side: dst row = [hi | hi | lo]; rows >= `rows` zero-filled.
__global__ void __launch_bounds__(256) split3_kernel(
    const float* __restrict__ src, int ldsrc, int rows, int cols,
    __hip_bfloat16* __restrict__ dst, int rowsPad) {
    const int idx = blockIdx.x * 256 + threadIdx.x;
    if (idx >= rowsPad * cols) return;
    const int r = idx / cols, c = idx % cols;
    const float v = (r < rows) ? src[(size_t)r * ldsrc + c] : 0.f;
    __hip_bfloat16 hi, lo;
    split_bf16(v, hi, lo);
    __hip_bfloat16* row = dst + (size_t)r * 3 * cols;
    row[c] = hi; row[cols + c] = hi; row[2 * cols + c] = lo;
}

// ---------------------------------------------------------------- embedding
__global__ void __launch_bounds__(256) embed_kernel(
    const int* __restrict__ tokens, const float* __restrict__ emb,
    float* __restrict__ x) {
    const int s = blockIdx.x;
    const int t = tokens[s];
    const float* src = emb + (size_t)t * kDModel;
    float* dst = x + (size_t)s * kDModel;
    for (int d = threadIdx.x; d < kDModel; d += blockDim.x) dst[d] = src[d];
}

// ----------------------------------- rmsnorm -> bf16 (plain or 3-term split)
template <bool SPLIT>
__global__ void __launch_bounds__(256) rmsnorm_kernel(
    const float* __restrict__ x, const float* __restrict__ w,
    __hip_bfloat16* __restrict__ out) {
    const int s = blockIdx.x;
    const float* row = x + (size_t)s * kDModel;
    float ss = 0.f;
    for (int d = threadIdx.x; d < kDModel; d += blockDim.x) {
        const float v = row[d];
        ss = fmaf(v, v, ss);
    }
    #pragma unroll
    for (int m = 32; m; m >>= 1) ss += __shfl_xor(ss, m);
    __shared__ float red[4];
    if ((threadIdx.x & 63) == 0) red[threadIdx.x >> 6] = ss;
    __syncthreads();
    const float total = red[0] + red[1] + red[2] + red[3];
    const float scale = rsqrtf(total / (float)kDModel + 1e-5f);
    __hip_bfloat16* dst = out + (size_t)s * (SPLIT ? 3 * kDModel : kDModel);
    for (int d = threadIdx.x; d < kDModel; d += blockDim.x) {
        const float v = row[d] * scale * w[d];
        if (SPLIT) {
            __hip_bfloat16 hi, lo;
            split_bf16(v, hi, lo);
            dst[d] = hi; dst[kDModel + d] = lo; dst[2 * kDModel + d] = hi;
        } else {
            dst[d] = __float2bfloat16(v);
        }
    }
}

// ---------------------------------------------------------------- MFMA GEMM
// C[m][n] = sum_{k in split part} A[m][k]*B[n][k].  A: MxK bf16, B: NxK bf16.
// 2-phase double-buffered pipeline (T3-min): prefetch STAGE(t+1) before
// compute(t); raw s_barrier + counted vmcnt(4) keeps next tile's loads in
// flight across the MFMA phase. Granule swizzle (bank-conflict-free) + XCD
// swizzle (L2 panel reuse) as verified in round 6.
template <int BM, int BN, int KSPLIT>
__global__ void __launch_bounds__(256) mfma_gemm(
    const __hip_bfloat16* __restrict__ A, int lda,
    const __hip_bfloat16* __restrict__ B, int ldb,
    float* __restrict__ C, int ldc,
    int N, int K, size_t partStride) {
    constexpr int BK = 32;
    static_assert(BM == 128 && BN == 128, "staging assumes 128x128");
    __shared__ unsigned short As[2][BM * BK];
    __shared__ unsigned short Bs[2][BN * BK];
    const int tid  = threadIdx.x;
    const int lane = tid & 63;

    // ---- bijective chunked XCD swizzle (m204) over the (x,y) grid ----
    const int nwg = gridDim.x * gridDim.y;
    int bid = blockIdx.y * gridDim.x + blockIdx.x;
    {
        const int q = nwg >> 3, r = nwg & 7;
        const int xcd = bid & 7, pos = bid >> 3;
        bid = (xcd < r ? xcd * (q + 1) : r * (q + 1) + (xcd - r) * q) + pos;
    }
    const int m0 = (bid % gridDim.x) * BM;   // m fast: same-n blocks adjacent
    const int n0 = (bid / gridDim.x) * BN;

    const int Kp = K / KSPLIT;
    const int kbeg = (KSPLIT > 1) ? blockIdx.z * Kp : 0;
    float* Cw = (KSPLIT > 1) ? C + (size_t)blockIdx.z * partStride : C;
    constexpr int WM = BM / 2, WN = BN / 2;   // 2x2 waves
    constexpr int MR = WM / 16, NR = WN / 16;
    const int wave = tid >> 6;
    const int wm = (wave >> 1) * WM, wn = (wave & 1) * WN;
    const int l15 = lane & 15, l4 = lane >> 4;
    f32x4 acc[MR][NR] = {};

    // stage one K-tile into buffer `buf` (4 gload_lds per thread, uniform)
    auto stage = [&](int buf, int k0) {
        #pragma unroll
        for (int i = 0; i < 2; ++i) {
            const int idx = tid + i * 256;           // A: BM*4 = 512 granules
            const int r = idx >> 2, qv = idx & 3;
            const int qs = qv ^ ((r >> 1) & 3);
            __builtin_amdgcn_global_load_lds(
                (const __attribute__((address_space(1))) void*)(A + (size_t)(m0 + r) * lda + k0 + qs * 8),
                (__attribute__((address_space(3))) void*)(&As[buf][(idx - lane) * 8]),
                16, 0, 0);
        }
        #pragma unroll
        for (int i = 0; i < 2; ++i) {
            const int idx = tid + i * 256;           // B: BN*4 = 512 granules
            const int r = idx >> 2, qv = idx & 3;
            const int qs = qv ^ ((r >> 1) & 3);
            __builtin_amdgcn_global_load_lds(
                (const __attribute__((address_space(1))) void*)(B + (size_t)(n0 + r) * ldb + k0 + qs * 8),
                (__attribute__((address_space(3))) void*)(&Bs[buf][(idx - lane) * 8]),
                16, 0, 0);
        }
    };

    const int nt = Kp / BK;
    int cur = 0;
    stage(0, kbeg);
    for (int t = 0; t < nt; ++t) {
        if (t + 1 < nt) {
            stage(cur ^ 1, kbeg + (t + 1) * BK);
            asm volatile("s_waitcnt vmcnt(4)" ::: "memory");  // cur landed; next in flight
        } else {
            asm volatile("s_waitcnt vmcnt(0)" ::: "memory");
        }
        __builtin_amdgcn_s_barrier();

        short8 af[MR], bfv[NR];
        #pragma unroll
        for (int mi = 0; mi < MR; ++mi) {
            const int R = wm + mi * 16 + l15;
            af[mi] = *reinterpret_cast<const short8*>(&As[cur][(R * 4 + (l4 ^ ((R >> 1) & 3))) * 8]);
        }
        #pragma unroll
        for (int ni = 0; ni < NR; ++ni) {
            const int R = wn + ni * 16 + l15;
            bfv[ni] = *reinterpret_cast<const short8*>(&Bs[cur][(R * 4 + (l4 ^ ((R >> 1) & 3))) * 8]);
        }
        #pragma unroll
        for (int mi = 0; mi < MR; ++mi)
            #pragma unroll
            for (int ni = 0; ni < NR; ++ni)
                acc[mi][ni] = __builtin_amdgcn_mfma_f32_16x16x32_bf16(
                    af[mi], bfv[ni], acc[mi][ni], 0, 0, 0);

        asm volatile("s_waitcnt lgkmcnt(0)" ::: "memory");
        __builtin_amdgcn_s_barrier();                // safe to overwrite cur
        cur ^= 1;
    }

    // C/D layout: col = lane&15, row = (lane>>4)*4 + reg  (m89/m91)
    #pragma unroll
    for (int mi = 0; mi < MR; ++mi) {
        const int mrow = m0 + wm + mi * 16 + l4 * 4;
        #pragma unroll
        for (int ni = 0; ni < NR; ++ni) {
            const int ncol = n0 + wn + ni * 16 + l15;
            if (ncol >= N) continue;
            #pragma unroll
            for (int r = 0; r < 4; ++r)
                Cw[(size_t)(mrow + r) * ldc + ncol] = acc[mi][ni][r];
        }
    }
}

// ------------------------- reduce NP split-K partials: dst = / += sum(parts)
template <int NP, bool ADD>
__global__ void __launch_bounds__(256) reduce_parts(
    const float* __restrict__ parts, size_t stride,
    float* __restrict__ dst, int count) {
    const int i = (blockIdx.x * 256 + threadIdx.x) * 4;
    if (i >= count) return;
    float4 s = *reinterpret_cast<const float4*>(parts + i);
    #pragma unroll
    for (int p = 1; p < NP; ++p) {
        const float4 v = *reinterpret_cast<const float4*>(parts + (size_t)p * stride + i);
        s.x += v.x; s.y += v.y; s.z += v.z; s.w += v.w;
    }
    float4* d = reinterpret_cast<float4*>(dst + i);
    if (ADD) {
        float4 o = *d;
        o.x += s.x; o.y += s.y; o.z += s.z; o.w += s.w;
        *d = o;
    } else {
        *d = s;
    }
}

// ---------------------------- dt = softplus(proj[:, :48] @ dtw^T + bias)
// fp32-exact, K=48. Block: 256 n-cols x 8 m-rows; dtw tile staged in LDS.
__global__ void __launch_bounds__(256) dt_kernel(
    const float* __restrict__ proj, const float* __restrict__ dtw,
    const float* __restrict__ bias, float* __restrict__ dt) {
    __shared__ float sw[kDtRank][257];
    const int tid = threadIdx.x;
    const int n0 = blockIdx.x * 256;
    const int m0 = blockIdx.y * 8;
    for (int idx = tid; idx < 256 * kDtRank; idx += 256) {
        const int nn = idx / kDtRank, k = idx % kDtRank;
        sw[k][nn] = dtw[(size_t)(n0 + nn) * kDtRank + k];
    }
    __syncthreads();
    const int n = n0 + tid;
    const float b = bias[n];
    #pragma unroll
    for (int mi = 0; mi < 8; ++mi) {
        const float* pr = proj + (size_t)(m0 + mi) * kPLd;
        float acc = b;
        #pragma unroll
        for (int k = 0; k < kDtRank; ++k)
            acc = fmaf(pr[k], sw[k][tid], acc);
        acc = (acc > 20.f) ? acc : log1pf(__expf(acc));  // softplus
        dt[(size_t)(m0 + mi) * kDInner + n] = acc;
    }
}

// ---------------- depthwise causal conv+silu, fused 2-part split-K reduce
__global__ void __launch_bounds__(256) conv_silu_kernel(
    const float* __restrict__ p0, const float* __restrict__ p1,
    const float* __restrict__ cw, const float* __restrict__ cb,
    float* __restrict__ xi, __hip_bfloat16* __restrict__ xi2) {
    const int s = blockIdx.x;
    const int d = blockIdx.y * 256 + threadIdx.x;
    float acc = cb[d];
    #pragma unroll
    for (int k = 0; k < kDConv; ++k) {
        const int sl = s - (kDConv - 1) + k;
        if (sl >= 0) {
            const size_t off = (size_t)sl * (2 * kDInner) + d;
            acc = fmaf(p0[off] + p1[off], cw[d * kDConv + k], acc);
        }
    }
    const float v = silu_f(acc);
    xi[(size_t)s * kDInner + d] = v;
    __hip_bfloat16 hi, lo;
    split_bf16(v, hi, lo);
    __hip_bfloat16* row = xi2 + (size_t)s * 3 * kDInner;
    row[d] = hi; row[kDInner + d] = lo; row[2 * kDInner + d] = hi;
}

// ------------------------------------------------- chunked selective scan
// recurrence: state = state * exp(exp(dt*A)) + dt*u*B ; y = <state,C> + u*Dv
__global__ void __launch_bounds__(256) scan_part1(
    const float* __restrict__ dt, const float* __restrict__ u,
    const float* __restrict__ proj, const float* __restrict__ A_log,
    float* __restrict__ P, float* __restrict__ S) {
    __shared__ float sdt[kCH][16], su[kCH][16], sB[kCH][16];
    const int tid = threadIdx.x;
    const int n = tid & 15, dl = tid >> 4;
    const int d0 = blockIdx.x * 16;
    const int l0 = blockIdx.y * kCH;
    for (int idx = tid; idx < kCH * 16; idx += 256) {
        const int r = idx >> 4, c = idx & 15;
        sdt[r][c] = dt[(size_t)(l0 + r) * kDInner + d0 + c];
        su [r][c] = u [(size_t)(l0 + r) * kDInner + d0 + c];
        sB [r][c] = proj[(size_t)(l0 + r) * kPLd + kDtRank + c];
    }
    __syncthreads();
    const int d = d0 + dl;
    const float Adn = -__expf(A_log[d * kDState + n]);
    float state = 0.f, sumA = 0.f;
    #pragma unroll 8
    for (int l = 0; l < kCH; ++l) {
        const float dtv = sdt[l][dl];
        const float adelta = __expf(dtv * Adn);
        const float mult = __expf(adelta);
        state = fmaf(state, mult, dtv * su[l][dl] * sB[l][n]);
        sumA += adelta;
    }
    const int dn = d * kDState + n;
    P[(size_t)blockIdx.y * kDN + dn] = __expf(sumA);
    S[(size_t)blockIdx.y * kDN + dn] = state;
}

__global__ void __launch_bounds__(256) scan_combine(
    const float* __restrict__ P, const float* __restrict__ S,
    float* __restrict__ SI) {
    const int dn = blockIdx.x * 256 + threadIdx.x;
    float s = 0.f;
    #pragma unroll
    for (int j = 0; j < kNCH; ++j) {
        const size_t idx = (size_t)j * kDN + dn;
        SI[idx] = s;
        s = fmaf(s, P[idx], S[idx]);
    }
}

__global__ void __launch_bounds__(256) scan_part2(
    const float* __restrict__ dt, const float* __restrict__ u,
    const float* __restrict__ proj, const float* __restrict__ A_log,
    const float* __restrict__ D_skip, const float* __restrict__ SI,
    float* __restrict__ y) {
    __shared__ float sdt[kCH][16], su[kCH][16], sB[kCH][16], sC[kCH][16];
    __shared__ float sy[kCH][16];
    const int tid = threadIdx.x;
    const int n = tid & 15, dl = tid >> 4;
    const int d0 = blockIdx.x * 16;
    const int l0 = blockIdx.y * kCH;
    for (int idx = tid; idx < kCH * 16; idx += 256) {
        const int r = idx >> 4, c = idx & 15;
        sdt[r][c] = dt[(size_t)(l0 + r) * kDInner + d0 + c];
        su [r][c] = u [(size_t)(l0 + r) * kDInner + d0 + c];
        sB [r][c] = proj[(size_t)(l0 + r) * kPLd + kDtRank + c];
        sC [r][c] = proj[(size_t)(l0 + r) * kPLd + kDtRank + kDState + c];
    }
    __syncthreads();
    const int d = d0 + dl;
    const float Adn = -__expf(A_log[d * kDState + n]);
    const float Dv  = D_skip[d];
    float state = SI[(size_t)blockIdx.y * kDN + d * kDState + n];
    for (int l = 0; l < kCH; ++l) {
        const float dtv = sdt[l][dl];
        const float uv  = su[l][dl];
        const float mult = __expf(__expf(dtv * Adn));
        state = fmaf(state, mult, dtv * uv * sB[l][n]);
        float contrib = state * sC[l][n];
        contrib += __shfl_xor(contrib, 8);
        contrib += __shfl_xor(contrib, 4);
        contrib += __shfl_xor(contrib, 2);
        contrib += __shfl_xor(contrib, 1);
        if (n == 0) sy[l][dl] = fmaf(uv, Dv, contrib);
    }
    __syncthreads();
    for (int idx = tid; idx < kCH * 16; idx += 256) {
        const int r = idx >> 4, c = idx & 15;
        y[(size_t)(l0 + r) * kDInner + d0 + c] = sy[r][c];
    }
}

// ------------- g = y * silu(res), res summed from 2 partials (split bf16)
__global__ void __launch_bounds__(256) mul_silu_kernel(
    const float* __restrict__ y, const float* __restrict__ p0,
    const float* __restrict__ p1, __hip_bfloat16* __restrict__ g2) {
    const int s = blockIdx.x;
    const int d = blockIdx.y * 256 + threadIdx.x;
    const size_t off = (size_t)s * (2 * kDInner) + kDInner + d;
    const float res = p0[off] + p1[off];
    const float v = y[(size_t)s * kDInner + d] * silu_f(res);
    __hip_bfloat16 hi, lo;
    split_bf16(v, hi, lo);
    __hip_bfloat16* row = g2 + (size_t)s * 3 * kDInner;
    row[d] = hi; row[kDInner + d] = lo; row[2 * kDInner + d] = hi;
}

}  // namespace

extern "C" void kernel_launch(void* const* d_in, const int* in_sizes, int n_in,
                              void* d_out, int out_size, void* d_ws, size_t ws_size,
                              hipStream_t stream) {
    const int*   tokens       = (const int*)d_in[0];
    const float* embedding    = (const float*)d_in[1];
    const float* norm_w       = (const float*)d_in[2];
    const float* in_proj_w    = (const float*)d_in[3];
    const float* conv_w       = (const float*)d_in[4];
    const float* conv_b       = (const float*)d_in[5];
    const float* x_proj_w     = (const float*)d_in[6];
    const float* dt_proj_w    = (const float*)d_in[7];
    const float* dt_proj_b    = (const float*)d_in[8];
    const float* A_log        = (const float*)d_in[9];
    const float* D_skip       = (const float*)d_in[10];
    const float* out_proj_w   = (const float*)d_in[11];
    const float* final_norm_w = (const float*)d_in[12];
    float* out = (float*)d_out;

    constexpr int K3m = 3 * kDModel;   // 2304
    constexpr int K3i = 3 * kDInner;   // 4608

    char* ws = (char*)d_ws;
    auto alloc = [&](size_t bytes) { char* p = ws; ws += (bytes + 255) & ~(size_t)255; return p; };
    float* x    = (float*)alloc((size_t)kSeq * kDModel * 4);
    float* xi   = (float*)alloc((size_t)kSeq * kDInner * 4);
    float* proj = (float*)alloc((size_t)kSeq * kPLd * 4);
    float* dt   = (float*)alloc((size_t)kSeq * kDInner * 4);
    float* y    = (float*)alloc((size_t)kSeq * kDInner * 4);
    float* scanP  = (float*)alloc((size_t)kNCH * kDN * 4);
    float* scanS  = (float*)alloc((size_t)kNCH * kDN * 4);
    float* scanSI = (float*)alloc((size_t)kNCH * kDN * 4);
    float* partsXZ = (float*)alloc((size_t)2 * kSeq * 2 * kDInner * 4);  // in_proj partials (live to mul_silu)
    float* partsP  = (float*)alloc((size_t)16 * kSeq * kPLd * 4);        // x_proj partials
    float* partsO  = (float*)alloc((size_t)4 * kSeq * kDModel * 4);      // out_proj partials
    __hip_bfloat16* h_bf   = (__hip_bfloat16*)alloc((size_t)kSeq * kDModel * 2);
    __hip_bfloat16* h2     = (__hip_bfloat16*)alloc((size_t)kSeq * K3m * 2);
    __hip_bfloat16* xi2    = (__hip_bfloat16*)alloc((size_t)kSeq * K3i * 2);
    __hip_bfloat16* g2     = (__hip_bfloat16*)alloc((size_t)kSeq * K3i * 2);
    __hip_bfloat16* emb_bf = (__hip_bfloat16*)alloc((size_t)kVocab * kDModel * 2);
    __hip_bfloat16* inw2   = (__hip_bfloat16*)alloc((size_t)kL * 2 * kDInner * K3m * 2);
    __hip_bfloat16* outw2  = (__hip_bfloat16*)alloc((size_t)kL * kDModel * K3i * 2);
    __hip_bfloat16* xw2    = (__hip_bfloat16*)alloc((size_t)kL * kPB * K3i * 2);

    // ---- weight conversions (per call; layer dims are contiguous) ----
    f2b_kernel<<<4096, 256, 0, stream>>>(embedding, emb_bf, kVocab * kDModel);
    split3_kernel<<<(kL * 2 * kDInner * kDModel + 255) / 256, 256, 0, stream>>>(
        in_proj_w, kDModel, kL * 2 * kDInner, kDModel, inw2, kL * 2 * kDInner);
    split3_kernel<<<(kL * kDModel * kDInner + 255) / 256, 256, 0, stream>>>(
        out_proj_w, kDInner, kL * kDModel, kDInner, outw2, kL * kDModel);
    for (int i = 0; i < kL; ++i)
        split3_kernel<<<(kPB * kDInner + 255) / 256, 256, 0, stream>>>(
            x_proj_w + (size_t)i * (kDtRank + 2 * kDState) * kDInner, kDInner,
            kDtRank + 2 * kDState, kDInner, xw2 + (size_t)i * kPB * K3i, kPB);

    embed_kernel<<<kSeq, 256, 0, stream>>>(tokens, embedding, x);

    for (int i = 0; i < kL; ++i) {
        rmsnorm_kernel<true><<<kSeq, 256, 0, stream>>>(x, norm_w + (size_t)i * kDModel, h2);

        // xz partials = h @ in_proj_w[i]^T  (1024 x 3072, K=2304, KSPLIT=2)
        mfma_gemm<128, 128, 2><<<dim3(kSeq / 128, 2 * kDInner / 128, 2), 256, 0, stream>>>(
            h2, K3m, inw2 + (size_t)i * 2 * kDInner * K3m, K3m,
            partsXZ, 2 * kDInner, 2 * kDInner, K3m, (size_t)kSeq * 2 * kDInner);

        // xi = silu(conv(sum(parts)[:, :1536]) + b)   (reduce fused)
        conv_silu_kernel<<<dim3(kSeq, kDInner / 256), 256, 0, stream>>>(
            partsXZ, partsXZ + (size_t)kSeq * 2 * kDInner,
            conv_w + (size_t)i * kDInner * kDConv, conv_b + (size_t)i * kDInner,
            xi, xi2);

        // proj = xi @ x_proj_w[i]^T   (1024 x 128pad, K=4608, KSPLIT=16)
        mfma_gemm<128, 128, 16><<<dim3(kSeq / 128, 1, 16), 256, 0, stream>>>(
            xi2, K3i, xw2 + (size_t)i * kPB * K3i, K3i,
            partsP, kPLd, kPLd, K3i, (size_t)kSeq * kPLd);
        reduce_parts<16, false><<<(kSeq * kPLd / 4 + 255) / 256, 256, 0, stream>>>(
            partsP, (size_t)kSeq * kPLd, proj, kSeq * kPLd);

        // dt = softplus(proj[:, :48] @ dt_proj_w^T + b)  -- fp32 exact
        dt_kernel<<<dim3(kDInner / 256, kSeq / 8), 256, 0, stream>>>(
            proj, dt_proj_w + (size_t)i * kDInner * kDtRank,
            dt_proj_b + (size_t)i * kDInner, dt);

        // y = selective_scan(xi, dt, A, B, C, D) — chunked 3-phase
        const float* A_l = A_log + (size_t)i * kDInner * kDState;
        scan_part1<<<dim3(kDInner / 16, kNCH), 256, 0, stream>>>(
            dt, xi, proj, A_l, scanP, scanS);
        scan_combine<<<kDN / 256, 256, 0, stream>>>(scanP, scanS, scanSI);
        scan_part2<<<dim3(kDInner / 16, kNCH), 256, 0, stream>>>(
            dt, xi, proj, A_l, D_skip + (size_t)i * kDInner, scanSI, y);

        // g = y * silu(res)   (res reduce fused)
        mul_silu_kernel<<<dim3(kSeq, kDInner / 256), 256, 0, stream>>>(
            y, partsXZ, partsXZ + (size_t)kSeq * 2 * kDInner, g2);

        // x += g @ out_proj_w[i]^T   (1024 x 768, K=4608, KSPLIT=4)
        mfma_gemm<128, 128, 4><<<dim3(kSeq / 128, kDModel / 128, 4), 256, 0, stream>>>(
            g2, K3i, outw2 + (size_t)i * kDModel * K3i, K3i,
            partsO, kDModel, kDModel, K3i, (size_t)kSeq * kDModel);
        reduce_parts<4, true><<<(kSeq * kDModel / 4 + 255) / 256, 256, 0, stream>>>(
            partsO, (size_t)kSeq * kDModel, x, kSeq * kDModel);
    }

    // out = rmsnorm(x, final_norm_w) @ embedding^T   (1024 x 32000, K=768)
    rmsnorm_kernel<false><<<kSeq, 256, 0, stream>>>(x, final_norm_w, h_bf);
    mfma_gemm<128, 128, 1><<<dim3(kSeq / 128, kVocab / 128, 1), 256, 0, stream>>>(
        h_bf, kDModel, emb_bf, kDModel, out, kVocab, kVocab, kDModel, 0);
}

// Round 8
// 822.522 us; speedup vs baseline: 6.1970x; 1.0355x over previous
//
#include <hip/hip_runtime.h>
#include <hip/hip_bf16.h>
#include <cmath>

namespace {

constexpr int kL      = 4;
constexpr int kDModel = 768;
constexpr int kDInner = 1536;
constexpr int kDtRank = 48;
constexpr int kDState = 16;
constexpr int kDConv  = 4;
constexpr int kSeq    = 1024;
constexpr int kPLd    = 96;    // proj row stride (80 used)
constexpr int kPB     = 128;   // x_proj weight rows padded for BN=128
constexpr int kVocab  = 32000;
constexpr int kCH     = 64;    // scan chunk length
constexpr int kNCH    = kSeq / kCH;  // 16 chunks
constexpr int kDN     = kDInner * kDState;  // 24576 (d,n) pairs

using short8 = __attribute__((ext_vector_type(8))) short;
using f32x4  = __attribute__((ext_vector_type(4))) float;

__device__ __forceinline__ float silu_f(float v) {
    return v / (1.f + __expf(-v));
}

__device__ __forceinline__ void split_bf16(float v, __hip_bfloat16& hi, __hip_bfloat16& lo) {
    hi = __float2bfloat16(v);
    lo = __float2bfloat16(v - __bfloat162float(hi));
}

// ---------------------------------------------------------------- fp32->bf16
__global__ void __launch_bounds__(256) f2b_kernel(
    const float* __restrict__ src, __hip_bfloat16* __restrict__ dst, int n) {
    int i = (blockIdx.x * 256 + threadIdx.x) * 4;
    const int stride = gridDim.x * 256 * 4;
    for (; i + 3 < n; i += stride) {
        const float4 v = *reinterpret_cast<const float4*>(src + i);
        dst[i + 0] = __float2bfloat16(v.x);
        dst[i + 1] = __float2bfloat16(v.y);
        dst[i + 2] = __float2bfloat16(v.z);
        dst[i + 3] = __float2bfloat16(v.w);
    }
}

// -------------------------------- fp32 -> 3-term split bf16 along K
// B-side: dst row = [hi | hi | lo]; rows >= `rows` zero-filled.
__global__ void __launch_bounds__(256) split3_kernel(
    const float* __restrict__ src, int ldsrc, int rows, int cols,
    __hip_bfloat16* __restrict__ dst, int rowsPad) {
    const int idx = blockIdx.x * 256 + threadIdx.x;
    if (idx >= rowsPad * cols) return;
    const int r = idx / cols, c = idx % cols;
    const float v = (r < rows) ? src[(size_t)r * ldsrc + c] : 0.f;
    __hip_bfloat16 hi, lo;
    split_bf16(v, hi, lo);
    __hip_bfloat16* row = dst + (size_t)r * 3 * cols;
    row[c] = hi; row[cols + c] = hi; row[2 * cols + c] = lo;
}

// ---------------------------------------------------------------- embedding
__global__ void __launch_bounds__(256) embed_kernel(
    const int* __restrict__ tokens, const float* __restrict__ emb,
    float* __restrict__ x) {
    const int s = blockIdx.x;
    const int t = tokens[s];
    const float* src = emb + (size_t)t * kDModel;
    float* dst = x + (size_t)s * kDModel;
    for (int d = threadIdx.x; d < kDModel; d += blockDim.x) dst[d] = src[d];
}

// ----------------------------------- rmsnorm -> bf16 (plain or 3-term split)
template <bool SPLIT>
__global__ void __launch_bounds__(256) rmsnorm_kernel(
    const float* __restrict__ x, const float* __restrict__ w,
    __hip_bfloat16* __restrict__ out) {
    const int s = blockIdx.x;
    const float* row = x + (size_t)s * kDModel;
    float ss = 0.f;
    for (int d = threadIdx.x; d < kDModel; d += blockDim.x) {
        const float v = row[d];
        ss = fmaf(v, v, ss);
    }
    #pragma unroll
    for (int m = 32; m; m >>= 1) ss += __shfl_xor(ss, m);
    __shared__ float red[4];
    if ((threadIdx.x & 63) == 0) red[threadIdx.x >> 6] = ss;
    __syncthreads();
    const float total = red[0] + red[1] + red[2] + red[3];
    const float scale = rsqrtf(total / (float)kDModel + 1e-5f);
    __hip_bfloat16* dst = out + (size_t)s * (SPLIT ? 3 * kDModel : kDModel);
    for (int d = threadIdx.x; d < kDModel; d += blockDim.x) {
        const float v = row[d] * scale * w[d];
        if (SPLIT) {
            __hip_bfloat16 hi, lo;
            split_bf16(v, hi, lo);
            dst[d] = hi; dst[kDModel + d] = lo; dst[2 * kDModel + d] = hi;
        } else {
            dst[d] = __float2bfloat16(v);
        }
    }
}

// ---------------------------------------------------------------- MFMA GEMM
// C[m][n] = sum_{k in split part} A[m][k]*B[n][k].  A: MxK bf16, B: NxK bf16.
// 2-phase double-buffered pipeline: prefetch STAGE(t+1) before compute(t);
// raw s_barrier + counted vmcnt keeps next tile's loads in flight across the
// MFMA phase. Granule swizzle (bank-conflict-free) + bijective XCD swizzle.
// BN=128: 256 thr, 2x2 waves.  BN=256: 512 thr, 2x4 waves (vocab).
template <int BM, int BN, int KSPLIT>
__global__ void __launch_bounds__((BN == 256) ? 512 : 256) mfma_gemm(
    const __hip_bfloat16* __restrict__ A, int lda,
    const __hip_bfloat16* __restrict__ B, int ldb,
    float* __restrict__ C, int ldc,
    int N, int K, size_t partStride) {
    constexpr int BK = 32;
    constexpr int THREADS = (BN == 256) ? 512 : 256;
    constexpr int WAVES_M = 2;
    constexpr int WAVES_N = THREADS / 64 / WAVES_M;  // 2 or 4
    constexpr int LPT = (BM * 4 + BN * 4) / THREADS; // loads per thread/stage
    static_assert(BM == 128, "A staging assumes BM=128");
    __shared__ unsigned short As[2][BM * BK];
    __shared__ unsigned short Bs[2][BN * BK];
    const int tid  = threadIdx.x;
    const int lane = tid & 63;

    // ---- bijective chunked XCD swizzle (m204) over the (x,y) grid ----
    const int nwg = gridDim.x * gridDim.y;
    int bid = blockIdx.y * gridDim.x + blockIdx.x;
    {
        const int q = nwg >> 3, r = nwg & 7;
        const int xcd = bid & 7, pos = bid >> 3;
        bid = (xcd < r ? xcd * (q + 1) : r * (q + 1) + (xcd - r) * q) + pos;
    }
    const int m0 = (bid % gridDim.x) * BM;   // m fast: same-n blocks adjacent
    const int n0 = (bid / gridDim.x) * BN;

    const int Kp = K / KSPLIT;
    const int kbeg = (KSPLIT > 1) ? blockIdx.z * Kp : 0;
    float* Cw = (KSPLIT > 1) ? C + (size_t)blockIdx.z * partStride : C;
    constexpr int WM = BM / WAVES_M, WN = BN / WAVES_N;   // 64, 64
    constexpr int MR = WM / 16, NR = WN / 16;
    const int wave = tid >> 6;
    const int wm = (wave / WAVES_N) * WM, wn = (wave % WAVES_N) * WN;
    const int l15 = lane & 15, l4 = lane >> 4;
    f32x4 acc[MR][NR] = {};

    // stage one K-tile into buffer `buf` (LPT gload_lds per thread, uniform)
    auto stage = [&](int buf, int k0) {
        #pragma unroll
        for (int i = 0; i < BM * 4 / THREADS; ++i) {
            const int idx = tid + i * THREADS;       // A granules: BM*4
            const int r = idx >> 2, qv = idx & 3;
            const int qs = qv ^ ((r >> 1) & 3);
            __builtin_amdgcn_global_load_lds(
                (const __attribute__((address_space(1))) void*)(A + (size_t)(m0 + r) * lda + k0 + qs * 8),
                (__attribute__((address_space(3))) void*)(&As[buf][(idx - lane) * 8]),
                16, 0, 0);
        }
        #pragma unroll
        for (int i = 0; i < BN * 4 / THREADS; ++i) {
            const int idx = tid + i * THREADS;       // B granules: BN*4
            const int r = idx >> 2, qv = idx & 3;
            const int qs = qv ^ ((r >> 1) & 3);
            __builtin_amdgcn_global_load_lds(
                (const __attribute__((address_space(1))) void*)(B + (size_t)(n0 + r) * ldb + k0 + qs * 8),
                (__attribute__((address_space(3))) void*)(&Bs[buf][(idx - lane) * 8]),
                16, 0, 0);
        }
    };

    const int nt = Kp / BK;
    int cur = 0;
    stage(0, kbeg);
    for (int t = 0; t < nt; ++t) {
        if (t + 1 < nt) {
            stage(cur ^ 1, kbeg + (t + 1) * BK);
            if constexpr (LPT == 4) asm volatile("s_waitcnt vmcnt(4)" ::: "memory");
            else                    asm volatile("s_waitcnt vmcnt(3)" ::: "memory");
        } else {
            asm volatile("s_waitcnt vmcnt(0)" ::: "memory");
        }
        __builtin_amdgcn_s_barrier();

        short8 af[MR], bfv[NR];
        #pragma unroll
        for (int mi = 0; mi < MR; ++mi) {
            const int R = wm + mi * 16 + l15;
            af[mi] = *reinterpret_cast<const short8*>(&As[cur][(R * 4 + (l4 ^ ((R >> 1) & 3))) * 8]);
        }
        #pragma unroll
        for (int ni = 0; ni < NR; ++ni) {
            const int R = wn + ni * 16 + l15;
            bfv[ni] = *reinterpret_cast<const short8*>(&Bs[cur][(R * 4 + (l4 ^ ((R >> 1) & 3))) * 8]);
        }
        #pragma unroll
        for (int mi = 0; mi < MR; ++mi)
            #pragma unroll
            for (int ni = 0; ni < NR; ++ni)
                acc[mi][ni] = __builtin_amdgcn_mfma_f32_16x16x32_bf16(
                    af[mi], bfv[ni], acc[mi][ni], 0, 0, 0);

        asm volatile("s_waitcnt lgkmcnt(0)" ::: "memory");
        __builtin_amdgcn_s_barrier();                // safe to overwrite cur
        cur ^= 1;
    }

    // C/D layout: col = lane&15, row = (lane>>4)*4 + reg  (m89/m91)
    #pragma unroll
    for (int mi = 0; mi < MR; ++mi) {
        const int mrow = m0 + wm + mi * 16 + l4 * 4;
        #pragma unroll
        for (int ni = 0; ni < NR; ++ni) {
            const int ncol = n0 + wn + ni * 16 + l15;
            if (ncol >= N) continue;
            #pragma unroll
            for (int r = 0; r < 4; ++r)
                Cw[(size_t)(mrow + r) * ldc + ncol] = acc[mi][ni][r];
        }
    }
}

// ------------------------- reduce NP split-K partials: dst = / += sum(parts)
template <int NP, bool ADD>
__global__ void __launch_bounds__(256) reduce_parts(
    const float* __restrict__ parts, size_t stride,
    float* __restrict__ dst, int count) {
    const int i = (blockIdx.x * 256 + threadIdx.x) * 4;
    if (i >= count) return;
    float4 s = *reinterpret_cast<const float4*>(parts + i);
    #pragma unroll
    for (int p = 1; p < NP; ++p) {
        const float4 v = *reinterpret_cast<const float4*>(parts + (size_t)p * stride + i);
        s.x += v.x; s.y += v.y; s.z += v.z; s.w += v.w;
    }
    float4* d = reinterpret_cast<float4*>(dst + i);
    if (ADD) {
        float4 o = *d;
        o.x += s.x; o.y += s.y; o.z += s.z; o.w += s.w;
        *d = o;
    } else {
        *d = s;
    }
}

// ---------------------------- dt = softplus(proj[:, :48] @ dtw^T + bias)
// fp32-exact, K=48. Block: 256 n-cols x 8 m-rows; dtw tile staged in LDS.
__global__ void __launch_bounds__(256) dt_kernel(
    const float* __restrict__ proj, const float* __restrict__ dtw,
    const float* __restrict__ bias, float* __restrict__ dt) {
    __shared__ float sw[kDtRank][257];
    const int tid = threadIdx.x;
    const int n0 = blockIdx.x * 256;
    const int m0 = blockIdx.y * 8;
    for (int idx = tid; idx < 256 * kDtRank; idx += 256) {
        const int nn = idx / kDtRank, k = idx % kDtRank;
        sw[k][nn] = dtw[(size_t)(n0 + nn) * kDtRank + k];
    }
    __syncthreads();
    const int n = n0 + tid;
    const float b = bias[n];
    #pragma unroll
    for (int mi = 0; mi < 8; ++mi) {
        const float* pr = proj + (size_t)(m0 + mi) * kPLd;
        float acc = b;
        #pragma unroll
        for (int k = 0; k < kDtRank; ++k)
            acc = fmaf(pr[k], sw[k][tid], acc);
        acc = (acc > 20.f) ? acc : log1pf(__expf(acc));  // softplus
        dt[(size_t)(m0 + mi) * kDInner + n] = acc;
    }
}

// ---------------- depthwise causal conv+silu, fused 2-part split-K reduce
__global__ void __launch_bounds__(256) conv_silu_kernel(
    const float* __restrict__ p0, const float* __restrict__ p1,
    const float* __restrict__ cw, const float* __restrict__ cb,
    float* __restrict__ xi, __hip_bfloat16* __restrict__ xi2) {
    const int s = blockIdx.x;
    const int d = blockIdx.y * 256 + threadIdx.x;
    float acc = cb[d];
    #pragma unroll
    for (int k = 0; k < kDConv; ++k) {
        const int sl = s - (kDConv - 1) + k;
        if (sl >= 0) {
            const size_t off = (size_t)sl * (2 * kDInner) + d;
            acc = fmaf(p0[off] + p1[off], cw[d * kDConv + k], acc);
        }
    }
    const float v = silu_f(acc);
    xi[(size_t)s * kDInner + d] = v;
    __hip_bfloat16 hi, lo;
    split_bf16(v, hi, lo);
    __hip_bfloat16* row = xi2 + (size_t)s * 3 * kDInner;
    row[d] = hi; row[kDInner + d] = lo; row[2 * kDInner + d] = hi;
}

// ------------------------------------------------- chunked selective scan
// recurrence: state = state * exp(exp(dt*A)) + dt*u*B ; y = <state,C> + u*Dv
__global__ void __launch_bounds__(256) scan_part1(
    const float* __restrict__ dt, const float* __restrict__ u,
    const float* __restrict__ proj, const float* __restrict__ A_log,
    float* __restrict__ P, float* __restrict__ S) {
    __shared__ float sdt[kCH][16], su[kCH][16], sB[kCH][16];
    const int tid = threadIdx.x;
    const int n = tid & 15, dl = tid >> 4;
    const int d0 = blockIdx.x * 16;
    const int l0 = blockIdx.y * kCH;
    for (int idx = tid; idx < kCH * 16; idx += 256) {
        const int r = idx >> 4, c = idx & 15;
        sdt[r][c] = dt[(size_t)(l0 + r) * kDInner + d0 + c];
        su [r][c] = u [(size_t)(l0 + r) * kDInner + d0 + c];
        sB [r][c] = proj[(size_t)(l0 + r) * kPLd + kDtRank + c];
    }
    __syncthreads();
    const int d = d0 + dl;
    const float Adn = -__expf(A_log[d * kDState + n]);
    float state = 0.f, sumA = 0.f;
    #pragma unroll 8
    for (int l = 0; l < kCH; ++l) {
        const float dtv = sdt[l][dl];
        const float adelta = __expf(dtv * Adn);
        const float mult = __expf(adelta);
        state = fmaf(state, mult, dtv * su[l][dl] * sB[l][n]);
        sumA += adelta;
    }
    const int dn = d * kDState + n;
    P[(size_t)blockIdx.y * kDN + dn] = __expf(sumA);
    S[(size_t)blockIdx.y * kDN + dn] = state;
}

// part2: inline prefix over chunks (combine folded in), then chunk scan -> y
__global__ void __launch_bounds__(256) scan_part2(
    const float* __restrict__ dt, const float* __restrict__ u,
    const float* __restrict__ proj, const float* __restrict__ A_log,
    const float* __restrict__ D_skip, const float* __restrict__ P,
    const float* __restrict__ S, float* __restrict__ y) {
    __shared__ float sdt[kCH][16], su[kCH][16], sB[kCH][16], sC[kCH][16];
    __shared__ float sy[kCH][16];
    const int tid = threadIdx.x;
    const int n = tid & 15, dl = tid >> 4;
    const int d0 = blockIdx.x * 16;
    const int l0 = blockIdx.y * kCH;
    for (int idx = tid; idx < kCH * 16; idx += 256) {
        const int r = idx >> 4, c = idx & 15;
        sdt[r][c] = dt[(size_t)(l0 + r) * kDInner + d0 + c];
        su [r][c] = u [(size_t)(l0 + r) * kDInner + d0 + c];
        sB [r][c] = proj[(size_t)(l0 + r) * kPLd + kDtRank + c];
        sC [r][c] = proj[(size_t)(l0 + r) * kPLd + kDtRank + kDState + c];
    }
    // inline prefix: state entering chunk blockIdx.y for this thread's dn
    const int dn = d0 * kDState + tid;   // == (d0+dl)*16 + n
    float state = 0.f;
    for (int jj = 0; jj < (int)blockIdx.y; ++jj) {
        const size_t idx = (size_t)jj * kDN + dn;
        state = fmaf(state, P[idx], S[idx]);
    }
    __syncthreads();
    const int d = d0 + dl;
    const float Adn = -__expf(A_log[d * kDState + n]);
    const float Dv  = D_skip[d];
    for (int l = 0; l < kCH; ++l) {
        const float dtv = sdt[l][dl];
        const float uv  = su[l][dl];
        const float mult = __expf(__expf(dtv * Adn));
        state = fmaf(state, mult, dtv * uv * sB[l][n]);
        float contrib = state * sC[l][n];
        contrib += __shfl_xor(contrib, 8);
        contrib += __shfl_xor(contrib, 4);
        contrib += __shfl_xor(contrib, 2);
        contrib += __shfl_xor(contrib, 1);
        if (n == 0) sy[l][dl] = fmaf(uv, Dv, contrib);
    }
    __syncthreads();
    for (int idx = tid; idx < kCH * 16; idx += 256) {
        const int r = idx >> 4, c = idx & 15;
        y[(size_t)(l0 + r) * kDInner + d0 + c] = sy[r][c];
    }
}

// ------------- g = y * silu(res), res summed from 2 partials (split bf16)
__global__ void __launch_bounds__(256) mul_silu_kernel(
    const float* __restrict__ y, const float* __restrict__ p0,
    const float* __restrict__ p1, __hip_bfloat16* __restrict__ g2) {
    const int s = blockIdx.x;
    const int d = blockIdx.y * 256 + threadIdx.x;
    const size_t off = (size_t)s * (2 * kDInner) + kDInner + d;
    const float res = p0[off] + p1[off];
    const float v = y[(size_t)s * kDInner + d] * silu_f(res);
    __hip_bfloat16 hi, lo;
    split_bf16(v, hi, lo);
    __hip_bfloat16* row = g2 + (size_t)s * 3 * kDInner;
    row[d] = hi; row[kDInner + d] = lo; row[2 * kDInner + d] = hi;
}

}  // namespace

extern "C" void kernel_launch(void* const* d_in, const int* in_sizes, int n_in,
                              void* d_out, int out_size, void* d_ws, size_t ws_size,
                              hipStream_t stream) {
    const int*   tokens       = (const int*)d_in[0];
    const float* embedding    = (const float*)d_in[1];
    const float* norm_w       = (const float*)d_in[2];
    const float* in_proj_w    = (const float*)d_in[3];
    const float* conv_w       = (const float*)d_in[4];
    const float* conv_b       = (const float*)d_in[5];
    const float* x_proj_w     = (const float*)d_in[6];
    const float* dt_proj_w    = (const float*)d_in[7];
    const float* dt_proj_b    = (const float*)d_in[8];
    const float* A_log        = (const float*)d_in[9];
    const float* D_skip       = (const float*)d_in[10];
    const float* out_proj_w   = (const float*)d_in[11];
    const float* final_norm_w = (const float*)d_in[12];
    float* out = (float*)d_out;

    constexpr int K3m = 3 * kDModel;   // 2304
    constexpr int K3i = 3 * kDInner;   // 4608

    char* ws = (char*)d_ws;
    auto alloc = [&](size_t bytes) { char* p = ws; ws += (bytes + 255) & ~(size_t)255; return p; };
    float* x    = (float*)alloc((size_t)kSeq * kDModel * 4);
    float* xi   = (float*)alloc((size_t)kSeq * kDInner * 4);
    float* proj = (float*)alloc((size_t)kSeq * kPLd * 4);
    float* dt   = (float*)alloc((size_t)kSeq * kDInner * 4);
    float* y    = (float*)alloc((size_t)kSeq * kDInner * 4);
    float* scanP  = (float*)alloc((size_t)kNCH * kDN * 4);
    float* scanS  = (float*)alloc((size_t)kNCH * kDN * 4);
    float* partsXZ = (float*)alloc((size_t)2 * kSeq * 2 * kDInner * 4);  // in_proj partials (live to mul_silu)
    float* partsP  = (float*)alloc((size_t)24 * kSeq * kPLd * 4);        // x_proj partials
    float* partsO  = (float*)alloc((size_t)6 * kSeq * kDModel * 4);      // out_proj partials
    __hip_bfloat16* h_bf   = (__hip_bfloat16*)alloc((size_t)kSeq * kDModel * 2);
    __hip_bfloat16* h2     = (__hip_bfloat16*)alloc((size_t)kSeq * K3m * 2);
    __hip_bfloat16* xi2    = (__hip_bfloat16*)alloc((size_t)kSeq * K3i * 2);
    __hip_bfloat16* g2     = (__hip_bfloat16*)alloc((size_t)kSeq * K3i * 2);
    __hip_bfloat16* emb_bf = (__hip_bfloat16*)alloc((size_t)kVocab * kDModel * 2);
    __hip_bfloat16* inw2   = (__hip_bfloat16*)alloc((size_t)kL * 2 * kDInner * K3m * 2);
    __hip_bfloat16* outw2  = (__hip_bfloat16*)alloc((size_t)kL * kDModel * K3i * 2);
    __hip_bfloat16* xw2    = (__hip_bfloat16*)alloc((size_t)kL * kPB * K3i * 2);

    // ---- weight conversions (per call; layer dims are contiguous) ----
    f2b_kernel<<<4096, 256, 0, stream>>>(embedding, emb_bf, kVocab * kDModel);
    split3_kernel<<<(kL * 2 * kDInner * kDModel + 255) / 256, 256, 0, stream>>>(
        in_proj_w, kDModel, kL * 2 * kDInner, kDModel, inw2, kL * 2 * kDInner);
    split3_kernel<<<(kL * kDModel * kDInner + 255) / 256, 256, 0, stream>>>(
        out_proj_w, kDInner, kL * kDModel, kDInner, outw2, kL * kDModel);
    for (int i = 0; i < kL; ++i)
        split3_kernel<<<(kPB * kDInner + 255) / 256, 256, 0, stream>>>(
            x_proj_w + (size_t)i * (kDtRank + 2 * kDState) * kDInner, kDInner,
            kDtRank + 2 * kDState, kDInner, xw2 + (size_t)i * kPB * K3i, kPB);

    embed_kernel<<<kSeq, 256, 0, stream>>>(tokens, embedding, x);

    for (int i = 0; i < kL; ++i) {
        rmsnorm_kernel<true><<<kSeq, 256, 0, stream>>>(x, norm_w + (size_t)i * kDModel, h2);

        // xz partials = h @ in_proj_w[i]^T  (1024 x 3072, K=2304, KSPLIT=2)
        mfma_gemm<128, 128, 2><<<dim3(kSeq / 128, 2 * kDInner / 128, 2), 256, 0, stream>>>(
            h2, K3m, inw2 + (size_t)i * 2 * kDInner * K3m, K3m,
            partsXZ, 2 * kDInner, 2 * kDInner, K3m, (size_t)kSeq * 2 * kDInner);

        // xi = silu(conv(sum(parts)[:, :1536]) + b)   (reduce fused)
        conv_silu_kernel<<<dim3(kSeq, kDInner / 256), 256, 0, stream>>>(
            partsXZ, partsXZ + (size_t)kSeq * 2 * kDInner,
            conv_w + (size_t)i * kDInner * kDConv, conv_b + (size_t)i * kDInner,
            xi, xi2);

        // proj = xi @ x_proj_w[i]^T   (1024 x 128pad, K=4608, KSPLIT=24)
        mfma_gemm<128, 128, 24><<<dim3(kSeq / 128, 1, 24), 256, 0, stream>>>(
            xi2, K3i, xw2 + (size_t)i * kPB * K3i, K3i,
            partsP, kPLd, kPLd, K3i, (size_t)kSeq * kPLd);
        reduce_parts<24, false><<<(kSeq * kPLd / 4 + 255) / 256, 256, 0, stream>>>(
            partsP, (size_t)kSeq * kPLd, proj, kSeq * kPLd);

        // dt = softplus(proj[:, :48] @ dt_proj_w^T + b)  -- fp32 exact
        dt_kernel<<<dim3(kDInner / 256, kSeq / 8), 256, 0, stream>>>(
            proj, dt_proj_w + (size_t)i * kDInner * kDtRank,
            dt_proj_b + (size_t)i * kDInner, dt);

        // y = selective_scan(xi, dt, A, B, C, D) — chunked, combine folded
        const float* A_l = A_log + (size_t)i * kDInner * kDState;
        scan_part1<<<dim3(kDInner / 16, kNCH), 256, 0, stream>>>(
            dt, xi, proj, A_l, scanP, scanS);
        scan_part2<<<dim3(kDInner / 16, kNCH), 256, 0, stream>>>(
            dt, xi, proj, A_l, D_skip + (size_t)i * kDInner, scanP, scanS, y);

        // g = y * silu(res)   (res reduce fused)
        mul_silu_kernel<<<dim3(kSeq, kDInner / 256), 256, 0, stream>>>(
            y, partsXZ, partsXZ + (size_t)kSeq * 2 * kDInner, g2);

        // x += g @ out_proj_w[i]^T   (1024 x 768, K=4608, KSPLIT=6)
        mfma_gemm<128, 128, 6><<<dim3(kSeq / 128, kDModel / 128, 6), 256, 0, stream>>>(
            g2, K3i, outw2 + (size_t)i * kDModel * K3i, K3i,
            partsO, kDModel, kDModel, K3i, (size_t)kSeq * kDModel);
        reduce_parts<6, true><<<(kSeq * kDModel / 4 + 255) / 256, 256, 0, stream>>>(
            partsO, (size_t)kSeq * kDModel, x, kSeq * kDModel);
    }

    // out = rmsnorm(x, final_norm_w) @ embedding^T  (1024 x 32000, K=768, 128x256)
    rmsnorm_kernel<false><<<kSeq, 256, 0, stream>>>(x, final_norm_w, h_bf);
    mfma_gemm<128, 256, 1><<<dim3(kSeq / 128, kVocab / 256, 1), 512, 0, stream>>>(
        h_bf, kDModel, emb_bf, kDModel, out, kVocab, kVocab, kDModel, 0);
}

// Round 9
// 819.747 us; speedup vs baseline: 6.2179x; 1.0034x over previous
//
#include <hip/hip_runtime.h>
#include <hip/hip_bf16.h>
#include <cmath>

namespace {

constexpr int kL      = 4;
constexpr int kDModel = 768;
constexpr int kDInner = 1536;
constexpr int kDtRank = 48;
constexpr int kDState = 16;
constexpr int kDConv  = 4;
constexpr int kSeq    = 1024;
constexpr int kPLd    = 96;    // proj row stride (80 used)
constexpr int kPB     = 128;   // x_proj weight rows padded for BN=128
constexpr int kVocab  = 32000;
constexpr int kCH     = 64;    // scan chunk length
constexpr int kNCH    = kSeq / kCH;  // 16 chunks
constexpr int kDN     = kDInner * kDState;  // 24576 (d,n) pairs

using short8 = __attribute__((ext_vector_type(8))) short;
using f32x4  = __attribute__((ext_vector_type(4))) float;

__device__ __forceinline__ float silu_f(float v) {
    return v / (1.f + __expf(-v));
}

__device__ __forceinline__ void split_bf16(float v, __hip_bfloat16& hi, __hip_bfloat16& lo) {
    hi = __float2bfloat16(v);
    lo = __float2bfloat16(v - __bfloat162float(hi));
}

// ---------------------------------------------------------------- fp32->bf16
__global__ void __launch_bounds__(256) f2b_kernel(
    const float* __restrict__ src, __hip_bfloat16* __restrict__ dst, int n) {
    int i = (blockIdx.x * 256 + threadIdx.x) * 4;
    const int stride = gridDim.x * 256 * 4;
    for (; i + 3 < n; i += stride) {
        const float4 v = *reinterpret_cast<const float4*>(src + i);
        dst[i + 0] = __float2bfloat16(v.x);
        dst[i + 1] = __float2bfloat16(v.y);
        dst[i + 2] = __float2bfloat16(v.z);
        dst[i + 3] = __float2bfloat16(v.w);
    }
}

// -------------------------------- fp32 -> 3-term split bf16 along K
// B-side: dst row = [hi | hi | lo]; rows >= `rows` zero-filled.
__global__ void __launch_bounds__(256) split3_kernel(
    const float* __restrict__ src, int ldsrc, int rows, int cols,
    __hip_bfloat16* __restrict__ dst, int rowsPad) {
    const int idx = blockIdx.x * 256 + threadIdx.x;
    if (idx >= rowsPad * cols) return;
    const int r = idx / cols, c = idx % cols;
    const float v = (r < rows) ? src[(size_t)r * ldsrc + c] : 0.f;
    __hip_bfloat16 hi, lo;
    split_bf16(v, hi, lo);
    __hip_bfloat16* row = dst + (size_t)r * 3 * cols;
    row[c] = hi; row[cols + c] = hi; row[2 * cols + c] = lo;
}

// ------------- x_proj weights, all layers in one grid: 80 rows -> 128 padded
__global__ void __launch_bounds__(256) split3x_kernel(
    const float* __restrict__ src, __hip_bfloat16* __restrict__ dst) {
    const int idx = blockIdx.x * 256 + threadIdx.x;
    if (idx >= kL * kPB * kDInner) return;
    const int layer = idx / (kPB * kDInner);
    const int rem   = idx % (kPB * kDInner);
    const int r = rem / kDInner, c = rem % kDInner;
    const float v = (r < kDtRank + 2 * kDState)
        ? src[(size_t)layer * (kDtRank + 2 * kDState) * kDInner + (size_t)r * kDInner + c]
        : 0.f;
    __hip_bfloat16 hi, lo;
    split_bf16(v, hi, lo);
    __hip_bfloat16* row = dst + ((size_t)layer * kPB + r) * 3 * kDInner;
    row[c] = hi; row[kDInner + c] = hi; row[2 * kDInner + c] = lo;
}

// ---------------------------------------------------------------- embedding
__global__ void __launch_bounds__(256) embed_kernel(
    const int* __restrict__ tokens, const float* __restrict__ emb,
    float* __restrict__ x) {
    const int s = blockIdx.x;
    const int t = tokens[s];
    const float* src = emb + (size_t)t * kDModel;
    float* dst = x + (size_t)s * kDModel;
    for (int d = threadIdx.x; d < kDModel; d += blockDim.x) dst[d] = src[d];
}

// ----------------------------------- rmsnorm -> bf16 (plain or 3-term split)
template <bool SPLIT>
__global__ void __launch_bounds__(256) rmsnorm_kernel(
    const float* __restrict__ x, const float* __restrict__ w,
    __hip_bfloat16* __restrict__ out) {
    const int s = blockIdx.x;
    const float* row = x + (size_t)s * kDModel;
    float ss = 0.f;
    for (int d = threadIdx.x; d < kDModel; d += blockDim.x) {
        const float v = row[d];
        ss = fmaf(v, v, ss);
    }
    #pragma unroll
    for (int m = 32; m; m >>= 1) ss += __shfl_xor(ss, m);
    __shared__ float red[4];
    if ((threadIdx.x & 63) == 0) red[threadIdx.x >> 6] = ss;
    __syncthreads();
    const float total = red[0] + red[1] + red[2] + red[3];
    const float scale = rsqrtf(total / (float)kDModel + 1e-5f);
    __hip_bfloat16* dst = out + (size_t)s * (SPLIT ? 3 * kDModel : kDModel);
    for (int d = threadIdx.x; d < kDModel; d += blockDim.x) {
        const float v = row[d] * scale * w[d];
        if (SPLIT) {
            __hip_bfloat16 hi, lo;
            split_bf16(v, hi, lo);
            dst[d] = hi; dst[kDModel + d] = lo; dst[2 * kDModel + d] = hi;
        } else {
            dst[d] = __float2bfloat16(v);
        }
    }
}

// ---------------------------------------------------------------- MFMA GEMM
// C[m][n] = sum_{k in split part} A[m][k]*B[n][k].  A: MxK bf16, B: NxK bf16.
// Triple-buffered pipeline: stage(t+2) issued at top of t, so the vmcnt wait
// targets loads issued TWO compute-phases ago (vmcnt(8): 12 outstanding - 4
// oldest). Granule swizzle (bank-conflict-free) + bijective XCD swizzle.
// 128x128 tile, 256 threads, 2x2 waves, 48 KB LDS (3 blocks/CU).
template <int BM, int BN, int KSPLIT>
__global__ void __launch_bounds__(256) mfma_gemm(
    const __hip_bfloat16* __restrict__ A, int lda,
    const __hip_bfloat16* __restrict__ B, int ldb,
    float* __restrict__ C, int ldc,
    int N, int K, size_t partStride) {
    constexpr int BK = 32;
    static_assert(BM == 128 && BN == 128, "staging assumes 128x128");
    __shared__ unsigned short As[3][BM * BK];
    __shared__ unsigned short Bs[3][BN * BK];
    const int tid  = threadIdx.x;
    const int lane = tid & 63;

    // ---- bijective chunked XCD swizzle (m204) over the (x,y) grid ----
    const int nwg = gridDim.x * gridDim.y;
    int bid = blockIdx.y * gridDim.x + blockIdx.x;
    {
        const int q = nwg >> 3, r = nwg & 7;
        const int xcd = bid & 7, pos = bid >> 3;
        bid = (xcd < r ? xcd * (q + 1) : r * (q + 1) + (xcd - r) * q) + pos;
    }
    const int m0 = (bid % gridDim.x) * BM;   // m fast: same-n blocks adjacent
    const int n0 = (bid / gridDim.x) * BN;

    const int Kp = K / KSPLIT;
    const int kbeg = (KSPLIT > 1) ? blockIdx.z * Kp : 0;
    float* Cw = (KSPLIT > 1) ? C + (size_t)blockIdx.z * partStride : C;
    constexpr int WM = BM / 2, WN = BN / 2;   // 2x2 waves
    constexpr int MR = WM / 16, NR = WN / 16;
    const int wave = tid >> 6;
    const int wm = (wave >> 1) * WM, wn = (wave & 1) * WN;
    const int l15 = lane & 15, l4 = lane >> 4;
    f32x4 acc[MR][NR] = {};

    // stage one K-tile into buffer `buf` (4 gload_lds per thread, uniform)
    auto stage = [&](int buf, int k0) {
        #pragma unroll
        for (int i = 0; i < 2; ++i) {
            const int idx = tid + i * 256;           // A granules: BM*4 = 512
            const int r = idx >> 2, qv = idx & 3;
            const int qs = qv ^ ((r >> 1) & 3);
            __builtin_amdgcn_global_load_lds(
                (const __attribute__((address_space(1))) void*)(A + (size_t)(m0 + r) * lda + k0 + qs * 8),
                (__attribute__((address_space(3))) void*)(&As[buf][(idx - lane) * 8]),
                16, 0, 0);
        }
        #pragma unroll
        for (int i = 0; i < 2; ++i) {
            const int idx = tid + i * 256;           // B granules: BN*4 = 512
            const int r = idx >> 2, qv = idx & 3;
            const int qs = qv ^ ((r >> 1) & 3);
            __builtin_amdgcn_global_load_lds(
                (const __attribute__((address_space(1))) void*)(B + (size_t)(n0 + r) * ldb + k0 + qs * 8),
                (__attribute__((address_space(3))) void*)(&Bs[buf][(idx - lane) * 8]),
                16, 0, 0);
        }
    };

    const int nt = Kp / BK;
    stage(0, kbeg);
    if (nt > 1) stage(1, kbeg + BK);
    for (int t = 0; t < nt; ++t) {
        const int cur = t % 3;
        if (t + 2 < nt) stage((t + 2) % 3, kbeg + (t + 2) * BK);
        const int rem = nt - 1 - t;   // stages in flight beyond cur
        if (rem >= 2)      asm volatile("s_waitcnt vmcnt(8)" ::: "memory");
        else if (rem == 1) asm volatile("s_waitcnt vmcnt(4)" ::: "memory");
        else               asm volatile("s_waitcnt vmcnt(0)" ::: "memory");
        __builtin_amdgcn_s_barrier();

        short8 af[MR], bfv[NR];
        #pragma unroll
        for (int mi = 0; mi < MR; ++mi) {
            const int R = wm + mi * 16 + l15;
            af[mi] = *reinterpret_cast<const short8*>(&As[cur][(R * 4 + (l4 ^ ((R >> 1) & 3))) * 8]);
        }
        #pragma unroll
        for (int ni = 0; ni < NR; ++ni) {
            const int R = wn + ni * 16 + l15;
            bfv[ni] = *reinterpret_cast<const short8*>(&Bs[cur][(R * 4 + (l4 ^ ((R >> 1) & 3))) * 8]);
        }
        #pragma unroll
        for (int mi = 0; mi < MR; ++mi)
            #pragma unroll
            for (int ni = 0; ni < NR; ++ni)
                acc[mi][ni] = __builtin_amdgcn_mfma_f32_16x16x32_bf16(
                    af[mi], bfv[ni], acc[mi][ni], 0, 0, 0);

        asm volatile("s_waitcnt lgkmcnt(0)" ::: "memory");
        __builtin_amdgcn_s_barrier();    // all waves done reading cur
    }

    // C/D layout: col = lane&15, row = (lane>>4)*4 + reg  (m89/m91)
    #pragma unroll
    for (int mi = 0; mi < MR; ++mi) {
        const int mrow = m0 + wm + mi * 16 + l4 * 4;
        #pragma unroll
        for (int ni = 0; ni < NR; ++ni) {
            const int ncol = n0 + wn + ni * 16 + l15;
            if (ncol >= N) continue;
            #pragma unroll
            for (int r = 0; r < 4; ++r)
                Cw[(size_t)(mrow + r) * ldc + ncol] = acc[mi][ni][r];
        }
    }
}

// ------------------------- reduce NP split-K partials: dst = / += sum(parts)
template <int NP, bool ADD>
__global__ void __launch_bounds__(256) reduce_parts(
    const float* __restrict__ parts, size_t stride,
    float* __restrict__ dst, int count) {
    const int i = (blockIdx.x * 256 + threadIdx.x) * 4;
    if (i >= count) return;
    float4 s = *reinterpret_cast<const float4*>(parts + i);
    #pragma unroll
    for (int p = 1; p < NP; ++p) {
        const float4 v = *reinterpret_cast<const float4*>(parts + (size_t)p * stride + i);
        s.x += v.x; s.y += v.y; s.z += v.z; s.w += v.w;
    }
    float4* d = reinterpret_cast<float4*>(dst + i);
    if (ADD) {
        float4 o = *d;
        o.x += s.x; o.y += s.y; o.z += s.z; o.w += s.w;
        *d = o;
    } else {
        *d = s;
    }
}

// ---------------------------- dt = softplus(proj[:, :48] @ dtw^T + bias)
// fp32-exact, K=48. Block: 256 n-cols x 8 m-rows; dtw tile staged in LDS.
__global__ void __launch_bounds__(256) dt_kernel(
    const float* __restrict__ proj, const float* __restrict__ dtw,
    const float* __restrict__ bias, float* __restrict__ dt) {
    __shared__ float sw[kDtRank][257];
    const int tid = threadIdx.x;
    const int n0 = blockIdx.x * 256;
    const int m0 = blockIdx.y * 8;
    for (int idx = tid; idx < 256 * kDtRank; idx += 256) {
        const int nn = idx / kDtRank, k = idx % kDtRank;
        sw[k][nn] = dtw[(size_t)(n0 + nn) * kDtRank + k];
    }
    __syncthreads();
    const int n = n0 + tid;
    const float b = bias[n];
    #pragma unroll
    for (int mi = 0; mi < 8; ++mi) {
        const float* pr = proj + (size_t)(m0 + mi) * kPLd;
        float acc = b;
        #pragma unroll
        for (int k = 0; k < kDtRank; ++k)
            acc = fmaf(pr[k], sw[k][tid], acc);
        acc = (acc > 20.f) ? acc : log1pf(__expf(acc));  // softplus
        dt[(size_t)(m0 + mi) * kDInner + n] = acc;
    }
}

// ---------------- depthwise causal conv+silu, fused 2-part split-K reduce
__global__ void __launch_bounds__(256) conv_silu_kernel(
    const float* __restrict__ p0, const float* __restrict__ p1,
    const float* __restrict__ cw, const float* __restrict__ cb,
    float* __restrict__ xi, __hip_bfloat16* __restrict__ xi2) {
    const int s = blockIdx.x;
    const int d = blockIdx.y * 256 + threadIdx.x;
    float acc = cb[d];
    #pragma unroll
    for (int k = 0; k < kDConv; ++k) {
        const int sl = s - (kDConv - 1) + k;
        if (sl >= 0) {
            const size_t off = (size_t)sl * (2 * kDInner) + d;
            acc = fmaf(p0[off] + p1[off], cw[d * kDConv + k], acc);
        }
    }
    const float v = silu_f(acc);
    xi[(size_t)s * kDInner + d] = v;
    __hip_bfloat16 hi, lo;
    split_bf16(v, hi, lo);
    __hip_bfloat16* row = xi2 + (size_t)s * 3 * kDInner;
    row[d] = hi; row[kDInner + d] = lo; row[2 * kDInner + d] = hi;
}

// ------------------------------------------------- chunked selective scan
// recurrence: state = state * exp(exp(dt*A)) + dt*u*B ; y = <state,C> + u*Dv
__global__ void __launch_bounds__(256) scan_part1(
    const float* __restrict__ dt, const float* __restrict__ u,
    const float* __restrict__ proj, const float* __restrict__ A_log,
    float* __restrict__ P, float* __restrict__ S) {
    __shared__ float sdt[kCH][16], su[kCH][16], sB[kCH][16];
    const int tid = threadIdx.x;
    const int n = tid & 15, dl = tid >> 4;
    const int d0 = blockIdx.x * 16;
    const int l0 = blockIdx.y * kCH;
    for (int idx = tid; idx < kCH * 16; idx += 256) {
        const int r = idx >> 4, c = idx & 15;
        sdt[r][c] = dt[(size_t)(l0 + r) * kDInner + d0 + c];
        su [r][c] = u [(size_t)(l0 + r) * kDInner + d0 + c];
        sB [r][c] = proj[(size_t)(l0 + r) * kPLd + kDtRank + c];
    }
    __syncthreads();
    const int d = d0 + dl;
    const float Adn = -__expf(A_log[d * kDState + n]);
    float state = 0.f, sumA = 0.f;
    #pragma unroll 8
    for (int l = 0; l < kCH; ++l) {
        const float dtv = sdt[l][dl];
        const float adelta = __expf(dtv * Adn);
        const float mult = __expf(adelta);
        state = fmaf(state, mult, dtv * su[l][dl] * sB[l][n]);
        sumA += adelta;
    }
    const int dn = d * kDState + n;
    P[(size_t)blockIdx.y * kDN + dn] = __expf(sumA);
    S[(size_t)blockIdx.y * kDN + dn] = state;
}

// part2: inline prefix over chunks (combine folded in), then chunk scan -> y
__global__ void __launch_bounds__(256) scan_part2(
    const float* __restrict__ dt, const float* __restrict__ u,
    const float* __restrict__ proj, const float* __restrict__ A_log,
    const float* __restrict__ D_skip, const float* __restrict__ P,
    const float* __restrict__ S, float* __restrict__ y) {
    __shared__ float sdt[kCH][16], su[kCH][16], sB[kCH][16], sC[kCH][16];
    __shared__ float sy[kCH][16];
    const int tid = threadIdx.x;
    const int n = tid & 15, dl = tid >> 4;
    const int d0 = blockIdx.x * 16;
    const int l0 = blockIdx.y * kCH;
    for (int idx = tid; idx < kCH * 16; idx += 256) {
        const int r = idx >> 4, c = idx & 15;
        sdt[r][c] = dt[(size_t)(l0 + r) * kDInner + d0 + c];
        su [r][c] = u [(size_t)(l0 + r) * kDInner + d0 + c];
        sB [r][c] = proj[(size_t)(l0 + r) * kPLd + kDtRank + c];
        sC [r][c] = proj[(size_t)(l0 + r) * kPLd + kDtRank + kDState + c];
    }
    // inline prefix: state entering chunk blockIdx.y for this thread's dn
    const int dn = d0 * kDState + tid;   // == (d0+dl)*16 + n
    float state = 0.f;
    for (int jj = 0; jj < (int)blockIdx.y; ++jj) {
        const size_t idx = (size_t)jj * kDN + dn;
        state = fmaf(state, P[idx], S[idx]);
    }
    __syncthreads();
    const int d = d0 + dl;
    const float Adn = -__expf(A_log[d * kDState + n]);
    const float Dv  = D_skip[d];
    for (int l = 0; l < kCH; ++l) {
        const float dtv = sdt[l][dl];
        const float uv  = su[l][dl];
        const float mult = __expf(__expf(dtv * Adn));
        state = fmaf(state, mult, dtv * uv * sB[l][n]);
        float contrib = state * sC[l][n];
        contrib += __shfl_xor(contrib, 8);
        contrib += __shfl_xor(contrib, 4);
        contrib += __shfl_xor(contrib, 2);
        contrib += __shfl_xor(contrib, 1);
        if (n == 0) sy[l][dl] = fmaf(uv, Dv, contrib);
    }
    __syncthreads();
    for (int idx = tid; idx < kCH * 16; idx += 256) {
        const int r = idx >> 4, c = idx & 15;
        y[(size_t)(l0 + r) * kDInner + d0 + c] = sy[r][c];
    }
}

// ------------- g = y * silu(res), res summed from 2 partials (split bf16)
__global__ void __launch_bounds__(256) mul_silu_kernel(
    const float* __restrict__ y, const float* __restrict__ p0,
    const float* __restrict__ p1, __hip_bfloat16* __restrict__ g2) {
    const int s = blockIdx.x;
    const int d = blockIdx.y * 256 + threadIdx.x;
    const size_t off = (size_t)s * (2 * kDInner) + kDInner + d;
    const float res = p0[off] + p1[off];
    const float v = y[(size_t)s * kDInner + d] * silu_f(res);
    __hip_bfloat16 hi, lo;
    split_bf16(v, hi, lo);
    __hip_bfloat16* row = g2 + (size_t)s * 3 * kDInner;
    row[d] = hi; row[kDInner + d] = lo; row[2 * kDInner + d] = hi;
}

}  // namespace

extern "C" void kernel_launch(void* const* d_in, const int* in_sizes, int n_in,
                              void* d_out, int out_size, void* d_ws, size_t ws_size,
                              hipStream_t stream) {
    const int*   tokens       = (const int*)d_in[0];
    const float* embedding    = (const float*)d_in[1];
    const float* norm_w       = (const float*)d_in[2];
    const float* in_proj_w    = (const float*)d_in[3];
    const float* conv_w       = (const float*)d_in[4];
    const float* conv_b       = (const float*)d_in[5];
    const float* x_proj_w     = (const float*)d_in[6];
    const float* dt_proj_w    = (const float*)d_in[7];
    const float* dt_proj_b    = (const float*)d_in[8];
    const float* A_log        = (const float*)d_in[9];
    const float* D_skip       = (const float*)d_in[10];
    const float* out_proj_w   = (const float*)d_in[11];
    const float* final_norm_w = (const float*)d_in[12];
    float* out = (float*)d_out;

    constexpr int K3m = 3 * kDModel;   // 2304
    constexpr int K3i = 3 * kDInner;   // 4608

    char* ws = (char*)d_ws;
    auto alloc = [&](size_t bytes) { char* p = ws; ws += (bytes + 255) & ~(size_t)255; return p; };
    float* x    = (float*)alloc((size_t)kSeq * kDModel * 4);
    float* xi   = (float*)alloc((size_t)kSeq * kDInner * 4);
    float* proj = (float*)alloc((size_t)kSeq * kPLd * 4);
    float* dt   = (float*)alloc((size_t)kSeq * kDInner * 4);
    float* y    = (float*)alloc((size_t)kSeq * kDInner * 4);
    float* scanP  = (float*)alloc((size_t)kNCH * kDN * 4);
    float* scanS  = (float*)alloc((size_t)kNCH * kDN * 4);
    float* partsXZ = (float*)alloc((size_t)2 * kSeq * 2 * kDInner * 4);  // in_proj partials (live to mul_silu)
    float* partsP  = (float*)alloc((size_t)24 * kSeq * kPLd * 4);        // x_proj partials
    float* partsO  = (float*)alloc((size_t)6 * kSeq * kDModel * 4);      // out_proj partials
    __hip_bfloat16* h_bf   = (__hip_bfloat16*)alloc((size_t)kSeq * kDModel * 2);
    __hip_bfloat16* h2     = (__hip_bfloat16*)alloc((size_t)kSeq * K3m * 2);
    __hip_bfloat16* xi2    = (__hip_bfloat16*)alloc((size_t)kSeq * K3i * 2);
    __hip_bfloat16* g2     = (__hip_bfloat16*)alloc((size_t)kSeq * K3i * 2);
    __hip_bfloat16* emb_bf = (__hip_bfloat16*)alloc((size_t)kVocab * kDModel * 2);
    __hip_bfloat16* inw2   = (__hip_bfloat16*)alloc((size_t)kL * 2 * kDInner * K3m * 2);
    __hip_bfloat16* outw2  = (__hip_bfloat16*)alloc((size_t)kL * kDModel * K3i * 2);
    __hip_bfloat16* xw2    = (__hip_bfloat16*)alloc((size_t)kL * kPB * K3i * 2);

    // ---- weight conversions (per call; layer dims are contiguous) ----
    f2b_kernel<<<4096, 256, 0, stream>>>(embedding, emb_bf, kVocab * kDModel);
    split3_kernel<<<(kL * 2 * kDInner * kDModel + 255) / 256, 256, 0, stream>>>(
        in_proj_w, kDModel, kL * 2 * kDInner, kDModel, inw2, kL * 2 * kDInner);
    split3_kernel<<<(kL * kDModel * kDInner + 255) / 256, 256, 0, stream>>>(
        out_proj_w, kDInner, kL * kDModel, kDInner, outw2, kL * kDModel);
    split3x_kernel<<<(kL * kPB * kDInner + 255) / 256, 256, 0, stream>>>(
        x_proj_w, xw2);

    embed_kernel<<<kSeq, 256, 0, stream>>>(tokens, embedding, x);

    for (int i = 0; i < kL; ++i) {
        rmsnorm_kernel<true><<<kSeq, 256, 0, stream>>>(x, norm_w + (size_t)i * kDModel, h2);

        // xz partials = h @ in_proj_w[i]^T  (1024 x 3072, K=2304, KSPLIT=2)
        mfma_gemm<128, 128, 2><<<dim3(kSeq / 128, 2 * kDInner / 128, 2), 256, 0, stream>>>(
            h2, K3m, inw2 + (size_t)i * 2 * kDInner * K3m, K3m,
            partsXZ, 2 * kDInner, 2 * kDInner, K3m, (size_t)kSeq * 2 * kDInner);

        // xi = silu(conv(sum(parts)[:, :1536]) + b)   (reduce fused)
        conv_silu_kernel<<<dim3(kSeq, kDInner / 256), 256, 0, stream>>>(
            partsXZ, partsXZ + (size_t)kSeq * 2 * kDInner,
            conv_w + (size_t)i * kDInner * kDConv, conv_b + (size_t)i * kDInner,
            xi, xi2);

        // proj = xi @ x_proj_w[i]^T   (1024 x 128pad, K=4608, KSPLIT=24)
        mfma_gemm<128, 128, 24><<<dim3(kSeq / 128, 1, 24), 256, 0, stream>>>(
            xi2, K3i, xw2 + (size_t)i * kPB * K3i, K3i,
            partsP, kPLd, kPLd, K3i, (size_t)kSeq * kPLd);
        reduce_parts<24, false><<<(kSeq * kPLd / 4 + 255) / 256, 256, 0, stream>>>(
            partsP, (size_t)kSeq * kPLd, proj, kSeq * kPLd);

        // dt = softplus(proj[:, :48] @ dt_proj_w^T + b)  -- fp32 exact
        dt_kernel<<<dim3(kDInner / 256, kSeq / 8), 256, 0, stream>>>(
            proj, dt_proj_w + (size_t)i * kDInner * kDtRank,
            dt_proj_b + (size_t)i * kDInner, dt);

        // y = selective_scan(xi, dt, A, B, C, D) — chunked, combine folded
        const float* A_l = A_log + (size_t)i * kDInner * kDState;
        scan_part1<<<dim3(kDInner / 16, kNCH), 256, 0, stream>>>(
            dt, xi, proj, A_l, scanP, scanS);
        scan_part2<<<dim3(kDInner / 16, kNCH), 256, 0, stream>>>(
            dt, xi, proj, A_l, D_skip + (size_t)i * kDInner, scanP, scanS, y);

        // g = y * silu(res)   (res reduce fused)
        mul_silu_kernel<<<dim3(kSeq, kDInner / 256), 256, 0, stream>>>(
            y, partsXZ, partsXZ + (size_t)kSeq * 2 * kDInner, g2);

        // x += g @ out_proj_w[i]^T   (1024 x 768, K=4608, KSPLIT=6)
        mfma_gemm<128, 128, 6><<<dim3(kSeq / 128, kDModel / 128, 6), 256, 0, stream>>>(
            g2, K3i, outw2 + (size_t)i * kDModel * K3i, K3i,
            partsO, kDModel, kDModel, K3i, (size_t)kSeq * kDModel);
        reduce_parts<6, true><<<(kSeq * kDModel / 4 + 255) / 256, 256, 0, stream>>>(
            partsO, (size_t)kSeq * kDModel, x, kSeq * kDModel);
    }

    // out = rmsnorm(x, final_norm_w) @ embedding^T  (1024 x 32000, K=768)
    rmsnorm_kernel<false><<<kSeq, 256, 0, stream>>>(x, final_norm_w, h_bf);
    mfma_gemm<128, 128, 1><<<dim3(kSeq / 128, kVocab / 128, 1), 256, 0, stream>>>(
        h_bf, kDModel, emb_bf, kDModel, out, kVocab, kVocab, kDModel, 0);
}

// Round 10
// 810.522 us; speedup vs baseline: 6.2887x; 1.0114x over previous
//
#include <hip/hip_runtime.h>
#include <hip/hip_bf16.h>
#include <cmath>

namespace {

constexpr int kL      = 4;
constexpr int kDModel = 768;
constexpr int kDInner = 1536;
constexpr int kDtRank = 48;
constexpr int kDState = 16;
constexpr int kDConv  = 4;
constexpr int kSeq    = 1024;
constexpr int kPLd    = 96;    // proj row stride (80 used)
constexpr int kPB     = 128;   // x_proj weight rows padded for BN=128
constexpr int kVocab  = 32000;
constexpr int kCH     = 64;    // scan chunk length
constexpr int kNCH    = kSeq / kCH;  // 16 chunks
constexpr int kDN     = kDInner * kDState;  // 24576 (d,n) pairs

using short8 = __attribute__((ext_vector_type(8))) short;
using f32x4  = __attribute__((ext_vector_type(4))) float;

__device__ __forceinline__ float silu_f(float v) {
    return v / (1.f + __expf(-v));
}

__device__ __forceinline__ void split_bf16(float v, __hip_bfloat16& hi, __hip_bfloat16& lo) {
    hi = __float2bfloat16(v);
    lo = __float2bfloat16(v - __bfloat162float(hi));
}

// ---------------------------------------------------------------- fp32->bf16
__global__ void __launch_bounds__(256) f2b_kernel(
    const float* __restrict__ src, __hip_bfloat16* __restrict__ dst, int n) {
    int i = (blockIdx.x * 256 + threadIdx.x) * 4;
    const int stride = gridDim.x * 256 * 4;
    for (; i + 3 < n; i += stride) {
        const float4 v = *reinterpret_cast<const float4*>(src + i);
        dst[i + 0] = __float2bfloat16(v.x);
        dst[i + 1] = __float2bfloat16(v.y);
        dst[i + 2] = __float2bfloat16(v.z);
        dst[i + 3] = __float2bfloat16(v.w);
    }
}

// -------------------------------- fp32 -> 3-term split bf16 along K
// B-side: dst row = [hi | hi | lo]; rows >= `rows` zero-filled.
__global__ void __launch_bounds__(256) split3_kernel(
    const float* __restrict__ src, int ldsrc, int rows, int cols,
    __hip_bfloat16* __restrict__ dst, int rowsPad) {
    const int idx = blockIdx.x * 256 + threadIdx.x;
    if (idx >= rowsPad * cols) return;
    const int r = idx / cols, c = idx % cols;
    const float v = (r < rows) ? src[(size_t)r * ldsrc + c] : 0.f;
    __hip_bfloat16 hi, lo;
    split_bf16(v, hi, lo);
    __hip_bfloat16* row = dst + (size_t)r * 3 * cols;
    row[c] = hi; row[cols + c] = hi; row[2 * cols + c] = lo;
}

// ------------- x_proj weights, all layers in one grid: 80 rows -> 128 padded
__global__ void __launch_bounds__(256) split3x_kernel(
    const float* __restrict__ src, __hip_bfloat16* __restrict__ dst) {
    const int idx = blockIdx.x * 256 + threadIdx.x;
    if (idx >= kL * kPB * kDInner) return;
    const int layer = idx / (kPB * kDInner);
    const int rem   = idx % (kPB * kDInner);
    const int r = rem / kDInner, c = rem % kDInner;
    const float v = (r < kDtRank + 2 * kDState)
        ? src[(size_t)layer * (kDtRank + 2 * kDState) * kDInner + (size_t)r * kDInner + c]
        : 0.f;
    __hip_bfloat16 hi, lo;
    split_bf16(v, hi, lo);
    __hip_bfloat16* row = dst + ((size_t)layer * kPB + r) * 3 * kDInner;
    row[c] = hi; row[kDInner + c] = hi; row[2 * kDInner + c] = lo;
}

// -------------------------- embed + rmsnorm(norm_w[0]) -> x, h2 (split bf16)
__global__ void __launch_bounds__(256) embed_rms_kernel(
    const int* __restrict__ tokens, const float* __restrict__ emb,
    const float* __restrict__ w, float* __restrict__ x,
    __hip_bfloat16* __restrict__ h2) {
    const int s = blockIdx.x;
    const int t = tokens[s];
    const float* src = emb + (size_t)t * kDModel;
    float v[3];
    float ss = 0.f;
    #pragma unroll
    for (int j = 0; j < 3; ++j) {
        const int d = threadIdx.x + j * 256;
        v[j] = src[d];
        x[(size_t)s * kDModel + d] = v[j];
        ss = fmaf(v[j], v[j], ss);
    }
    #pragma unroll
    for (int m = 32; m; m >>= 1) ss += __shfl_xor(ss, m);
    __shared__ float red[4];
    if ((threadIdx.x & 63) == 0) red[threadIdx.x >> 6] = ss;
    __syncthreads();
    const float total = red[0] + red[1] + red[2] + red[3];
    const float scale = rsqrtf(total / (float)kDModel + 1e-5f);
    __hip_bfloat16* dst = h2 + (size_t)s * 3 * kDModel;
    #pragma unroll
    for (int j = 0; j < 3; ++j) {
        const int d = threadIdx.x + j * 256;
        const float hv = v[j] * scale * w[d];
        __hip_bfloat16 hi, lo;
        split_bf16(hv, hi, lo);
        dst[d] = hi; dst[kDModel + d] = lo; dst[2 * kDModel + d] = hi;
    }
}

// ------- x += sum(6 out_proj partials); rmsnorm -> h2 (split) or h_bf (plain)
template <bool FINAL>
__global__ void __launch_bounds__(256) reduce_rms_kernel(
    const float* __restrict__ parts, size_t stride,
    const float* __restrict__ w, float* __restrict__ x,
    __hip_bfloat16* __restrict__ out) {
    const int s = blockIdx.x;
    float v[3];
    float ss = 0.f;
    #pragma unroll
    for (int j = 0; j < 3; ++j) {
        const int d = threadIdx.x + j * 256;
        const size_t off = (size_t)s * kDModel + d;
        float acc = x[off];
        #pragma unroll
        for (int p = 0; p < 6; ++p) acc += parts[(size_t)p * stride + off];
        v[j] = acc;
        x[off] = acc;
        ss = fmaf(acc, acc, ss);
    }
    #pragma unroll
    for (int m = 32; m; m >>= 1) ss += __shfl_xor(ss, m);
    __shared__ float red[4];
    if ((threadIdx.x & 63) == 0) red[threadIdx.x >> 6] = ss;
    __syncthreads();
    const float total = red[0] + red[1] + red[2] + red[3];
    const float scale = rsqrtf(total / (float)kDModel + 1e-5f);
    #pragma unroll
    for (int j = 0; j < 3; ++j) {
        const int d = threadIdx.x + j * 256;
        const float hv = v[j] * scale * w[d];
        if (FINAL) {
            out[(size_t)s * kDModel + d] = __float2bfloat16(hv);
        } else {
            __hip_bfloat16 hi, lo;
            split_bf16(hv, hi, lo);
            __hip_bfloat16* dst = out + (size_t)s * 3 * kDModel;
            dst[d] = hi; dst[kDModel + d] = lo; dst[2 * kDModel + d] = hi;
        }
    }
}

// ---------------------------------------------------------------- MFMA GEMM
// C[m][n] = sum_{k in split part} A[m][k]*B[n][k].  A: MxK bf16, B: NxK bf16.
// 2-phase double-buffered pipeline (round-7 measured best): prefetch
// STAGE(t+1) before compute(t); s_barrier + vmcnt(4) keeps next tile's loads
// in flight across the MFMA phase. Granule swizzle + bijective XCD swizzle.
template <int BM, int BN, int KSPLIT>
__global__ void __launch_bounds__(256) mfma_gemm(
    const __hip_bfloat16* __restrict__ A, int lda,
    const __hip_bfloat16* __restrict__ B, int ldb,
    float* __restrict__ C, int ldc,
    int N, int K, size_t partStride) {
    constexpr int BK = 32;
    static_assert(BM == 128 && BN == 128, "staging assumes 128x128");
    __shared__ unsigned short As[2][BM * BK];
    __shared__ unsigned short Bs[2][BN * BK];
    const int tid  = threadIdx.x;
    const int lane = tid & 63;

    // ---- bijective chunked XCD swizzle (m204) over the (x,y) grid ----
    const int nwg = gridDim.x * gridDim.y;
    int bid = blockIdx.y * gridDim.x + blockIdx.x;
    {
        const int q = nwg >> 3, r = nwg & 7;
        const int xcd = bid & 7, pos = bid >> 3;
        bid = (xcd < r ? xcd * (q + 1) : r * (q + 1) + (xcd - r) * q) + pos;
    }
    const int m0 = (bid % gridDim.x) * BM;   // m fast: same-n blocks adjacent
    const int n0 = (bid / gridDim.x) * BN;

    const int Kp = K / KSPLIT;
    const int kbeg = (KSPLIT > 1) ? blockIdx.z * Kp : 0;
    float* Cw = (KSPLIT > 1) ? C + (size_t)blockIdx.z * partStride : C;
    constexpr int WM = BM / 2, WN = BN / 2;   // 2x2 waves
    constexpr int MR = WM / 16, NR = WN / 16;
    const int wave = tid >> 6;
    const int wm = (wave >> 1) * WM, wn = (wave & 1) * WN;
    const int l15 = lane & 15, l4 = lane >> 4;
    f32x4 acc[MR][NR] = {};

    // stage one K-tile into buffer `buf` (4 gload_lds per thread, uniform)
    auto stage = [&](int buf, int k0) {
        #pragma unroll
        for (int i = 0; i < 2; ++i) {
            const int idx = tid + i * 256;           // A granules: BM*4 = 512
            const int r = idx >> 2, qv = idx & 3;
            const int qs = qv ^ ((r >> 1) & 3);
            __builtin_amdgcn_global_load_lds(
                (const __attribute__((address_space(1))) void*)(A + (size_t)(m0 + r) * lda + k0 + qs * 8),
                (__attribute__((address_space(3))) void*)(&As[buf][(idx - lane) * 8]),
                16, 0, 0);
        }
        #pragma unroll
        for (int i = 0; i < 2; ++i) {
            const int idx = tid + i * 256;           // B granules: BN*4 = 512
            const int r = idx >> 2, qv = idx & 3;
            const int qs = qv ^ ((r >> 1) & 3);
            __builtin_amdgcn_global_load_lds(
                (const __attribute__((address_space(1))) void*)(B + (size_t)(n0 + r) * ldb + k0 + qs * 8),
                (__attribute__((address_space(3))) void*)(&Bs[buf][(idx - lane) * 8]),
                16, 0, 0);
        }
    };

    const int nt = Kp / BK;
    int cur = 0;
    stage(0, kbeg);
    for (int t = 0; t < nt; ++t) {
        if (t + 1 < nt) {
            stage(cur ^ 1, kbeg + (t + 1) * BK);
            asm volatile("s_waitcnt vmcnt(4)" ::: "memory");  // cur landed
        } else {
            asm volatile("s_waitcnt vmcnt(0)" ::: "memory");
        }
        __builtin_amdgcn_s_barrier();

        short8 af[MR], bfv[NR];
        #pragma unroll
        for (int mi = 0; mi < MR; ++mi) {
            const int R = wm + mi * 16 + l15;
            af[mi] = *reinterpret_cast<const short8*>(&As[cur][(R * 4 + (l4 ^ ((R >> 1) & 3))) * 8]);
        }
        #pragma unroll
        for (int ni = 0; ni < NR; ++ni) {
            const int R = wn + ni * 16 + l15;
            bfv[ni] = *reinterpret_cast<const short8*>(&Bs[cur][(R * 4 + (l4 ^ ((R >> 1) & 3))) * 8]);
        }
        #pragma unroll
        for (int mi = 0; mi < MR; ++mi)
            #pragma unroll
            for (int ni = 0; ni < NR; ++ni)
                acc[mi][ni] = __builtin_amdgcn_mfma_f32_16x16x32_bf16(
                    af[mi], bfv[ni], acc[mi][ni], 0, 0, 0);

        asm volatile("s_waitcnt lgkmcnt(0)" ::: "memory");
        __builtin_amdgcn_s_barrier();                // safe to overwrite cur
        cur ^= 1;
    }

    // C/D layout: col = lane&15, row = (lane>>4)*4 + reg  (m89/m91)
    #pragma unroll
    for (int mi = 0; mi < MR; ++mi) {
        const int mrow = m0 + wm + mi * 16 + l4 * 4;
        #pragma unroll
        for (int ni = 0; ni < NR; ++ni) {
            const int ncol = n0 + wn + ni * 16 + l15;
            if (ncol >= N) continue;
            #pragma unroll
            for (int r = 0; r < 4; ++r)
                Cw[(size_t)(mrow + r) * ldc + ncol] = acc[mi][ni][r];
        }
    }
}

// ------------------------- reduce NP split-K partials: dst = sum(parts)
template <int NP>
__global__ void __launch_bounds__(256) reduce_parts(
    const float* __restrict__ parts, size_t stride,
    float* __restrict__ dst, int count) {
    const int i = (blockIdx.x * 256 + threadIdx.x) * 4;
    if (i >= count) return;
    float4 s = *reinterpret_cast<const float4*>(parts + i);
    #pragma unroll
    for (int p = 1; p < NP; ++p) {
        const float4 v = *reinterpret_cast<const float4*>(parts + (size_t)p * stride + i);
        s.x += v.x; s.y += v.y; s.z += v.z; s.w += v.w;
    }
    *reinterpret_cast<float4*>(dst + i) = s;
}

// ---------------- depthwise causal conv+silu, fused 2-part split-K reduce
__global__ void __launch_bounds__(256) conv_silu_kernel(
    const float* __restrict__ p0, const float* __restrict__ p1,
    const float* __restrict__ cw, const float* __restrict__ cb,
    float* __restrict__ xi, __hip_bfloat16* __restrict__ xi2) {
    const int s = blockIdx.x;
    const int d = blockIdx.y * 256 + threadIdx.x;
    float acc = cb[d];
    #pragma unroll
    for (int k = 0; k < kDConv; ++k) {
        const int sl = s - (kDConv - 1) + k;
        if (sl >= 0) {
            const size_t off = (size_t)sl * (2 * kDInner) + d;
            acc = fmaf(p0[off] + p1[off], cw[d * kDConv + k], acc);
        }
    }
    const float v = silu_f(acc);
    xi[(size_t)s * kDInner + d] = v;
    __hip_bfloat16 hi, lo;
    split_bf16(v, hi, lo);
    __hip_bfloat16* row = xi2 + (size_t)s * 3 * kDInner;
    row[d] = hi; row[kDInner + d] = lo; row[2 * kDInner + d] = hi;
}

// ------------------------------------------------- chunked selective scan
// recurrence: state = state * exp(exp(dt*A)) + dt*u*B ; y = <state,C> + u*Dv
// dt = softplus(proj[:, :48] @ dtw^T + bias) computed inline (fp32-exact).

// shared helper: stage proj[:, :48] + dtw tile, compute sdt[64][16]
__device__ __forceinline__ void compute_dt_tile(
    const float* __restrict__ proj, const float* __restrict__ dtw,
    const float* __restrict__ dtb, int l0, int d0, int tid,
    float (*sP)[kDtRank], float (*sdtw)[kDtRank + 1], float (*sdt)[16]) {
    for (int idx = tid; idx < kCH * kDtRank; idx += 256) {
        const int r = idx / kDtRank, c = idx % kDtRank;
        sP[r][c] = proj[(size_t)(l0 + r) * kPLd + c];
    }
    for (int idx = tid; idx < 16 * kDtRank; idx += 256) {
        const int dd = idx / kDtRank, c = idx % kDtRank;
        sdtw[dd][c] = dtw[(size_t)(d0 + dd) * kDtRank + c];
    }
    __syncthreads();
    #pragma unroll
    for (int e = 0; e < 4; ++e) {
        const int idx = tid + e * 256;
        const int r = idx >> 4, dd = idx & 15;
        float acc = dtb[d0 + dd];
        #pragma unroll
        for (int k = 0; k < kDtRank; ++k)
            acc = fmaf(sP[r][k], sdtw[dd][k], acc);
        acc = (acc > 20.f) ? acc : log1pf(__expf(acc));  // softplus
        sdt[r][dd] = acc;
    }
}

__global__ void __launch_bounds__(256) scan_part1(
    const float* __restrict__ u, const float* __restrict__ proj,
    const float* __restrict__ A_log, const float* __restrict__ dtw,
    const float* __restrict__ dtb,
    float* __restrict__ P, float* __restrict__ S) {
    __shared__ float sP[kCH][kDtRank];
    __shared__ float sdtw[16][kDtRank + 1];
    __shared__ float sdt[kCH][16], su[kCH][16], sB[kCH][16];
    const int tid = threadIdx.x;
    const int n = tid & 15, dl = tid >> 4;
    const int d0 = blockIdx.x * 16;
    const int l0 = blockIdx.y * kCH;
    for (int idx = tid; idx < kCH * 16; idx += 256) {
        const int r = idx >> 4, c = idx & 15;
        su[r][c] = u[(size_t)(l0 + r) * kDInner + d0 + c];
        sB[r][c] = proj[(size_t)(l0 + r) * kPLd + kDtRank + c];
    }
    compute_dt_tile(proj, dtw, dtb, l0, d0, tid, sP, sdtw, sdt);
    __syncthreads();
    const int d = d0 + dl;
    const float Adn = -__expf(A_log[d * kDState + n]);
    float state = 0.f, sumA = 0.f;
    #pragma unroll 8
    for (int l = 0; l < kCH; ++l) {
        const float dtv = sdt[l][dl];
        const float adelta = __expf(dtv * Adn);
        const float mult = __expf(adelta);
        state = fmaf(state, mult, dtv * su[l][dl] * sB[l][n]);
        sumA += adelta;
    }
    const int dn = d * kDState + n;
    P[(size_t)blockIdx.y * kDN + dn] = __expf(sumA);
    S[(size_t)blockIdx.y * kDN + dn] = state;
}

// part2: inline chunk-prefix, chunk scan, then g2 = y * silu(res) (fused)
__global__ void __launch_bounds__(256) scan_part2(
    const float* __restrict__ u, const float* __restrict__ proj,
    const float* __restrict__ A_log, const float* __restrict__ dtw,
    const float* __restrict__ dtb, const float* __restrict__ D_skip,
    const float* __restrict__ P, const float* __restrict__ S,
    const float* __restrict__ res0, const float* __restrict__ res1,
    __hip_bfloat16* __restrict__ g2) {
    __shared__ float sP[kCH][kDtRank];
    __shared__ float sdtw[16][kDtRank + 1];
    __shared__ float sdt[kCH][16], su[kCH][16], sB[kCH][16], sC[kCH][16];
    __shared__ float sy[kCH][16];
    const int tid = threadIdx.x;
    const int n = tid & 15, dl = tid >> 4;
    const int d0 = blockIdx.x * 16;
    const int l0 = blockIdx.y * kCH;
    for (int idx = tid; idx < kCH * 16; idx += 256) {
        const int r = idx >> 4, c = idx & 15;
        su[r][c] = u[(size_t)(l0 + r) * kDInner + d0 + c];
        sB[r][c] = proj[(size_t)(l0 + r) * kPLd + kDtRank + c];
        sC[r][c] = proj[(size_t)(l0 + r) * kPLd + kDtRank + kDState + c];
    }
    compute_dt_tile(proj, dtw, dtb, l0, d0, tid, sP, sdtw, sdt);
    // inline prefix: state entering chunk blockIdx.y for this thread's dn
    const int dn = d0 * kDState + tid;   // == (d0+dl)*16 + n
    float state = 0.f;
    for (int jj = 0; jj < (int)blockIdx.y; ++jj) {
        const size_t idx = (size_t)jj * kDN + dn;
        state = fmaf(state, P[idx], S[idx]);
    }
    __syncthreads();
    const int d = d0 + dl;
    const float Adn = -__expf(A_log[d * kDState + n]);
    const float Dv  = D_skip[d];
    for (int l = 0; l < kCH; ++l) {
        const float dtv = sdt[l][dl];
        const float uv  = su[l][dl];
        const float mult = __expf(__expf(dtv * Adn));
        state = fmaf(state, mult, dtv * uv * sB[l][n]);
        float contrib = state * sC[l][n];
        contrib += __shfl_xor(contrib, 8);
        contrib += __shfl_xor(contrib, 4);
        contrib += __shfl_xor(contrib, 2);
        contrib += __shfl_xor(contrib, 1);
        if (n == 0) sy[l][dl] = fmaf(uv, Dv, contrib);
    }
    __syncthreads();
    // fused: g = y * silu(res), 3-term split bf16
    for (int idx = tid; idx < kCH * 16; idx += 256) {
        const int r = idx >> 4, c = idx & 15;
        const size_t roff = (size_t)(l0 + r) * (2 * kDInner) + kDInner + d0 + c;
        const float res = res0[roff] + res1[roff];
        const float v = sy[r][c] * silu_f(res);
        __hip_bfloat16 hi, lo;
        split_bf16(v, hi, lo);
        __hip_bfloat16* row = g2 + (size_t)(l0 + r) * 3 * kDInner;
        row[d0 + c] = hi; row[kDInner + d0 + c] = lo; row[2 * kDInner + d0 + c] = hi;
    }
}

}  // namespace

extern "C" void kernel_launch(void* const* d_in, const int* in_sizes, int n_in,
                              void* d_out, int out_size, void* d_ws, size_t ws_size,
                              hipStream_t stream) {
    const int*   tokens       = (const int*)d_in[0];
    const float* embedding    = (const float*)d_in[1];
    const float* norm_w       = (const float*)d_in[2];
    const float* in_proj_w    = (const float*)d_in[3];
    const float* conv_w       = (const float*)d_in[4];
    const float* conv_b       = (const float*)d_in[5];
    const float* x_proj_w     = (const float*)d_in[6];
    const float* dt_proj_w    = (const float*)d_in[7];
    const float* dt_proj_b    = (const float*)d_in[8];
    const float* A_log        = (const float*)d_in[9];
    const float* D_skip       = (const float*)d_in[10];
    const float* out_proj_w   = (const float*)d_in[11];
    const float* final_norm_w = (const float*)d_in[12];
    float* out = (float*)d_out;

    constexpr int K3m = 3 * kDModel;   // 2304
    constexpr int K3i = 3 * kDInner;   // 4608

    char* ws = (char*)d_ws;
    auto alloc = [&](size_t bytes) { char* p = ws; ws += (bytes + 255) & ~(size_t)255; return p; };
    float* x    = (float*)alloc((size_t)kSeq * kDModel * 4);
    float* xi   = (float*)alloc((size_t)kSeq * kDInner * 4);
    float* proj = (float*)alloc((size_t)kSeq * kPLd * 4);
    float* scanP  = (float*)alloc((size_t)kNCH * kDN * 4);
    float* scanS  = (float*)alloc((size_t)kNCH * kDN * 4);
    float* partsXZ = (float*)alloc((size_t)2 * kSeq * 2 * kDInner * 4);  // in_proj partials (live to scan2)
    float* partsP  = (float*)alloc((size_t)24 * kSeq * kPLd * 4);        // x_proj partials
    float* partsO  = (float*)alloc((size_t)6 * kSeq * kDModel * 4);      // out_proj partials
    __hip_bfloat16* h_bf   = (__hip_bfloat16*)alloc((size_t)kSeq * kDModel * 2);
    __hip_bfloat16* h2     = (__hip_bfloat16*)alloc((size_t)kSeq * K3m * 2);
    __hip_bfloat16* xi2    = (__hip_bfloat16*)alloc((size_t)kSeq * K3i * 2);
    __hip_bfloat16* g2     = (__hip_bfloat16*)alloc((size_t)kSeq * K3i * 2);
    __hip_bfloat16* emb_bf = (__hip_bfloat16*)alloc((size_t)kVocab * kDModel * 2);
    __hip_bfloat16* inw2   = (__hip_bfloat16*)alloc((size_t)kL * 2 * kDInner * K3m * 2);
    __hip_bfloat16* outw2  = (__hip_bfloat16*)alloc((size_t)kL * kDModel * K3i * 2);
    __hip_bfloat16* xw2    = (__hip_bfloat16*)alloc((size_t)kL * kPB * K3i * 2);

    // ---- weight conversions (per call; layer dims are contiguous) ----
    f2b_kernel<<<4096, 256, 0, stream>>>(embedding, emb_bf, kVocab * kDModel);
    split3_kernel<<<(kL * 2 * kDInner * kDModel + 255) / 256, 256, 0, stream>>>(
        in_proj_w, kDModel, kL * 2 * kDInner, kDModel, inw2, kL * 2 * kDInner);
    split3_kernel<<<(kL * kDModel * kDInner + 255) / 256, 256, 0, stream>>>(
        out_proj_w, kDInner, kL * kDModel, kDInner, outw2, kL * kDModel);
    split3x_kernel<<<(kL * kPB * kDInner + 255) / 256, 256, 0, stream>>>(
        x_proj_w, xw2);

    // x = embed; h2 = split-rmsnorm(x, norm_w[0])
    embed_rms_kernel<<<kSeq, 256, 0, stream>>>(tokens, embedding, norm_w, x, h2);

    for (int i = 0; i < kL; ++i) {
        // xz partials = h @ in_proj_w[i]^T  (1024 x 3072, K=2304, KSPLIT=2)
        mfma_gemm<128, 128, 2><<<dim3(kSeq / 128, 2 * kDInner / 128, 2), 256, 0, stream>>>(
            h2, K3m, inw2 + (size_t)i * 2 * kDInner * K3m, K3m,
            partsXZ, 2 * kDInner, 2 * kDInner, K3m, (size_t)kSeq * 2 * kDInner);

        // xi = silu(conv(sum(parts)[:, :1536]) + b)   (reduce fused)
        conv_silu_kernel<<<dim3(kSeq, kDInner / 256), 256, 0, stream>>>(
            partsXZ, partsXZ + (size_t)kSeq * 2 * kDInner,
            conv_w + (size_t)i * kDInner * kDConv, conv_b + (size_t)i * kDInner,
            xi, xi2);

        // proj = xi @ x_proj_w[i]^T   (1024 x 128pad, K=4608, KSPLIT=24)
        mfma_gemm<128, 128, 24><<<dim3(kSeq / 128, 1, 24), 256, 0, stream>>>(
            xi2, K3i, xw2 + (size_t)i * kPB * K3i, K3i,
            partsP, kPLd, kPLd, K3i, (size_t)kSeq * kPLd);
        reduce_parts<24><<<(kSeq * kPLd / 4 + 255) / 256, 256, 0, stream>>>(
            partsP, (size_t)kSeq * kPLd, proj, kSeq * kPLd);

        // selective scan (dt inline, mul_silu fused into part2)
        const float* A_l  = A_log + (size_t)i * kDInner * kDState;
        const float* dtw  = dt_proj_w + (size_t)i * kDInner * kDtRank;
        const float* dtb  = dt_proj_b + (size_t)i * kDInner;
        scan_part1<<<dim3(kDInner / 16, kNCH), 256, 0, stream>>>(
            xi, proj, A_l, dtw, dtb, scanP, scanS);
        scan_part2<<<dim3(kDInner / 16, kNCH), 256, 0, stream>>>(
            xi, proj, A_l, dtw, dtb, D_skip + (size_t)i * kDInner,
            scanP, scanS, partsXZ, partsXZ + (size_t)kSeq * 2 * kDInner, g2);

        // out_proj partials = g @ out_proj_w[i]^T  (1024 x 768, K=4608, KSPLIT=6)
        mfma_gemm<128, 128, 6><<<dim3(kSeq / 128, kDModel / 128, 6), 256, 0, stream>>>(
            g2, K3i, outw2 + (size_t)i * kDModel * K3i, K3i,
            partsO, kDModel, kDModel, K3i, (size_t)kSeq * kDModel);

        // x += sum(partsO); rmsnorm -> h2 (next layer) or h_bf (final)
        if (i + 1 < kL) {
            reduce_rms_kernel<false><<<kSeq, 256, 0, stream>>>(
                partsO, (size_t)kSeq * kDModel, norm_w + (size_t)(i + 1) * kDModel, x, h2);
        } else {
            reduce_rms_kernel<true><<<kSeq, 256, 0, stream>>>(
                partsO, (size_t)kSeq * kDModel, final_norm_w, x, h_bf);
        }
    }

    // out = h_bf @ embedding^T   (1024 x 32000, K=768)
    mfma_gemm<128, 128, 1><<<dim3(kSeq / 128, kVocab / 128, 1), 256, 0, stream>>>(
        h_bf, kDModel, emb_bf, kDModel, out, kVocab, kVocab, kDModel, 0);
}

// Round 12
// 777.574 us; speedup vs baseline: 6.5552x; 1.0424x over previous
//
#include <hip/hip_runtime.h>
#include <hip/hip_bf16.h>
#include <cmath>

namespace {

constexpr int kL      = 4;
constexpr int kDModel = 768;
constexpr int kDInner = 1536;
constexpr int kDtRank = 48;
constexpr int kDState = 16;
constexpr int kDConv  = 4;
constexpr int kSeq    = 1024;
constexpr int kPLd    = 96;    // proj row stride (80 used)
constexpr int kPB     = 128;   // x_proj weight rows padded for BN=128
constexpr int kVocab  = 32000;
constexpr int kCH     = 64;    // scan chunk length
constexpr int kNCH    = kSeq / kCH;  // 16 chunks
constexpr int kDN     = kDInner * kDState;  // 24576 (d,n) pairs

using short8 = __attribute__((ext_vector_type(8))) short;
using f32x4  = __attribute__((ext_vector_type(4))) float;

__device__ __forceinline__ float silu_f(float v) {
    return v / (1.f + __expf(-v));
}

__device__ __forceinline__ void split_bf16(float v, __hip_bfloat16& hi, __hip_bfloat16& lo) {
    hi = __float2bfloat16(v);
    lo = __float2bfloat16(v - __bfloat162float(hi));
}

// ---------------------------------------------------------------- fp32->bf16
__global__ void __launch_bounds__(256) f2b_kernel(
    const float* __restrict__ src, __hip_bfloat16* __restrict__ dst, int n) {
    int i = (blockIdx.x * 256 + threadIdx.x) * 4;
    const int stride = gridDim.x * 256 * 4;
    for (; i + 3 < n; i += stride) {
        const float4 v = *reinterpret_cast<const float4*>(src + i);
        dst[i + 0] = __float2bfloat16(v.x);
        dst[i + 1] = __float2bfloat16(v.y);
        dst[i + 2] = __float2bfloat16(v.z);
        dst[i + 3] = __float2bfloat16(v.w);
    }
}

// -------------------------------- fp32 -> 3-term split bf16 along K
// B-side: dst row = [hi | hi | lo]; rows >= `rows` zero-filled.
__global__ void __launch_bounds__(256) split3_kernel(
    const float* __restrict__ src, int ldsrc, int rows, int cols,
    __hip_bfloat16* __restrict__ dst, int rowsPad) {
    const int idx = blockIdx.x * 256 + threadIdx.x;
    if (idx >= rowsPad * cols) return;
    const int r = idx / cols, c = idx % cols;
    const float v = (r < rows) ? src[(size_t)r * ldsrc + c] : 0.f;
    __hip_bfloat16 hi, lo;
    split_bf16(v, hi, lo);
    __hip_bfloat16* row = dst + (size_t)r * 3 * cols;
    row[c] = hi; row[cols + c] = hi; row[2 * cols + c] = lo;
}

// ------------------- fp32 -> duplicated bf16 hi along K: row = [hi | hi]
// (B-side of a 2-term activation-exact split: (ah+al)*bh)
__global__ void __launch_bounds__(256) dup2_kernel(
    const float* __restrict__ src, __hip_bfloat16* __restrict__ dst, int rows, int cols) {
    const int idx = blockIdx.x * 256 + threadIdx.x;
    if (idx >= rows * cols) return;
    const int r = idx / cols, c = idx % cols;
    const __hip_bfloat16 hi = __float2bfloat16(src[(size_t)r * cols + c]);
    __hip_bfloat16* row = dst + (size_t)r * 2 * cols;
    row[c] = hi; row[cols + c] = hi;
}

// ------------- x_proj weights, all layers in one grid: 80 rows -> 128 padded
__global__ void __launch_bounds__(256) split3x_kernel(
    const float* __restrict__ src, __hip_bfloat16* __restrict__ dst) {
    const int idx = blockIdx.x * 256 + threadIdx.x;
    if (idx >= kL * kPB * kDInner) return;
    const int layer = idx / (kPB * kDInner);
    const int rem   = idx % (kPB * kDInner);
    const int r = rem / kDInner, c = rem % kDInner;
    const float v = (r < kDtRank + 2 * kDState)
        ? src[(size_t)layer * (kDtRank + 2 * kDState) * kDInner + (size_t)r * kDInner + c]
        : 0.f;
    __hip_bfloat16 hi, lo;
    split_bf16(v, hi, lo);
    __hip_bfloat16* row = dst + ((size_t)layer * kPB + r) * 3 * kDInner;
    row[c] = hi; row[kDInner + c] = hi; row[2 * kDInner + c] = lo;
}

// -------------------------- embed + rmsnorm(norm_w[0]) -> x, h2 (split bf16)
__global__ void __launch_bounds__(256) embed_rms_kernel(
    const int* __restrict__ tokens, const float* __restrict__ emb,
    const float* __restrict__ w, float* __restrict__ x,
    __hip_bfloat16* __restrict__ h2) {
    const int s = blockIdx.x;
    const int t = tokens[s];
    const float* src = emb + (size_t)t * kDModel;
    float v[3];
    float ss = 0.f;
    #pragma unroll
    for (int j = 0; j < 3; ++j) {
        const int d = threadIdx.x + j * 256;
        v[j] = src[d];
        x[(size_t)s * kDModel + d] = v[j];
        ss = fmaf(v[j], v[j], ss);
    }
    #pragma unroll
    for (int m = 32; m; m >>= 1) ss += __shfl_xor(ss, m);
    __shared__ float red[4];
    if ((threadIdx.x & 63) == 0) red[threadIdx.x >> 6] = ss;
    __syncthreads();
    const float total = red[0] + red[1] + red[2] + red[3];
    const float scale = rsqrtf(total / (float)kDModel + 1e-5f);
    __hip_bfloat16* dst = h2 + (size_t)s * 3 * kDModel;
    #pragma unroll
    for (int j = 0; j < 3; ++j) {
        const int d = threadIdx.x + j * 256;
        const float hv = v[j] * scale * w[d];
        __hip_bfloat16 hi, lo;
        split_bf16(hv, hi, lo);
        dst[d] = hi; dst[kDModel + d] = lo; dst[2 * kDModel + d] = hi;
    }
}

// ------- x += sum(6 out_proj partials); rmsnorm -> h2 (split) or h_bf (plain)
template <bool FINAL>
__global__ void __launch_bounds__(256) reduce_rms_kernel(
    const float* __restrict__ parts, size_t stride,
    const float* __restrict__ w, float* __restrict__ x,
    __hip_bfloat16* __restrict__ out) {
    const int s = blockIdx.x;
    float v[3];
    float ss = 0.f;
    #pragma unroll
    for (int j = 0; j < 3; ++j) {
        const int d = threadIdx.x + j * 256;
        const size_t off = (size_t)s * kDModel + d;
        float acc = x[off];
        #pragma unroll
        for (int p = 0; p < 6; ++p) acc += parts[(size_t)p * stride + off];
        v[j] = acc;
        x[off] = acc;
        ss = fmaf(acc, acc, ss);
    }
    #pragma unroll
    for (int m = 32; m; m >>= 1) ss += __shfl_xor(ss, m);
    __shared__ float red[4];
    if ((threadIdx.x & 63) == 0) red[threadIdx.x >> 6] = ss;
    __syncthreads();
    const float total = red[0] + red[1] + red[2] + red[3];
    const float scale = rsqrtf(total / (float)kDModel + 1e-5f);
    #pragma unroll
    for (int j = 0; j < 3; ++j) {
        const int d = threadIdx.x + j * 256;
        const float hv = v[j] * scale * w[d];
        if (FINAL) {
            out[(size_t)s * kDModel + d] = __float2bfloat16(hv);
        } else {
            __hip_bfloat16 hi, lo;
            split_bf16(hv, hi, lo);
            __hip_bfloat16* dst = out + (size_t)s * 3 * kDModel;
            dst[d] = hi; dst[kDModel + d] = lo; dst[2 * kDModel + d] = hi;
        }
    }
}

// ---------------------------------------------------------------- MFMA GEMM
// C[m][n] = sum_{k in split part} A[m][k]*B[n][k].  A: MxK bf16, B: NxK bf16.
// 2-phase double-buffered pipeline (round-7 measured best): prefetch
// STAGE(t+1) before compute(t); s_barrier + vmcnt(4) keeps next tile's loads
// in flight across the MFMA phase. Granule swizzle + bijective XCD swizzle.
template <int BM, int BN, int KSPLIT>
__global__ void __launch_bounds__(256) mfma_gemm(
    const __hip_bfloat16* __restrict__ A, int lda,
    const __hip_bfloat16* __restrict__ B, int ldb,
    float* __restrict__ C, int ldc,
    int N, int K, size_t partStride) {
    constexpr int BK = 32;
    static_assert(BM == 128 && BN == 128, "staging assumes 128x128");
    __shared__ unsigned short As[2][BM * BK];
    __shared__ unsigned short Bs[2][BN * BK];
    const int tid  = threadIdx.x;
    const int lane = tid & 63;

    // ---- bijective chunked XCD swizzle (m204) over the (x,y) grid ----
    const int nwg = gridDim.x * gridDim.y;
    int bid = blockIdx.y * gridDim.x + blockIdx.x;
    {
        const int q = nwg >> 3, r = nwg & 7;
        const int xcd = bid & 7, pos = bid >> 3;
        bid = (xcd < r ? xcd * (q + 1) : r * (q + 1) + (xcd - r) * q) + pos;
    }
    const int m0 = (bid % gridDim.x) * BM;   // m fast: same-n blocks adjacent
    const int n0 = (bid / gridDim.x) * BN;

    const int Kp = K / KSPLIT;
    const int kbeg = (KSPLIT > 1) ? blockIdx.z * Kp : 0;
    float* Cw = (KSPLIT > 1) ? C + (size_t)blockIdx.z * partStride : C;
    constexpr int WM = BM / 2, WN = BN / 2;   // 2x2 waves
    constexpr int MR = WM / 16, NR = WN / 16;
    const int wave = tid >> 6;
    const int wm = (wave >> 1) * WM, wn = (wave & 1) * WN;
    const int l15 = lane & 15, l4 = lane >> 4;
    f32x4 acc[MR][NR] = {};

    // stage one K-tile into buffer `buf` (4 gload_lds per thread, uniform)
    auto stage = [&](int buf, int k0) {
        #pragma unroll
        for (int i = 0; i < 2; ++i) {
            const int idx = tid + i * 256;           // A granules: BM*4 = 512
            const int r = idx >> 2, qv = idx & 3;
            const int qs = qv ^ ((r >> 1) & 3);
            __builtin_amdgcn_global_load_lds(
                (const __attribute__((address_space(1))) void*)(A + (size_t)(m0 + r) * lda + k0 + qs * 8),
                (__attribute__((address_space(3))) void*)(&As[buf][(idx - lane) * 8]),
                16, 0, 0);
        }
        #pragma unroll
        for (int i = 0; i < 2; ++i) {
            const int idx = tid + i * 256;           // B granules: BN*4 = 512
            const int r = idx >> 2, qv = idx & 3;
            const int qs = qv ^ ((r >> 1) & 3);
            __builtin_amdgcn_global_load_lds(
                (const __attribute__((address_space(1))) void*)(B + (size_t)(n0 + r) * ldb + k0 + qs * 8),
                (__attribute__((address_space(3))) void*)(&Bs[buf][(idx - lane) * 8]),
                16, 0, 0);
        }
    };

    const int nt = Kp / BK;
    int cur = 0;
    stage(0, kbeg);
    for (int t = 0; t < nt; ++t) {
        if (t + 1 < nt) {
            stage(cur ^ 1, kbeg + (t + 1) * BK);
            asm volatile("s_waitcnt vmcnt(4)" ::: "memory");  // cur landed
        } else {
            asm volatile("s_waitcnt vmcnt(0)" ::: "memory");
        }
        __builtin_amdgcn_s_barrier();

        short8 af[MR], bfv[NR];
        #pragma unroll
        for (int mi = 0; mi < MR; ++mi) {
            const int R = wm + mi * 16 + l15;
            af[mi] = *reinterpret_cast<const short8*>(&As[cur][(R * 4 + (l4 ^ ((R >> 1) & 3))) * 8]);
        }
        #pragma unroll
        for (int ni = 0; ni < NR; ++ni) {
            const int R = wn + ni * 16 + l15;
            bfv[ni] = *reinterpret_cast<const short8*>(&Bs[cur][(R * 4 + (l4 ^ ((R >> 1) & 3))) * 8]);
        }
        #pragma unroll
        for (int mi = 0; mi < MR; ++mi)
            #pragma unroll
            for (int ni = 0; ni < NR; ++ni)
                acc[mi][ni] = __builtin_amdgcn_mfma_f32_16x16x32_bf16(
                    af[mi], bfv[ni], acc[mi][ni], 0, 0, 0);

        asm volatile("s_waitcnt lgkmcnt(0)" ::: "memory");
        __builtin_amdgcn_s_barrier();                // safe to overwrite cur
        cur ^= 1;
    }

    // C/D layout: col = lane&15, row = (lane>>4)*4 + reg  (m89/m91)
    #pragma unroll
    for (int mi = 0; mi < MR; ++mi) {
        const int mrow = m0 + wm + mi * 16 + l4 * 4;
        #pragma unroll
        for (int ni = 0; ni < NR; ++ni) {
            const int ncol = n0 + wn + ni * 16 + l15;
            if (ncol >= N) continue;
            #pragma unroll
            for (int r = 0; r < 4; ++r)
                Cw[(size_t)(mrow + r) * ldc + ncol] = acc[mi][ni][r];
        }
    }
}

// ------------------------- reduce NP split-K partials: dst = sum(parts)
template <int NP>
__global__ void __launch_bounds__(256) reduce_parts(
    const float* __restrict__ parts, size_t stride,
    float* __restrict__ dst, int count) {
    const int i = (blockIdx.x * 256 + threadIdx.x) * 4;
    if (i >= count) return;
    float4 s = *reinterpret_cast<const float4*>(parts + i);
    #pragma unroll
    for (int p = 1; p < NP; ++p) {
        const float4 v = *reinterpret_cast<const float4*>(parts + (size_t)p * stride + i);
        s.x += v.x; s.y += v.y; s.z += v.z; s.w += v.w;
    }
    *reinterpret_cast<float4*>(dst + i) = s;
}

// ---------------- depthwise causal conv+silu, fused 2-part split-K reduce
__global__ void __launch_bounds__(256) conv_silu_kernel(
    const float* __restrict__ p0, const float* __restrict__ p1,
    const float* __restrict__ cw, const float* __restrict__ cb,
    float* __restrict__ xi, __hip_bfloat16* __restrict__ xi2) {
    const int s = blockIdx.x;
    const int d = blockIdx.y * 256 + threadIdx.x;
    float acc = cb[d];
    #pragma unroll
    for (int k = 0; k < kDConv; ++k) {
        const int sl = s - (kDConv - 1) + k;
        if (sl >= 0) {
            const size_t off = (size_t)sl * (2 * kDInner) + d;
            acc = fmaf(p0[off] + p1[off], cw[d * kDConv + k], acc);
        }
    }
    const float v = silu_f(acc);
    xi[(size_t)s * kDInner + d] = v;
    __hip_bfloat16 hi, lo;
    split_bf16(v, hi, lo);
    __hip_bfloat16* row = xi2 + (size_t)s * 3 * kDInner;
    row[d] = hi; row[kDInner + d] = lo; row[2 * kDInner + d] = hi;
}

// ------------------------------------------------- chunked selective scan
// recurrence: state = state * exp(exp(dt*A)) + dt*u*B ; y = <state,C> + u*Dv
// dt = softplus(proj[:, :48] @ dtw^T + bias) computed inline (fp32-exact).

// shared helper: stage proj[:, :48] + dtw tile, compute sdt[64][16]
__device__ __forceinline__ void compute_dt_tile(
    const float* __restrict__ proj, const float* __restrict__ dtw,
    const float* __restrict__ dtb, int l0, int d0, int tid,
    float (*sP)[kDtRank], float (*sdtw)[kDtRank + 1], float (*sdt)[16]) {
    for (int idx = tid; idx < kCH * kDtRank; idx += 256) {
        const int r = idx / kDtRank, c = idx % kDtRank;
        sP[r][c] = proj[(size_t)(l0 + r) * kPLd + c];
    }
    for (int idx = tid; idx < 16 * kDtRank; idx += 256) {
        const int dd = idx / kDtRank, c = idx % kDtRank;
        sdtw[dd][c] = dtw[(size_t)(d0 + dd) * kDtRank + c];
    }
    __syncthreads();
    #pragma unroll
    for (int e = 0; e < 4; ++e) {
        const int idx = tid + e * 256;
        const int r = idx >> 4, dd = idx & 15;
        float acc = dtb[d0 + dd];
        #pragma unroll
        for (int k = 0; k < kDtRank; ++k)
            acc = fmaf(sP[r][k], sdtw[dd][k], acc);
        acc = (acc > 20.f) ? acc : log1pf(__expf(acc));  // softplus
        sdt[r][dd] = acc;
    }
}

__global__ void __launch_bounds__(256) scan_part1(
    const float* __restrict__ u, const float* __restrict__ proj,
    const float* __restrict__ A_log, const float* __restrict__ dtw,
    const float* __restrict__ dtb,
    float* __restrict__ P, float* __restrict__ S) {
    __shared__ float sP[kCH][kDtRank];
    __shared__ float sdtw[16][kDtRank + 1];
    __shared__ float sdt[kCH][16], su[kCH][16], sB[kCH][16];
    const int tid = threadIdx.x;
    const int n = tid & 15, dl = tid >> 4;
    const int d0 = blockIdx.x * 16;
    const int l0 = blockIdx.y * kCH;
    for (int idx = tid; idx < kCH * 16; idx += 256) {
        const int r = idx >> 4, c = idx & 15;
        su[r][c] = u[(size_t)(l0 + r) * kDInner + d0 + c];
        sB[r][c] = proj[(size_t)(l0 + r) * kPLd + kDtRank + c];
    }
    compute_dt_tile(proj, dtw, dtb, l0, d0, tid, sP, sdtw, sdt);
    __syncthreads();
    const int d = d0 + dl;
    const float Adn = -__expf(A_log[d * kDState + n]);
    float state = 0.f, sumA = 0.f;
    #pragma unroll 8
    for (int l = 0; l < kCH; ++l) {
        const float dtv = sdt[l][dl];
        const float adelta = __expf(dtv * Adn);
        const float mult = __expf(adelta);
        state = fmaf(state, mult, dtv * su[l][dl] * sB[l][n]);
        sumA += adelta;
    }
    const int dn = d * kDState + n;
    P[(size_t)blockIdx.y * kDN + dn] = __expf(sumA);
    S[(size_t)blockIdx.y * kDN + dn] = state;
}

// part2: inline chunk-prefix, chunk scan, then g = y * silu(res) fused,
// written as 2-term split [hi | lo] (activation-exact out_proj input)
__global__ void __launch_bounds__(256) scan_part2(
    const float* __restrict__ u, const float* __restrict__ proj,
    const float* __restrict__ A_log, const float* __restrict__ dtw,
    const float* __restrict__ dtb, const float* __restrict__ D_skip,
    const float* __restrict__ P, const float* __restrict__ S,
    const float* __restrict__ res0, const float* __restrict__ res1,
    __hip_bfloat16* __restrict__ g2) {
    __shared__ float sP[kCH][kDtRank];
    __shared__ float sdtw[16][kDtRank + 1];
    __shared__ float sdt[kCH][16], su[kCH][16], sB[kCH][16], sC[kCH][16];
    __shared__ float sy[kCH][16];
    const int tid = threadIdx.x;
    const int n = tid & 15, dl = tid >> 4;
    const int d0 = blockIdx.x * 16;
    const int l0 = blockIdx.y * kCH;
    for (int idx = tid; idx < kCH * 16; idx += 256) {
        const int r = idx >> 4, c = idx & 15;
        su[r][c] = u[(size_t)(l0 + r) * kDInner + d0 + c];
        sB[r][c] = proj[(size_t)(l0 + r) * kPLd + kDtRank + c];
        sC[r][c] = proj[(size_t)(l0 + r) * kPLd + kDtRank + kDState + c];
    }
    compute_dt_tile(proj, dtw, dtb, l0, d0, tid, sP, sdtw, sdt);
    // inline prefix: state entering chunk blockIdx.y for this thread's dn
    const int dn = d0 * kDState + tid;   // == (d0+dl)*16 + n
    float state = 0.f;
    for (int jj = 0; jj < (int)blockIdx.y; ++jj) {
        const size_t idx = (size_t)jj * kDN + dn;
        state = fmaf(state, P[idx], S[idx]);
    }
    __syncthreads();
    const int d = d0 + dl;
    const float Adn = -__expf(A_log[d * kDState + n]);
    const float Dv  = D_skip[d];
    for (int l = 0; l < kCH; ++l) {
        const float dtv = sdt[l][dl];
        const float uv  = su[l][dl];
        const float mult = __expf(__expf(dtv * Adn));
        state = fmaf(state, mult, dtv * uv * sB[l][n]);
        float contrib = state * sC[l][n];
        contrib += __shfl_xor(contrib, 8);
        contrib += __shfl_xor(contrib, 4);
        contrib += __shfl_xor(contrib, 2);
        contrib += __shfl_xor(contrib, 1);
        if (n == 0) sy[l][dl] = fmaf(uv, Dv, contrib);
    }
    __syncthreads();
    // fused: g = y * silu(res), 2-term split [hi | lo]
    for (int idx = tid; idx < kCH * 16; idx += 256) {
        const int r = idx >> 4, c = idx & 15;
        const size_t roff = (size_t)(l0 + r) * (2 * kDInner) + kDInner + d0 + c;
        const float res = res0[roff] + res1[roff];
        const float v = sy[r][c] * silu_f(res);
        __hip_bfloat16 hi, lo;
        split_bf16(v, hi, lo);
        __hip_bfloat16* row = g2 + (size_t)(l0 + r) * 2 * kDInner;
        row[d0 + c] = hi; row[kDInner + d0 + c] = lo;
    }
}

}  // namespace

extern "C" void kernel_launch(void* const* d_in, const int* in_sizes, int n_in,
                              void* d_out, int out_size, void* d_ws, size_t ws_size,
                              hipStream_t stream) {
    const int*   tokens       = (const int*)d_in[0];
    const float* embedding    = (const float*)d_in[1];
    const float* norm_w       = (const float*)d_in[2];
    const float* in_proj_w    = (const float*)d_in[3];
    const float* conv_w       = (const float*)d_in[4];
    const float* conv_b       = (const float*)d_in[5];
    const float* x_proj_w     = (const float*)d_in[6];
    const float* dt_proj_w    = (const float*)d_in[7];
    const float* dt_proj_b    = (const float*)d_in[8];
    const float* A_log        = (const float*)d_in[9];
    const float* D_skip       = (const float*)d_in[10];
    const float* out_proj_w   = (const float*)d_in[11];
    const float* final_norm_w = (const float*)d_in[12];
    float* out = (float*)d_out;

    constexpr int K3m = 3 * kDModel;   // 2304
    constexpr int K3i = 3 * kDInner;   // 4608
    constexpr int K2i = 2 * kDInner;   // 3072 (out_proj 2-term)

    char* ws = (char*)d_ws;
    auto alloc = [&](size_t bytes) { char* p = ws; ws += (bytes + 255) & ~(size_t)255; return p; };
    float* x    = (float*)alloc((size_t)kSeq * kDModel * 4);
    float* xi   = (float*)alloc((size_t)kSeq * kDInner * 4);
    float* proj = (float*)alloc((size_t)kSeq * kPLd * 4);
    float* scanP  = (float*)alloc((size_t)kNCH * kDN * 4);
    float* scanS  = (float*)alloc((size_t)kNCH * kDN * 4);
    float* partsXZ = (float*)alloc((size_t)2 * kSeq * 2 * kDInner * 4);  // in_proj partials (live to scan2)
    float* partsP  = (float*)alloc((size_t)24 * kSeq * kPLd * 4);        // x_proj partials
    float* partsO  = (float*)alloc((size_t)6 * kSeq * kDModel * 4);      // out_proj partials
    __hip_bfloat16* h_bf   = (__hip_bfloat16*)alloc((size_t)kSeq * kDModel * 2);
    __hip_bfloat16* h2     = (__hip_bfloat16*)alloc((size_t)kSeq * K3m * 2);
    __hip_bfloat16* xi2    = (__hip_bfloat16*)alloc((size_t)kSeq * K3i * 2);
    __hip_bfloat16* g2     = (__hip_bfloat16*)alloc((size_t)kSeq * K2i * 2);
    __hip_bfloat16* emb_bf = (__hip_bfloat16*)alloc((size_t)kVocab * kDModel * 2);
    __hip_bfloat16* inw2   = (__hip_bfloat16*)alloc((size_t)kL * 2 * kDInner * K3m * 2);
    __hip_bfloat16* outw2  = (__hip_bfloat16*)alloc((size_t)kL * kDModel * K2i * 2);
    __hip_bfloat16* xw2    = (__hip_bfloat16*)alloc((size_t)kL * kPB * K3i * 2);

    // ---- weight conversions (per call; layer dims are contiguous) ----
    f2b_kernel<<<4096, 256, 0, stream>>>(embedding, emb_bf, kVocab * kDModel);
    dup2_kernel<<<(kL * kDModel * kDInner + 255) / 256, 256, 0, stream>>>(
        out_proj_w, outw2, kL * kDModel, kDInner);
    split3_kernel<<<(kL * 2 * kDInner * kDModel + 255) / 256, 256, 0, stream>>>(
        in_proj_w, kDModel, kL * 2 * kDInner, kDModel, inw2, kL * 2 * kDInner);
    split3x_kernel<<<(kL * kPB * kDInner + 255) / 256, 256, 0, stream>>>(
        x_proj_w, xw2);

    // x = embed; h2 = split-rmsnorm(x, norm_w[0])
    embed_rms_kernel<<<kSeq, 256, 0, stream>>>(tokens, embedding, norm_w, x, h2);

    for (int i = 0; i < kL; ++i) {
        // xz partials = h @ in_proj_w[i]^T  (1024 x 3072, K=2304, KSPLIT=2)
        mfma_gemm<128, 128, 2><<<dim3(kSeq / 128, 2 * kDInner / 128, 2), 256, 0, stream>>>(
            h2, K3m, inw2 + (size_t)i * 2 * kDInner * K3m, K3m,
            partsXZ, 2 * kDInner, 2 * kDInner, K3m, (size_t)kSeq * 2 * kDInner);

        // xi = silu(conv(sum(parts)[:, :1536]) + b)   (reduce fused)
        conv_silu_kernel<<<dim3(kSeq, kDInner / 256), 256, 0, stream>>>(
            partsXZ, partsXZ + (size_t)kSeq * 2 * kDInner,
            conv_w + (size_t)i * kDInner * kDConv, conv_b + (size_t)i * kDInner,
            xi, xi2);

        // proj = xi @ x_proj_w[i]^T   (1024 x 128pad, K=4608, KSPLIT=24)
        mfma_gemm<128, 128, 24><<<dim3(kSeq / 128, 1, 24), 256, 0, stream>>>(
            xi2, K3i, xw2 + (size_t)i * kPB * K3i, K3i,
            partsP, kPLd, kPLd, K3i, (size_t)kSeq * kPLd);
        reduce_parts<24><<<(kSeq * kPLd / 4 + 255) / 256, 256, 0, stream>>>(
            partsP, (size_t)kSeq * kPLd, proj, kSeq * kPLd);

        // selective scan (dt inline, mul_silu fused into part2)
        const float* A_l  = A_log + (size_t)i * kDInner * kDState;
        const float* dtw  = dt_proj_w + (size_t)i * kDInner * kDtRank;
        const float* dtb  = dt_proj_b + (size_t)i * kDInner;
        scan_part1<<<dim3(kDInner / 16, kNCH), 256, 0, stream>>>(
            xi, proj, A_l, dtw, dtb, scanP, scanS);
        scan_part2<<<dim3(kDInner / 16, kNCH), 256, 0, stream>>>(
            xi, proj, A_l, dtw, dtb, D_skip + (size_t)i * kDInner,
            scanP, scanS, partsXZ, partsXZ + (size_t)kSeq * 2 * kDInner, g2);

        // out_proj partials = g @ out_proj_w[i]^T  (1024 x 768, K=3072 2-term, KSPLIT=6)
        mfma_gemm<128, 128, 6><<<dim3(kSeq / 128, kDModel / 128, 6), 256, 0, stream>>>(
            g2, K2i, outw2 + (size_t)i * kDModel * K2i, K2i,
            partsO, kDModel, kDModel, K2i, (size_t)kSeq * kDModel);

        // x += sum(partsO); rmsnorm -> h2 (next layer) or h_bf (final)
        if (i + 1 < kL) {
            reduce_rms_kernel<false><<<kSeq, 256, 0, stream>>>(
                partsO, (size_t)kSeq * kDModel, norm_w + (size_t)(i + 1) * kDModel, x, h2);
        } else {
            reduce_rms_kernel<true><<<kSeq, 256, 0, stream>>>(
                partsO, (size_t)kSeq * kDModel, final_norm_w, x, h_bf);
        }
    }

    // out = h_bf @ embedding^T   (1024 x 32000, K=768)
    mfma_gemm<128, 128, 1><<<dim3(kSeq / 128, kVocab / 128, 1), 256, 0, stream>>>(
        h_bf, kDModel, emb_bf, kDModel, out, kVocab, kVocab, kDModel, 0);
}

// Round 13
// 767.650 us; speedup vs baseline: 6.6399x; 1.0129x over previous
//
#include <hip/hip_runtime.h>
#include <hip/hip_bf16.h>
#include <cmath>

namespace {

constexpr int kL      = 4;
constexpr int kDModel = 768;
constexpr int kDInner = 1536;
constexpr int kDtRank = 48;
constexpr int kDState = 16;
constexpr int kDConv  = 4;
constexpr int kSeq    = 1024;
constexpr int kPLd    = 96;    // proj row stride (80 used)
constexpr int kPB     = 128;   // x_proj weight rows padded for BN=128
constexpr int kVocab  = 32000;
constexpr int kCH     = 64;    // scan chunk length
constexpr int kNCH    = kSeq / kCH;  // 16 chunks
constexpr int kDN     = kDInner * kDState;  // 24576 (d,n) pairs
constexpr int kSplitIn  = 4;   // in_proj split-K parts (768 blocks = 3/CU)
constexpr int kSplitOut = 8;   // out_proj split-K parts

using short8 = __attribute__((ext_vector_type(8))) short;
using f32x4  = __attribute__((ext_vector_type(4))) float;

__device__ __forceinline__ float silu_f(float v) {
    return v / (1.f + __expf(-v));
}

__device__ __forceinline__ unsigned short f2bu(float v) {
    __hip_bfloat16 h = __float2bfloat16(v);
    return *reinterpret_cast<unsigned short*>(&h);
}

__device__ __forceinline__ void split_bf16(float v, __hip_bfloat16& hi, __hip_bfloat16& lo) {
    hi = __float2bfloat16(v);
    lo = __float2bfloat16(v - __bfloat162float(hi));
}

__device__ __forceinline__ void split_u(float v, unsigned short& hi, unsigned short& lo) {
    __hip_bfloat16 h, l;
    split_bf16(v, h, l);
    hi = *reinterpret_cast<unsigned short*>(&h);
    lo = *reinterpret_cast<unsigned short*>(&l);
}

// ------------------------------------- fp32->bf16, 8 elems/thread, 16B store
__global__ void __launch_bounds__(256) f2b_kernel(
    const float* __restrict__ src, __hip_bfloat16* __restrict__ dst, int n) {
    int i = (blockIdx.x * 256 + threadIdx.x) * 8;
    const int stride = gridDim.x * 256 * 8;
    for (; i + 7 < n; i += stride) {
        const float4 a = *reinterpret_cast<const float4*>(src + i);
        const float4 b = *reinterpret_cast<const float4*>(src + i + 4);
        union { unsigned short u[8]; uint4 v; } pk;
        pk.u[0] = f2bu(a.x); pk.u[1] = f2bu(a.y); pk.u[2] = f2bu(a.z); pk.u[3] = f2bu(a.w);
        pk.u[4] = f2bu(b.x); pk.u[5] = f2bu(b.y); pk.u[6] = f2bu(b.z); pk.u[7] = f2bu(b.w);
        *reinterpret_cast<uint4*>(reinterpret_cast<unsigned short*>(dst) + i) = pk.v;
    }
}

// ------------- fp32 -> 3-term split bf16 along K, 4 elems/thread, 8B stores
// B-side: dst row = [hi | hi | lo]
__global__ void __launch_bounds__(256) split3_kernel(
    const float* __restrict__ src, int rows, int cols,
    __hip_bfloat16* __restrict__ dst) {
    const int idx = blockIdx.x * 256 + threadIdx.x;
    const int c4cnt = cols >> 2;
    if (idx >= rows * c4cnt) return;
    const int r = idx / c4cnt, c = (idx % c4cnt) << 2;
    const float4 v = *reinterpret_cast<const float4*>(src + (size_t)r * cols + c);
    ushort4 hi4, lo4;
    split_u(v.x, hi4.x, lo4.x); split_u(v.y, hi4.y, lo4.y);
    split_u(v.z, hi4.z, lo4.z); split_u(v.w, hi4.w, lo4.w);
    unsigned short* row = reinterpret_cast<unsigned short*>(dst) + (size_t)r * 3 * cols;
    *reinterpret_cast<ushort4*>(row + c) = hi4;
    *reinterpret_cast<ushort4*>(row + cols + c) = hi4;
    *reinterpret_cast<ushort4*>(row + 2 * cols + c) = lo4;
}

// ---------------- fp32 -> duplicated hi along K: row = [hi | hi], 4-wide
__global__ void __launch_bounds__(256) dup2_kernel(
    const float* __restrict__ src, __hip_bfloat16* __restrict__ dst,
    int rows, int cols) {
    const int idx = blockIdx.x * 256 + threadIdx.x;
    const int c4cnt = cols >> 2;
    if (idx >= rows * c4cnt) return;
    const int r = idx / c4cnt, c = (idx % c4cnt) << 2;
    const float4 v = *reinterpret_cast<const float4*>(src + (size_t)r * cols + c);
    ushort4 hi4 = {f2bu(v.x), f2bu(v.y), f2bu(v.z), f2bu(v.w)};
    unsigned short* row = reinterpret_cast<unsigned short*>(dst) + (size_t)r * 2 * cols;
    *reinterpret_cast<ushort4*>(row + c) = hi4;
    *reinterpret_cast<ushort4*>(row + cols + c) = hi4;
}

// ------- x_proj weights, all layers: 80 rows -> 128 padded, 3-term, 4-wide
__global__ void __launch_bounds__(256) split3x_kernel(
    const float* __restrict__ src, __hip_bfloat16* __restrict__ dst) {
    const int idx = blockIdx.x * 256 + threadIdx.x;
    constexpr int c4cnt = kDInner >> 2;
    if (idx >= kL * kPB * c4cnt) return;
    const int layer = idx / (kPB * c4cnt);
    const int rem   = idx % (kPB * c4cnt);
    const int r = rem / c4cnt, c = (rem % c4cnt) << 2;
    float4 v = {0.f, 0.f, 0.f, 0.f};
    if (r < kDtRank + 2 * kDState)
        v = *reinterpret_cast<const float4*>(
            src + (size_t)layer * (kDtRank + 2 * kDState) * kDInner + (size_t)r * kDInner + c);
    ushort4 hi4, lo4;
    split_u(v.x, hi4.x, lo4.x); split_u(v.y, hi4.y, lo4.y);
    split_u(v.z, hi4.z, lo4.z); split_u(v.w, hi4.w, lo4.w);
    unsigned short* row = reinterpret_cast<unsigned short*>(dst)
        + ((size_t)layer * kPB + r) * 3 * kDInner;
    *reinterpret_cast<ushort4*>(row + c) = hi4;
    *reinterpret_cast<ushort4*>(row + kDInner + c) = hi4;
    *reinterpret_cast<ushort4*>(row + 2 * kDInner + c) = lo4;
}

// -------------------------- embed + rmsnorm(norm_w[0]) -> x, h2 (split bf16)
__global__ void __launch_bounds__(256) embed_rms_kernel(
    const int* __restrict__ tokens, const float* __restrict__ emb,
    const float* __restrict__ w, float* __restrict__ x,
    __hip_bfloat16* __restrict__ h2) {
    const int s = blockIdx.x;
    const int t = tokens[s];
    const float* src = emb + (size_t)t * kDModel;
    float v[3];
    float ss = 0.f;
    #pragma unroll
    for (int j = 0; j < 3; ++j) {
        const int d = threadIdx.x + j * 256;
        v[j] = src[d];
        x[(size_t)s * kDModel + d] = v[j];
        ss = fmaf(v[j], v[j], ss);
    }
    #pragma unroll
    for (int m = 32; m; m >>= 1) ss += __shfl_xor(ss, m);
    __shared__ float red[4];
    if ((threadIdx.x & 63) == 0) red[threadIdx.x >> 6] = ss;
    __syncthreads();
    const float total = red[0] + red[1] + red[2] + red[3];
    const float scale = rsqrtf(total / (float)kDModel + 1e-5f);
    __hip_bfloat16* dst = h2 + (size_t)s * 3 * kDModel;
    #pragma unroll
    for (int j = 0; j < 3; ++j) {
        const int d = threadIdx.x + j * 256;
        const float hv = v[j] * scale * w[d];
        __hip_bfloat16 hi, lo;
        split_bf16(hv, hi, lo);
        dst[d] = hi; dst[kDModel + d] = lo; dst[2 * kDModel + d] = hi;
    }
}

// -- x += sum(kSplitOut out_proj partials); rmsnorm -> h2 (split) / h_bf
template <bool FINAL>
__global__ void __launch_bounds__(256) reduce_rms_kernel(
    const float* __restrict__ parts, size_t stride,
    const float* __restrict__ w, float* __restrict__ x,
    __hip_bfloat16* __restrict__ out) {
    const int s = blockIdx.x;
    float v[3];
    float ss = 0.f;
    #pragma unroll
    for (int j = 0; j < 3; ++j) {
        const int d = threadIdx.x + j * 256;
        const size_t off = (size_t)s * kDModel + d;
        float acc = x[off];
        #pragma unroll
        for (int p = 0; p < kSplitOut; ++p) acc += parts[(size_t)p * stride + off];
        v[j] = acc;
        x[off] = acc;
        ss = fmaf(acc, acc, ss);
    }
    #pragma unroll
    for (int m = 32; m; m >>= 1) ss += __shfl_xor(ss, m);
    __shared__ float red[4];
    if ((threadIdx.x & 63) == 0) red[threadIdx.x >> 6] = ss;
    __syncthreads();
    const float total = red[0] + red[1] + red[2] + red[3];
    const float scale = rsqrtf(total / (float)kDModel + 1e-5f);
    #pragma unroll
    for (int j = 0; j < 3; ++j) {
        const int d = threadIdx.x + j * 256;
        const float hv = v[j] * scale * w[d];
        if (FINAL) {
            out[(size_t)s * kDModel + d] = __float2bfloat16(hv);
        } else {
            __hip_bfloat16 hi, lo;
            split_bf16(hv, hi, lo);
            __hip_bfloat16* dst = out + (size_t)s * 3 * kDModel;
            dst[d] = hi; dst[kDModel + d] = lo; dst[2 * kDModel + d] = hi;
        }
    }
}

// ---------------------------------------------------------------- MFMA GEMM
// C[m][n] = sum_{k in split part} A[m][k]*B[n][k].  A: MxK bf16, B: NxK bf16.
// 2-phase double-buffered pipeline (round-7 measured best): prefetch
// STAGE(t+1) before compute(t); s_barrier + vmcnt(4) keeps next tile's loads
// in flight across the MFMA phase. Granule swizzle + bijective XCD swizzle.
template <int BM, int BN, int KSPLIT>
__global__ void __launch_bounds__(256) mfma_gemm(
    const __hip_bfloat16* __restrict__ A, int lda,
    const __hip_bfloat16* __restrict__ B, int ldb,
    float* __restrict__ C, int ldc,
    int N, int K, size_t partStride) {
    constexpr int BK = 32;
    static_assert(BM == 128 && BN == 128, "staging assumes 128x128");
    __shared__ unsigned short As[2][BM * BK];
    __shared__ unsigned short Bs[2][BN * BK];
    const int tid  = threadIdx.x;
    const int lane = tid & 63;

    // ---- bijective chunked XCD swizzle (m204) over the (x,y) grid ----
    const int nwg = gridDim.x * gridDim.y;
    int bid = blockIdx.y * gridDim.x + blockIdx.x;
    {
        const int q = nwg >> 3, r = nwg & 7;
        const int xcd = bid & 7, pos = bid >> 3;
        bid = (xcd < r ? xcd * (q + 1) : r * (q + 1) + (xcd - r) * q) + pos;
    }
    const int m0 = (bid % gridDim.x) * BM;   // m fast: same-n blocks adjacent
    const int n0 = (bid / gridDim.x) * BN;

    const int Kp = K / KSPLIT;
    const int kbeg = (KSPLIT > 1) ? blockIdx.z * Kp : 0;
    float* Cw = (KSPLIT > 1) ? C + (size_t)blockIdx.z * partStride : C;
    constexpr int WM = BM / 2, WN = BN / 2;   // 2x2 waves
    constexpr int MR = WM / 16, NR = WN / 16;
    const int wave = tid >> 6;
    const int wm = (wave >> 1) * WM, wn = (wave & 1) * WN;
    const int l15 = lane & 15, l4 = lane >> 4;
    f32x4 acc[MR][NR] = {};

    // stage one K-tile into buffer `buf` (4 gload_lds per thread, uniform)
    auto stage = [&](int buf, int k0) {
        #pragma unroll
        for (int i = 0; i < 2; ++i) {
            const int idx = tid + i * 256;           // A granules: BM*4 = 512
            const int r = idx >> 2, qv = idx & 3;
            const int qs = qv ^ ((r >> 1) & 3);
            __builtin_amdgcn_global_load_lds(
                (const __attribute__((address_space(1))) void*)(A + (size_t)(m0 + r) * lda + k0 + qs * 8),
                (__attribute__((address_space(3))) void*)(&As[buf][(idx - lane) * 8]),
                16, 0, 0);
        }
        #pragma unroll
        for (int i = 0; i < 2; ++i) {
            const int idx = tid + i * 256;           // B granules: BN*4 = 512
            const int r = idx >> 2, qv = idx & 3;
            const int qs = qv ^ ((r >> 1) & 3);
            __builtin_amdgcn_global_load_lds(
                (const __attribute__((address_space(1))) void*)(B + (size_t)(n0 + r) * ldb + k0 + qs * 8),
                (__attribute__((address_space(3))) void*)(&Bs[buf][(idx - lane) * 8]),
                16, 0, 0);
        }
    };

    const int nt = Kp / BK;
    int cur = 0;
    stage(0, kbeg);
    for (int t = 0; t < nt; ++t) {
        if (t + 1 < nt) {
            stage(cur ^ 1, kbeg + (t + 1) * BK);
            asm volatile("s_waitcnt vmcnt(4)" ::: "memory");  // cur landed
        } else {
            asm volatile("s_waitcnt vmcnt(0)" ::: "memory");
        }
        __builtin_amdgcn_s_barrier();

        short8 af[MR], bfv[NR];
        #pragma unroll
        for (int mi = 0; mi < MR; ++mi) {
            const int R = wm + mi * 16 + l15;
            af[mi] = *reinterpret_cast<const short8*>(&As[cur][(R * 4 + (l4 ^ ((R >> 1) & 3))) * 8]);
        }
        #pragma unroll
        for (int ni = 0; ni < NR; ++ni) {
            const int R = wn + ni * 16 + l15;
            bfv[ni] = *reinterpret_cast<const short8*>(&Bs[cur][(R * 4 + (l4 ^ ((R >> 1) & 3))) * 8]);
        }
        #pragma unroll
        for (int mi = 0; mi < MR; ++mi)
            #pragma unroll
            for (int ni = 0; ni < NR; ++ni)
                acc[mi][ni] = __builtin_amdgcn_mfma_f32_16x16x32_bf16(
                    af[mi], bfv[ni], acc[mi][ni], 0, 0, 0);

        asm volatile("s_waitcnt lgkmcnt(0)" ::: "memory");
        __builtin_amdgcn_s_barrier();                // safe to overwrite cur
        cur ^= 1;
    }

    // C/D layout: col = lane&15, row = (lane>>4)*4 + reg  (m89/m91)
    #pragma unroll
    for (int mi = 0; mi < MR; ++mi) {
        const int mrow = m0 + wm + mi * 16 + l4 * 4;
        #pragma unroll
        for (int ni = 0; ni < NR; ++ni) {
            const int ncol = n0 + wn + ni * 16 + l15;
            if (ncol >= N) continue;
            #pragma unroll
            for (int r = 0; r < 4; ++r)
                Cw[(size_t)(mrow + r) * ldc + ncol] = acc[mi][ni][r];
        }
    }
}

// ------------------------- reduce NP split-K partials: dst = sum(parts)
template <int NP>
__global__ void __launch_bounds__(256) reduce_parts(
    const float* __restrict__ parts, size_t stride,
    float* __restrict__ dst, int count) {
    const int i = (blockIdx.x * 256 + threadIdx.x) * 4;
    if (i >= count) return;
    float4 s = *reinterpret_cast<const float4*>(parts + i);
    #pragma unroll
    for (int p = 1; p < NP; ++p) {
        const float4 v = *reinterpret_cast<const float4*>(parts + (size_t)p * stride + i);
        s.x += v.x; s.y += v.y; s.z += v.z; s.w += v.w;
    }
    *reinterpret_cast<float4*>(dst + i) = s;
}

// -------- depthwise causal conv+silu, fused kSplitIn-part split-K reduce
__global__ void __launch_bounds__(256) conv_silu_kernel(
    const float* __restrict__ parts, size_t stride,
    const float* __restrict__ cw, const float* __restrict__ cb,
    float* __restrict__ xi, __hip_bfloat16* __restrict__ xi2) {
    const int s = blockIdx.x;
    const int d = blockIdx.y * 256 + threadIdx.x;
    float acc = cb[d];
    #pragma unroll
    for (int k = 0; k < kDConv; ++k) {
        const int sl = s - (kDConv - 1) + k;
        if (sl >= 0) {
            const size_t off = (size_t)sl * (2 * kDInner) + d;
            float xzv = parts[off];
            #pragma unroll
            for (int p = 1; p < kSplitIn; ++p) xzv += parts[(size_t)p * stride + off];
            acc = fmaf(xzv, cw[d * kDConv + k], acc);
        }
    }
    const float v = silu_f(acc);
    xi[(size_t)s * kDInner + d] = v;
    __hip_bfloat16 hi, lo;
    split_bf16(v, hi, lo);
    __hip_bfloat16* row = xi2 + (size_t)s * 3 * kDInner;
    row[d] = hi; row[kDInner + d] = lo; row[2 * kDInner + d] = hi;
}

// ------------------------------------------------- chunked selective scan
// recurrence: state = state * exp(exp(dt*A)) + dt*u*B ; y = <state,C> + u*Dv
// dt = softplus(proj[:, :48] @ dtw^T + bias) computed inline (fp32-exact).

// shared helper: stage proj[:, :48] + dtw tile, compute sdt[64][16]
__device__ __forceinline__ void compute_dt_tile(
    const float* __restrict__ proj, const float* __restrict__ dtw,
    const float* __restrict__ dtb, int l0, int d0, int tid,
    float (*sP)[kDtRank], float (*sdtw)[kDtRank + 1], float (*sdt)[16]) {
    for (int idx = tid; idx < kCH * kDtRank; idx += 256) {
        const int r = idx / kDtRank, c = idx % kDtRank;
        sP[r][c] = proj[(size_t)(l0 + r) * kPLd + c];
    }
    for (int idx = tid; idx < 16 * kDtRank; idx += 256) {
        const int dd = idx / kDtRank, c = idx % kDtRank;
        sdtw[dd][c] = dtw[(size_t)(d0 + dd) * kDtRank + c];
    }
    __syncthreads();
    #pragma unroll
    for (int e = 0; e < 4; ++e) {
        const int idx = tid + e * 256;
        const int r = idx >> 4, dd = idx & 15;
        float acc = dtb[d0 + dd];
        #pragma unroll
        for (int k = 0; k < kDtRank; ++k)
            acc = fmaf(sP[r][k], sdtw[dd][k], acc);
        acc = (acc > 20.f) ? acc : log1pf(__expf(acc));  // softplus
        sdt[r][dd] = acc;
    }
}

__global__ void __launch_bounds__(256) scan_part1(
    const float* __restrict__ u, const float* __restrict__ proj,
    const float* __restrict__ A_log, const float* __restrict__ dtw,
    const float* __restrict__ dtb,
    float* __restrict__ P, float* __restrict__ S) {
    __shared__ float sP[kCH][kDtRank];
    __shared__ float sdtw[16][kDtRank + 1];
    __shared__ float sdt[kCH][16], su[kCH][16], sB[kCH][16];
    const int tid = threadIdx.x;
    const int n = tid & 15, dl = tid >> 4;
    const int d0 = blockIdx.x * 16;
    const int l0 = blockIdx.y * kCH;
    for (int idx = tid; idx < kCH * 16; idx += 256) {
        const int r = idx >> 4, c = idx & 15;
        su[r][c] = u[(size_t)(l0 + r) * kDInner + d0 + c];
        sB[r][c] = proj[(size_t)(l0 + r) * kPLd + kDtRank + c];
    }
    compute_dt_tile(proj, dtw, dtb, l0, d0, tid, sP, sdtw, sdt);
    __syncthreads();
    const int d = d0 + dl;
    const float Adn = -__expf(A_log[d * kDState + n]);
    float state = 0.f, sumA = 0.f;
    #pragma unroll 8
    for (int l = 0; l < kCH; ++l) {
        const float dtv = sdt[l][dl];
        const float adelta = __expf(dtv * Adn);
        const float mult = __expf(adelta);
        state = fmaf(state, mult, dtv * su[l][dl] * sB[l][n]);
        sumA += adelta;
    }
    const int dn = d * kDState + n;
    P[(size_t)blockIdx.y * kDN + dn] = __expf(sumA);
    S[(size_t)blockIdx.y * kDN + dn] = state;
}

// part2: inline chunk-prefix, chunk scan, then g = y * silu(res) fused,
// written as 2-term split [hi | lo] (activation-exact out_proj input)
__global__ void __launch_bounds__(256) scan_part2(
    const float* __restrict__ u, const float* __restrict__ proj,
    const float* __restrict__ A_log, const float* __restrict__ dtw,
    const float* __restrict__ dtb, const float* __restrict__ D_skip,
    const float* __restrict__ P, const float* __restrict__ S,
    const float* __restrict__ resparts, size_t rstride,
    __hip_bfloat16* __restrict__ g2) {
    __shared__ float sP[kCH][kDtRank];
    __shared__ float sdtw[16][kDtRank + 1];
    __shared__ float sdt[kCH][16], su[kCH][16], sB[kCH][16], sC[kCH][16];
    __shared__ float sy[kCH][16];
    const int tid = threadIdx.x;
    const int n = tid & 15, dl = tid >> 4;
    const int d0 = blockIdx.x * 16;
    const int l0 = blockIdx.y * kCH;
    for (int idx = tid; idx < kCH * 16; idx += 256) {
        const int r = idx >> 4, c = idx & 15;
        su[r][c] = u[(size_t)(l0 + r) * kDInner + d0 + c];
        sB[r][c] = proj[(size_t)(l0 + r) * kPLd + kDtRank + c];
        sC[r][c] = proj[(size_t)(l0 + r) * kPLd + kDtRank + kDState + c];
    }
    compute_dt_tile(proj, dtw, dtb, l0, d0, tid, sP, sdtw, sdt);
    // inline prefix: state entering chunk blockIdx.y for this thread's dn
    const int dn = d0 * kDState + tid;   // == (d0+dl)*16 + n
    float state = 0.f;
    for (int jj = 0; jj < (int)blockIdx.y; ++jj) {
        const size_t idx = (size_t)jj * kDN + dn;
        state = fmaf(state, P[idx], S[idx]);
    }
    __syncthreads();
    const int d = d0 + dl;
    const float Adn = -__expf(A_log[d * kDState + n]);
    const float Dv  = D_skip[d];
    for (int l = 0; l < kCH; ++l) {
        const float dtv = sdt[l][dl];
        const float uv  = su[l][dl];
        const float mult = __expf(__expf(dtv * Adn));
        state = fmaf(state, mult, dtv * uv * sB[l][n]);
        float contrib = state * sC[l][n];
        contrib += __shfl_xor(contrib, 8);
        contrib += __shfl_xor(contrib, 4);
        contrib += __shfl_xor(contrib, 2);
        contrib += __shfl_xor(contrib, 1);
        if (n == 0) sy[l][dl] = fmaf(uv, Dv, contrib);
    }
    __syncthreads();
    // fused: g = y * silu(res), 2-term split [hi | lo]
    for (int idx = tid; idx < kCH * 16; idx += 256) {
        const int r = idx >> 4, c = idx & 15;
        const size_t roff = (size_t)(l0 + r) * (2 * kDInner) + kDInner + d0 + c;
        float res = resparts[roff];
        #pragma unroll
        for (int p = 1; p < kSplitIn; ++p) res += resparts[(size_t)p * rstride + roff];
        const float v = sy[r][c] * silu_f(res);
        __hip_bfloat16 hi, lo;
        split_bf16(v, hi, lo);
        __hip_bfloat16* row = g2 + (size_t)(l0 + r) * 2 * kDInner;
        row[d0 + c] = hi; row[kDInner + d0 + c] = lo;
    }
}

}  // namespace

extern "C" void kernel_launch(void* const* d_in, const int* in_sizes, int n_in,
                              void* d_out, int out_size, void* d_ws, size_t ws_size,
                              hipStream_t stream) {
    const int*   tokens       = (const int*)d_in[0];
    const float* embedding    = (const float*)d_in[1];
    const float* norm_w       = (const float*)d_in[2];
    const float* in_proj_w    = (const float*)d_in[3];
    const float* conv_w       = (const float*)d_in[4];
    const float* conv_b       = (const float*)d_in[5];
    const float* x_proj_w     = (const float*)d_in[6];
    const float* dt_proj_w    = (const float*)d_in[7];
    const float* dt_proj_b    = (const float*)d_in[8];
    const float* A_log        = (const float*)d_in[9];
    const float* D_skip       = (const float*)d_in[10];
    const float* out_proj_w   = (const float*)d_in[11];
    const float* final_norm_w = (const float*)d_in[12];
    float* out = (float*)d_out;

    constexpr int K3m = 3 * kDModel;   // 2304
    constexpr int K3i = 3 * kDInner;   // 4608
    constexpr int K2i = 2 * kDInner;   // 3072 (out_proj 2-term)

    char* ws = (char*)d_ws;
    auto alloc = [&](size_t bytes) { char* p = ws; ws += (bytes + 255) & ~(size_t)255; return p; };
    float* x    = (float*)alloc((size_t)kSeq * kDModel * 4);
    float* xi   = (float*)alloc((size_t)kSeq * kDInner * 4);
    float* proj = (float*)alloc((size_t)kSeq * kPLd * 4);
    float* scanP  = (float*)alloc((size_t)kNCH * kDN * 4);
    float* scanS  = (float*)alloc((size_t)kNCH * kDN * 4);
    float* partsXZ = (float*)alloc((size_t)kSplitIn * kSeq * 2 * kDInner * 4);  // in_proj partials
    float* partsP  = (float*)alloc((size_t)24 * kSeq * kPLd * 4);               // x_proj partials
    float* partsO  = (float*)alloc((size_t)kSplitOut * kSeq * kDModel * 4);     // out_proj partials
    __hip_bfloat16* h_bf   = (__hip_bfloat16*)alloc((size_t)kSeq * kDModel * 2);
    __hip_bfloat16* h2     = (__hip_bfloat16*)alloc((size_t)kSeq * K3m * 2);
    __hip_bfloat16* xi2    = (__hip_bfloat16*)alloc((size_t)kSeq * K3i * 2);
    __hip_bfloat16* g2     = (__hip_bfloat16*)alloc((size_t)kSeq * K2i * 2);
    __hip_bfloat16* emb_bf = (__hip_bfloat16*)alloc((size_t)kVocab * kDModel * 2);
    __hip_bfloat16* inw2   = (__hip_bfloat16*)alloc((size_t)kL * 2 * kDInner * K3m * 2);
    __hip_bfloat16* outw2  = (__hip_bfloat16*)alloc((size_t)kL * kDModel * K2i * 2);
    __hip_bfloat16* xw2    = (__hip_bfloat16*)alloc((size_t)kL * kPB * K3i * 2);

    // ---- weight conversions (per call; layer dims are contiguous) ----
    f2b_kernel<<<4096, 256, 0, stream>>>(embedding, emb_bf, kVocab * kDModel);
    dup2_kernel<<<(kL * kDModel * kDInner / 4 + 255) / 256, 256, 0, stream>>>(
        out_proj_w, outw2, kL * kDModel, kDInner);
    split3_kernel<<<(kL * 2 * kDInner * kDModel / 4 + 255) / 256, 256, 0, stream>>>(
        in_proj_w, kL * 2 * kDInner, kDModel, inw2);
    split3x_kernel<<<(kL * kPB * kDInner / 4 + 255) / 256, 256, 0, stream>>>(
        x_proj_w, xw2);

    // x = embed; h2 = split-rmsnorm(x, norm_w[0])
    embed_rms_kernel<<<kSeq, 256, 0, stream>>>(tokens, embedding, norm_w, x, h2);

    for (int i = 0; i < kL; ++i) {
        // xz partials = h @ in_proj_w[i]^T  (1024 x 3072, K=2304, KSPLIT=4)
        mfma_gemm<128, 128, kSplitIn><<<dim3(kSeq / 128, 2 * kDInner / 128, kSplitIn), 256, 0, stream>>>(
            h2, K3m, inw2 + (size_t)i * 2 * kDInner * K3m, K3m,
            partsXZ, 2 * kDInner, 2 * kDInner, K3m, (size_t)kSeq * 2 * kDInner);

        // xi = silu(conv(sum(parts)[:, :1536]) + b)   (reduce fused)
        conv_silu_kernel<<<dim3(kSeq, kDInner / 256), 256, 0, stream>>>(
            partsXZ, (size_t)kSeq * 2 * kDInner,
            conv_w + (size_t)i * kDInner * kDConv, conv_b + (size_t)i * kDInner,
            xi, xi2);

        // proj = xi @ x_proj_w[i]^T   (1024 x 128pad, K=4608, KSPLIT=24)
        mfma_gemm<128, 128, 24><<<dim3(kSeq / 128, 1, 24), 256, 0, stream>>>(
            xi2, K3i, xw2 + (size_t)i * kPB * K3i, K3i,
            partsP, kPLd, kPLd, K3i, (size_t)kSeq * kPLd);
        reduce_parts<24><<<(kSeq * kPLd / 4 + 255) / 256, 256, 0, stream>>>(
            partsP, (size_t)kSeq * kPLd, proj, kSeq * kPLd);

        // selective scan (dt inline, mul_silu fused into part2)
        const float* A_l  = A_log + (size_t)i * kDInner * kDState;
        const float* dtw  = dt_proj_w + (size_t)i * kDInner * kDtRank;
        const float* dtb  = dt_proj_b + (size_t)i * kDInner;
        scan_part1<<<dim3(kDInner / 16, kNCH), 256, 0, stream>>>(
            xi, proj, A_l, dtw, dtb, scanP, scanS);
        scan_part2<<<dim3(kDInner / 16, kNCH), 256, 0, stream>>>(
            xi, proj, A_l, dtw, dtb, D_skip + (size_t)i * kDInner,
            scanP, scanS, partsXZ, (size_t)kSeq * 2 * kDInner, g2);

        // out_proj partials = g @ W^T  (1024 x 768, K=3072 2-term, KSPLIT=8)
        mfma_gemm<128, 128, kSplitOut><<<dim3(kSeq / 128, kDModel / 128, kSplitOut), 256, 0, stream>>>(
            g2, K2i, outw2 + (size_t)i * kDModel * K2i, K2i,
            partsO, kDModel, kDModel, K2i, (size_t)kSeq * kDModel);

        // x += sum(partsO); rmsnorm -> h2 (next layer) or h_bf (final)
        if (i + 1 < kL) {
            reduce_rms_kernel<false><<<kSeq, 256, 0, stream>>>(
                partsO, (size_t)kSeq * kDModel, norm_w + (size_t)(i + 1) * kDModel, x, h2);
        } else {
            reduce_rms_kernel<true><<<kSeq, 256, 0, stream>>>(
                partsO, (size_t)kSeq * kDModel, final_norm_w, x, h_bf);
        }
    }

    // out = h_bf @ embedding^T   (1024 x 32000, K=768)
    mfma_gemm<128, 128, 1><<<dim3(kSeq / 128, kVocab / 128, 1), 256, 0, stream>>>(
        h_bf, kDModel, emb_bf, kDModel, out, kVocab, kVocab, kDModel, 0);
}

// Round 14
// 746.091 us; speedup vs baseline: 6.8318x; 1.0289x over previous
//
#include <hip/hip_runtime.h>
#include <hip/hip_bf16.h>
#include <cmath>

namespace {

constexpr int kL      = 4;
constexpr int kDModel = 768;
constexpr int kDInner = 1536;
constexpr int kDtRank = 48;
constexpr int kDState = 16;
constexpr int kDConv  = 4;
constexpr int kSeq    = 1024;
constexpr int kPLd    = 96;    // proj row stride (80 used)
constexpr int kPB     = 128;   // x_proj weight rows padded for BN=128
constexpr int kVocab  = 32000;
constexpr int kCH     = 64;    // scan chunk length
constexpr int kNCH    = kSeq / kCH;  // 16 chunks
constexpr int kDN     = kDInner * kDState;  // 24576 (d,n) pairs
constexpr int kSplitIn  = 4;   // in_proj split-K parts
constexpr int kSplitOut = 8;   // out_proj split-K parts

using short8 = __attribute__((ext_vector_type(8))) short;
using f32x4  = __attribute__((ext_vector_type(4))) float;

__device__ __forceinline__ float silu_f(float v) {
    return v / (1.f + __expf(-v));
}

__device__ __forceinline__ unsigned short f2bu(float v) {
    __hip_bfloat16 h = __float2bfloat16(v);
    return *reinterpret_cast<unsigned short*>(&h);
}

__device__ __forceinline__ void split_bf16(float v, __hip_bfloat16& hi, __hip_bfloat16& lo) {
    hi = __float2bfloat16(v);
    lo = __float2bfloat16(v - __bfloat162float(hi));
}

__device__ __forceinline__ void split_u(float v, unsigned short& hi, unsigned short& lo) {
    __hip_bfloat16 h, l;
    split_bf16(v, h, l);
    hi = *reinterpret_cast<unsigned short*>(&h);
    lo = *reinterpret_cast<unsigned short*>(&l);
}

// ------------------------------------- fp32->bf16, 8 elems/thread, 16B store
__global__ void __launch_bounds__(256) f2b_kernel(
    const float* __restrict__ src, __hip_bfloat16* __restrict__ dst, int n) {
    int i = (blockIdx.x * 256 + threadIdx.x) * 8;
    const int stride = gridDim.x * 256 * 8;
    for (; i + 7 < n; i += stride) {
        const float4 a = *reinterpret_cast<const float4*>(src + i);
        const float4 b = *reinterpret_cast<const float4*>(src + i + 4);
        union { unsigned short u[8]; uint4 v; } pk;
        pk.u[0] = f2bu(a.x); pk.u[1] = f2bu(a.y); pk.u[2] = f2bu(a.z); pk.u[3] = f2bu(a.w);
        pk.u[4] = f2bu(b.x); pk.u[5] = f2bu(b.y); pk.u[6] = f2bu(b.z); pk.u[7] = f2bu(b.w);
        *reinterpret_cast<uint4*>(reinterpret_cast<unsigned short*>(dst) + i) = pk.v;
    }
}

// ------------- fp32 -> 3-term split bf16 along K, 4 elems/thread, 8B stores
__global__ void __launch_bounds__(256) split3_kernel(
    const float* __restrict__ src, int rows, int cols,
    __hip_bfloat16* __restrict__ dst) {
    const int idx = blockIdx.x * 256 + threadIdx.x;
    const int c4cnt = cols >> 2;
    if (idx >= rows * c4cnt) return;
    const int r = idx / c4cnt, c = (idx % c4cnt) << 2;
    const float4 v = *reinterpret_cast<const float4*>(src + (size_t)r * cols + c);
    ushort4 hi4, lo4;
    split_u(v.x, hi4.x, lo4.x); split_u(v.y, hi4.y, lo4.y);
    split_u(v.z, hi4.z, lo4.z); split_u(v.w, hi4.w, lo4.w);
    unsigned short* row = reinterpret_cast<unsigned short*>(dst) + (size_t)r * 3 * cols;
    *reinterpret_cast<ushort4*>(row + c) = hi4;
    *reinterpret_cast<ushort4*>(row + cols + c) = hi4;
    *reinterpret_cast<ushort4*>(row + 2 * cols + c) = lo4;
}

// ---------------- fp32 -> duplicated hi along K: row = [hi | hi], 4-wide
__global__ void __launch_bounds__(256) dup2_kernel(
    const float* __restrict__ src, __hip_bfloat16* __restrict__ dst,
    int rows, int cols) {
    const int idx = blockIdx.x * 256 + threadIdx.x;
    const int c4cnt = cols >> 2;
    if (idx >= rows * c4cnt) return;
    const int r = idx / c4cnt, c = (idx % c4cnt) << 2;
    const float4 v = *reinterpret_cast<const float4*>(src + (size_t)r * cols + c);
    ushort4 hi4 = {f2bu(v.x), f2bu(v.y), f2bu(v.z), f2bu(v.w)};
    unsigned short* row = reinterpret_cast<unsigned short*>(dst) + (size_t)r * 2 * cols;
    *reinterpret_cast<ushort4*>(row + c) = hi4;
    *reinterpret_cast<ushort4*>(row + cols + c) = hi4;
}

// ------- x_proj weights, all layers: 80 rows -> 128 padded, 3-term, 4-wide
__global__ void __launch_bounds__(256) split3x_kernel(
    const float* __restrict__ src, __hip_bfloat16* __restrict__ dst) {
    const int idx = blockIdx.x * 256 + threadIdx.x;
    constexpr int c4cnt = kDInner >> 2;
    if (idx >= kL * kPB * c4cnt) return;
    const int layer = idx / (kPB * c4cnt);
    const int rem   = idx % (kPB * c4cnt);
    const int r = rem / c4cnt, c = (rem % c4cnt) << 2;
    float4 v = {0.f, 0.f, 0.f, 0.f};
    if (r < kDtRank + 2 * kDState)
        v = *reinterpret_cast<const float4*>(
            src + (size_t)layer * (kDtRank + 2 * kDState) * kDInner + (size_t)r * kDInner + c);
    ushort4 hi4, lo4;
    split_u(v.x, hi4.x, lo4.x); split_u(v.y, hi4.y, lo4.y);
    split_u(v.z, hi4.z, lo4.z); split_u(v.w, hi4.w, lo4.w);
    unsigned short* row = reinterpret_cast<unsigned short*>(dst)
        + ((size_t)layer * kPB + r) * 3 * kDInner;
    *reinterpret_cast<ushort4*>(row + c) = hi4;
    *reinterpret_cast<ushort4*>(row + kDInner + c) = hi4;
    *reinterpret_cast<ushort4*>(row + 2 * kDInner + c) = lo4;
}

// -------------------------- embed + rmsnorm(norm_w[0]) -> x, h2 (split bf16)
__global__ void __launch_bounds__(256) embed_rms_kernel(
    const int* __restrict__ tokens, const float* __restrict__ emb,
    const float* __restrict__ w, float* __restrict__ x,
    __hip_bfloat16* __restrict__ h2) {
    const int s = blockIdx.x;
    const int t = tokens[s];
    const float* src = emb + (size_t)t * kDModel;
    float v[3];
    float ss = 0.f;
    #pragma unroll
    for (int j = 0; j < 3; ++j) {
        const int d = threadIdx.x + j * 256;
        v[j] = src[d];
        x[(size_t)s * kDModel + d] = v[j];
        ss = fmaf(v[j], v[j], ss);
    }
    #pragma unroll
    for (int m = 32; m; m >>= 1) ss += __shfl_xor(ss, m);
    __shared__ float red[4];
    if ((threadIdx.x & 63) == 0) red[threadIdx.x >> 6] = ss;
    __syncthreads();
    const float total = red[0] + red[1] + red[2] + red[3];
    const float scale = rsqrtf(total / (float)kDModel + 1e-5f);
    __hip_bfloat16* dst = h2 + (size_t)s * 3 * kDModel;
    #pragma unroll
    for (int j = 0; j < 3; ++j) {
        const int d = threadIdx.x + j * 256;
        const float hv = v[j] * scale * w[d];
        __hip_bfloat16 hi, lo;
        split_bf16(hv, hi, lo);
        dst[d] = hi; dst[kDModel + d] = lo; dst[2 * kDModel + d] = hi;
    }
}

// -- x += sum(kSplitOut out_proj partials); rmsnorm -> h2 (split) / h_bf
template <bool FINAL>
__global__ void __launch_bounds__(256) reduce_rms_kernel(
    const float* __restrict__ parts, size_t stride,
    const float* __restrict__ w, float* __restrict__ x,
    __hip_bfloat16* __restrict__ out) {
    const int s = blockIdx.x;
    float v[3];
    float ss = 0.f;
    #pragma unroll
    for (int j = 0; j < 3; ++j) {
        const int d = threadIdx.x + j * 256;
        const size_t off = (size_t)s * kDModel + d;
        float acc = x[off];
        #pragma unroll
        for (int p = 0; p < kSplitOut; ++p) acc += parts[(size_t)p * stride + off];
        v[j] = acc;
        x[off] = acc;
        ss = fmaf(acc, acc, ss);
    }
    #pragma unroll
    for (int m = 32; m; m >>= 1) ss += __shfl_xor(ss, m);
    __shared__ float red[4];
    if ((threadIdx.x & 63) == 0) red[threadIdx.x >> 6] = ss;
    __syncthreads();
    const float total = red[0] + red[1] + red[2] + red[3];
    const float scale = rsqrtf(total / (float)kDModel + 1e-5f);
    #pragma unroll
    for (int j = 0; j < 3; ++j) {
        const int d = threadIdx.x + j * 256;
        const float hv = v[j] * scale * w[d];
        if (FINAL) {
            out[(size_t)s * kDModel + d] = __float2bfloat16(hv);
        } else {
            __hip_bfloat16 hi, lo;
            split_bf16(hv, hi, lo);
            __hip_bfloat16* dst = out + (size_t)s * 3 * kDModel;
            dst[d] = hi; dst[kDModel + d] = lo; dst[2 * kDModel + d] = hi;
        }
    }
}

// ---------------------------------------------------------------- MFMA GEMM
// (layer GEMMs) 2-phase double-buffered 128x128 pipeline, round-7 config.
template <int BM, int BN, int KSPLIT>
__global__ void __launch_bounds__(256) mfma_gemm(
    const __hip_bfloat16* __restrict__ A, int lda,
    const __hip_bfloat16* __restrict__ B, int ldb,
    float* __restrict__ C, int ldc,
    int N, int K, size_t partStride) {
    constexpr int BK = 32;
    static_assert(BM == 128 && BN == 128, "staging assumes 128x128");
    __shared__ unsigned short As[2][BM * BK];
    __shared__ unsigned short Bs[2][BN * BK];
    const int tid  = threadIdx.x;
    const int lane = tid & 63;

    const int nwg = gridDim.x * gridDim.y;
    int bid = blockIdx.y * gridDim.x + blockIdx.x;
    {
        const int q = nwg >> 3, r = nwg & 7;
        const int xcd = bid & 7, pos = bid >> 3;
        bid = (xcd < r ? xcd * (q + 1) : r * (q + 1) + (xcd - r) * q) + pos;
    }
    const int m0 = (bid % gridDim.x) * BM;
    const int n0 = (bid / gridDim.x) * BN;

    const int Kp = K / KSPLIT;
    const int kbeg = (KSPLIT > 1) ? blockIdx.z * Kp : 0;
    float* Cw = (KSPLIT > 1) ? C + (size_t)blockIdx.z * partStride : C;
    constexpr int WM = BM / 2, WN = BN / 2;
    constexpr int MR = WM / 16, NR = WN / 16;
    const int wave = tid >> 6;
    const int wm = (wave >> 1) * WM, wn = (wave & 1) * WN;
    const int l15 = lane & 15, l4 = lane >> 4;
    f32x4 acc[MR][NR] = {};

    auto stage = [&](int buf, int k0) {
        #pragma unroll
        for (int i = 0; i < 2; ++i) {
            const int idx = tid + i * 256;
            const int r = idx >> 2, qv = idx & 3;
            const int qs = qv ^ ((r >> 1) & 3);
            __builtin_amdgcn_global_load_lds(
                (const __attribute__((address_space(1))) void*)(A + (size_t)(m0 + r) * lda + k0 + qs * 8),
                (__attribute__((address_space(3))) void*)(&As[buf][(idx - lane) * 8]),
                16, 0, 0);
        }
        #pragma unroll
        for (int i = 0; i < 2; ++i) {
            const int idx = tid + i * 256;
            const int r = idx >> 2, qv = idx & 3;
            const int qs = qv ^ ((r >> 1) & 3);
            __builtin_amdgcn_global_load_lds(
                (const __attribute__((address_space(1))) void*)(B + (size_t)(n0 + r) * ldb + k0 + qs * 8),
                (__attribute__((address_space(3))) void*)(&Bs[buf][(idx - lane) * 8]),
                16, 0, 0);
        }
    };

    const int nt = Kp / BK;
    int cur = 0;
    stage(0, kbeg);
    for (int t = 0; t < nt; ++t) {
        if (t + 1 < nt) {
            stage(cur ^ 1, kbeg + (t + 1) * BK);
            asm volatile("s_waitcnt vmcnt(4)" ::: "memory");
        } else {
            asm volatile("s_waitcnt vmcnt(0)" ::: "memory");
        }
        __builtin_amdgcn_s_barrier();

        short8 af[MR], bfv[NR];
        #pragma unroll
        for (int mi = 0; mi < MR; ++mi) {
            const int R = wm + mi * 16 + l15;
            af[mi] = *reinterpret_cast<const short8*>(&As[cur][(R * 4 + (l4 ^ ((R >> 1) & 3))) * 8]);
        }
        #pragma unroll
        for (int ni = 0; ni < NR; ++ni) {
            const int R = wn + ni * 16 + l15;
            bfv[ni] = *reinterpret_cast<const short8*>(&Bs[cur][(R * 4 + (l4 ^ ((R >> 1) & 3))) * 8]);
        }
        #pragma unroll
        for (int mi = 0; mi < MR; ++mi)
            #pragma unroll
            for (int ni = 0; ni < NR; ++ni)
                acc[mi][ni] = __builtin_amdgcn_mfma_f32_16x16x32_bf16(
                    af[mi], bfv[ni], acc[mi][ni], 0, 0, 0);

        asm volatile("s_waitcnt lgkmcnt(0)" ::: "memory");
        __builtin_amdgcn_s_barrier();
        cur ^= 1;
    }

    #pragma unroll
    for (int mi = 0; mi < MR; ++mi) {
        const int mrow = m0 + wm + mi * 16 + l4 * 4;
        #pragma unroll
        for (int ni = 0; ni < NR; ++ni) {
            const int ncol = n0 + wn + ni * 16 + l15;
            if (ncol >= N) continue;
            #pragma unroll
            for (int r = 0; r < 4; ++r)
                Cw[(size_t)(mrow + r) * ldc + ncol] = acc[mi][ni][r];
        }
    }
}

// ------------------------------- vocab GEMM: 256x256, BK=64, 8 waves, deep
// K-tile-granular double buffer (128 KB dynamic LDS). Per K-tile: full-tile
// prefetch of t+1 at top of t (buffer (t+1)&1 holds consumed tile t-1 ->
// race-free), then 4 quadrant clusters of 16 MFMA each with setprio.
// Granule swizzle p ^= (row&7) on both stage-source and ds_read.
__global__ void __launch_bounds__(512) vocab_gemm(
    const __hip_bfloat16* __restrict__ A,   // 1024 x 768
    const __hip_bfloat16* __restrict__ B,   // 32000 x 768
    float* __restrict__ C) {
    constexpr int BM = 256, BN = 256, BK = 64;
    constexpr int K = kDModel, NT = K / BK;      // 12
    constexpr int lda = kDModel, ldb = kDModel, ldc = kVocab;
    extern __shared__ unsigned short lds[];
    unsigned short* AsB = lds;                    // [2][BM*BK]
    unsigned short* BsB = lds + 2 * BM * BK;      // [2][BN*BK]
    const int tid = threadIdx.x, lane = tid & 63;
    const int wave = tid >> 6;
    const int wr = wave >> 2;      // 0..1 (M half)
    const int wc = wave & 3;       // 0..3 (N quarter)
    const int l15 = lane & 15, l4 = lane >> 4;

    const int nwg = gridDim.x * gridDim.y;
    int bid = blockIdx.y * gridDim.x + blockIdx.x;
    {
        const int q = nwg >> 3, r = nwg & 7;
        const int xcd = bid & 7, pos = bid >> 3;
        bid = (xcd < r ? xcd * (q + 1) : r * (q + 1) + (xcd - r) * q) + pos;
    }
    const int m0 = (bid % gridDim.x) * BM;
    const int n0 = (bid / gridDim.x) * BN;

    f32x4 acc[8][4] = {};

    // stage one full K-tile (A: 2048 granules, B: 2048; 8 loads/thread)
    auto stage = [&](int buf, int k0) {
        #pragma unroll
        for (int i = 0; i < 4; ++i) {
            const int idx = tid + i * 512;
            const int r = idx >> 3, p = idx & 7;
            const int ps = p ^ (r & 7);
            __builtin_amdgcn_global_load_lds(
                (const __attribute__((address_space(1))) void*)(A + (size_t)(m0 + r) * lda + k0 + ps * 8),
                (__attribute__((address_space(3))) void*)(AsB + (size_t)buf * BM * BK + (size_t)(idx - lane) * 8),
                16, 0, 0);
        }
        #pragma unroll
        for (int i = 0; i < 4; ++i) {
            const int idx = tid + i * 512;
            const int r = idx >> 3, p = idx & 7;
            const int ps = p ^ (r & 7);
            __builtin_amdgcn_global_load_lds(
                (const __attribute__((address_space(1))) void*)(B + (size_t)(n0 + r) * ldb + k0 + ps * 8),
                (__attribute__((address_space(3))) void*)(BsB + (size_t)buf * BN * BK + (size_t)(idx - lane) * 8),
                16, 0, 0);
        }
    };

    stage(0, 0);
    for (int t = 0; t < NT; ++t) {
        asm volatile("s_waitcnt vmcnt(0)" ::: "memory");
        __builtin_amdgcn_s_barrier();
        if (t + 1 < NT) stage((t + 1) & 1, (t + 1) * BK);
        const unsigned short* Ab = AsB + (size_t)(t & 1) * BM * BK;
        const unsigned short* Bb = BsB + (size_t)(t & 1) * BN * BK;

        short8 af[4][2], bfv[2][2];

#define LOAD_A(MQ)                                                          \
        _Pragma("unroll")                                                   \
        for (int mi = 0; mi < 4; ++mi) {                                    \
            _Pragma("unroll")                                               \
            for (int kk = 0; kk < 2; ++kk) {                                \
                const int R = wr * 128 + (MQ) * 64 + mi * 16 + l15;         \
                const int ps = (kk * 4 + l4) ^ (R & 7);                     \
                af[mi][kk] = *reinterpret_cast<const short8*>(              \
                    Ab + ((size_t)R * 8 + ps) * 8);                         \
            }                                                               \
        }
#define LOAD_B(NQ)                                                          \
        _Pragma("unroll")                                                   \
        for (int ni = 0; ni < 2; ++ni) {                                    \
            _Pragma("unroll")                                               \
            for (int kk = 0; kk < 2; ++kk) {                                \
                const int R = wc * 64 + (NQ) * 32 + ni * 16 + l15;          \
                const int ps = (kk * 4 + l4) ^ (R & 7);                     \
                bfv[ni][kk] = *reinterpret_cast<const short8*>(             \
                    Bb + ((size_t)R * 8 + ps) * 8);                         \
            }                                                               \
        }
#define QUAD(MQ, NQ)                                                        \
        __builtin_amdgcn_s_setprio(1);                                      \
        _Pragma("unroll")                                                   \
        for (int mi = 0; mi < 4; ++mi)                                      \
            _Pragma("unroll")                                               \
            for (int ni = 0; ni < 2; ++ni)                                  \
                _Pragma("unroll")                                           \
                for (int kk = 0; kk < 2; ++kk)                              \
                    acc[(MQ) * 4 + mi][(NQ) * 2 + ni] =                     \
                        __builtin_amdgcn_mfma_f32_16x16x32_bf16(            \
                            af[mi][kk], bfv[ni][kk],                        \
                            acc[(MQ) * 4 + mi][(NQ) * 2 + ni], 0, 0, 0);    \
        __builtin_amdgcn_s_setprio(0);

        LOAD_A(0); LOAD_B(0);
        QUAD(0, 0);
        LOAD_B(1);
        QUAD(0, 1);
        LOAD_A(1);
        QUAD(1, 1);
        LOAD_B(0);
        QUAD(1, 0);
#undef LOAD_A
#undef LOAD_B
#undef QUAD
    }

    // C/D layout: col = lane&15, row = (lane>>4)*4 + reg
    #pragma unroll
    for (int mg = 0; mg < 8; ++mg) {
        const int mrow = m0 + wr * 128 + mg * 16 + l4 * 4;
        #pragma unroll
        for (int ng = 0; ng < 4; ++ng) {
            const int ncol = n0 + wc * 64 + ng * 16 + l15;
            #pragma unroll
            for (int r = 0; r < 4; ++r)
                C[(size_t)(mrow + r) * ldc + ncol] = acc[mg][ng][r];
        }
    }
}

// ------------------------- reduce NP split-K partials: dst = sum(parts)
template <int NP>
__global__ void __launch_bounds__(256) reduce_parts(
    const float* __restrict__ parts, size_t stride,
    float* __restrict__ dst, int count) {
    const int i = (blockIdx.x * 256 + threadIdx.x) * 4;
    if (i >= count) return;
    float4 s = *reinterpret_cast<const float4*>(parts + i);
    #pragma unroll
    for (int p = 1; p < NP; ++p) {
        const float4 v = *reinterpret_cast<const float4*>(parts + (size_t)p * stride + i);
        s.x += v.x; s.y += v.y; s.z += v.z; s.w += v.w;
    }
    *reinterpret_cast<float4*>(dst + i) = s;
}

// -------- depthwise causal conv+silu, fused kSplitIn-part split-K reduce
__global__ void __launch_bounds__(256) conv_silu_kernel(
    const float* __restrict__ parts, size_t stride,
    const float* __restrict__ cw, const float* __restrict__ cb,
    float* __restrict__ xi, __hip_bfloat16* __restrict__ xi2) {
    const int s = blockIdx.x;
    const int d = blockIdx.y * 256 + threadIdx.x;
    float acc = cb[d];
    #pragma unroll
    for (int k = 0; k < kDConv; ++k) {
        const int sl = s - (kDConv - 1) + k;
        if (sl >= 0) {
            const size_t off = (size_t)sl * (2 * kDInner) + d;
            float xzv = parts[off];
            #pragma unroll
            for (int p = 1; p < kSplitIn; ++p) xzv += parts[(size_t)p * stride + off];
            acc = fmaf(xzv, cw[d * kDConv + k], acc);
        }
    }
    const float v = silu_f(acc);
    xi[(size_t)s * kDInner + d] = v;
    __hip_bfloat16 hi, lo;
    split_bf16(v, hi, lo);
    __hip_bfloat16* row = xi2 + (size_t)s * 3 * kDInner;
    row[d] = hi; row[kDInner + d] = lo; row[2 * kDInner + d] = hi;
}

// ------------------------------------------------- chunked selective scan
__device__ __forceinline__ void compute_dt_tile(
    const float* __restrict__ proj, const float* __restrict__ dtw,
    const float* __restrict__ dtb, int l0, int d0, int tid,
    float (*sP)[kDtRank], float (*sdtw)[kDtRank + 1], float (*sdt)[16]) {
    for (int idx = tid; idx < kCH * kDtRank; idx += 256) {
        const int r = idx / kDtRank, c = idx % kDtRank;
        sP[r][c] = proj[(size_t)(l0 + r) * kPLd + c];
    }
    for (int idx = tid; idx < 16 * kDtRank; idx += 256) {
        const int dd = idx / kDtRank, c = idx % kDtRank;
        sdtw[dd][c] = dtw[(size_t)(d0 + dd) * kDtRank + c];
    }
    __syncthreads();
    #pragma unroll
    for (int e = 0; e < 4; ++e) {
        const int idx = tid + e * 256;
        const int r = idx >> 4, dd = idx & 15;
        float acc = dtb[d0 + dd];
        #pragma unroll
        for (int k = 0; k < kDtRank; ++k)
            acc = fmaf(sP[r][k], sdtw[dd][k], acc);
        acc = (acc > 20.f) ? acc : log1pf(__expf(acc));  // softplus
        sdt[r][dd] = acc;
    }
}

__global__ void __launch_bounds__(256) scan_part1(
    const float* __restrict__ u, const float* __restrict__ proj,
    const float* __restrict__ A_log, const float* __restrict__ dtw,
    const float* __restrict__ dtb,
    float* __restrict__ P, float* __restrict__ S) {
    __shared__ float sP[kCH][kDtRank];
    __shared__ float sdtw[16][kDtRank + 1];
    __shared__ float sdt[kCH][16], su[kCH][16], sB[kCH][16];
    const int tid = threadIdx.x;
    const int n = tid & 15, dl = tid >> 4;
    const int d0 = blockIdx.x * 16;
    const int l0 = blockIdx.y * kCH;
    for (int idx = tid; idx < kCH * 16; idx += 256) {
        const int r = idx >> 4, c = idx & 15;
        su[r][c] = u[(size_t)(l0 + r) * kDInner + d0 + c];
        sB[r][c] = proj[(size_t)(l0 + r) * kPLd + kDtRank + c];
    }
    compute_dt_tile(proj, dtw, dtb, l0, d0, tid, sP, sdtw, sdt);
    __syncthreads();
    const int d = d0 + dl;
    const float Adn = -__expf(A_log[d * kDState + n]);
    float state = 0.f, sumA = 0.f;
    #pragma unroll 8
    for (int l = 0; l < kCH; ++l) {
        const float dtv = sdt[l][dl];
        const float adelta = __expf(dtv * Adn);
        const float mult = __expf(adelta);
        state = fmaf(state, mult, dtv * su[l][dl] * sB[l][n]);
        sumA += adelta;
    }
    const int dn = d * kDState + n;
    P[(size_t)blockIdx.y * kDN + dn] = __expf(sumA);
    S[(size_t)blockIdx.y * kDN + dn] = state;
}

__global__ void __launch_bounds__(256) scan_part2(
    const float* __restrict__ u, const float* __restrict__ proj,
    const float* __restrict__ A_log, const float* __restrict__ dtw,
    const float* __restrict__ dtb, const float* __restrict__ D_skip,
    const float* __restrict__ P, const float* __restrict__ S,
    const float* __restrict__ resparts, size_t rstride,
    __hip_bfloat16* __restrict__ g2) {
    __shared__ float sP[kCH][kDtRank];
    __shared__ float sdtw[16][kDtRank + 1];
    __shared__ float sdt[kCH][16], su[kCH][16], sB[kCH][16], sC[kCH][16];
    __shared__ float sy[kCH][16];
    const int tid = threadIdx.x;
    const int n = tid & 15, dl = tid >> 4;
    const int d0 = blockIdx.x * 16;
    const int l0 = blockIdx.y * kCH;
    for (int idx = tid; idx < kCH * 16; idx += 256) {
        const int r = idx >> 4, c = idx & 15;
        su[r][c] = u[(size_t)(l0 + r) * kDInner + d0 + c];
        sB[r][c] = proj[(size_t)(l0 + r) * kPLd + kDtRank + c];
        sC[r][c] = proj[(size_t)(l0 + r) * kPLd + kDtRank + kDState + c];
    }
    compute_dt_tile(proj, dtw, dtb, l0, d0, tid, sP, sdtw, sdt);
    const int dn = d0 * kDState + tid;
    float state = 0.f;
    for (int jj = 0; jj < (int)blockIdx.y; ++jj) {
        const size_t idx = (size_t)jj * kDN + dn;
        state = fmaf(state, P[idx], S[idx]);
    }
    __syncthreads();
    const int d = d0 + dl;
    const float Adn = -__expf(A_log[d * kDState + n]);
    const float Dv  = D_skip[d];
    for (int l = 0; l < kCH; ++l) {
        const float dtv = sdt[l][dl];
        const float uv  = su[l][dl];
        const float mult = __expf(__expf(dtv * Adn));
        state = fmaf(state, mult, dtv * uv * sB[l][n]);
        float contrib = state * sC[l][n];
        contrib += __shfl_xor(contrib, 8);
        contrib += __shfl_xor(contrib, 4);
        contrib += __shfl_xor(contrib, 2);
        contrib += __shfl_xor(contrib, 1);
        if (n == 0) sy[l][dl] = fmaf(uv, Dv, contrib);
    }
    __syncthreads();
    for (int idx = tid; idx < kCH * 16; idx += 256) {
        const int r = idx >> 4, c = idx & 15;
        const size_t roff = (size_t)(l0 + r) * (2 * kDInner) + kDInner + d0 + c;
        float res = resparts[roff];
        #pragma unroll
        for (int p = 1; p < kSplitIn; ++p) res += resparts[(size_t)p * rstride + roff];
        const float v = sy[r][c] * silu_f(res);
        __hip_bfloat16 hi, lo;
        split_bf16(v, hi, lo);
        __hip_bfloat16* row = g2 + (size_t)(l0 + r) * 2 * kDInner;
        row[d0 + c] = hi; row[kDInner + d0 + c] = lo;
    }
}

}  // namespace

extern "C" void kernel_launch(void* const* d_in, const int* in_sizes, int n_in,
                              void* d_out, int out_size, void* d_ws, size_t ws_size,
                              hipStream_t stream) {
    const int*   tokens       = (const int*)d_in[0];
    const float* embedding    = (const float*)d_in[1];
    const float* norm_w       = (const float*)d_in[2];
    const float* in_proj_w    = (const float*)d_in[3];
    const float* conv_w       = (const float*)d_in[4];
    const float* conv_b       = (const float*)d_in[5];
    const float* x_proj_w     = (const float*)d_in[6];
    const float* dt_proj_w    = (const float*)d_in[7];
    const float* dt_proj_b    = (const float*)d_in[8];
    const float* A_log        = (const float*)d_in[9];
    const float* D_skip       = (const float*)d_in[10];
    const float* out_proj_w   = (const float*)d_in[11];
    const float* final_norm_w = (const float*)d_in[12];
    float* out = (float*)d_out;

    constexpr int K3m = 3 * kDModel;   // 2304
    constexpr int K3i = 3 * kDInner;   // 4608
    constexpr int K2i = 2 * kDInner;   // 3072

    // allow 128 KB dynamic LDS for the vocab kernel (idempotent)
    (void)hipFuncSetAttribute((const void*)vocab_gemm,
                              hipFuncAttributeMaxDynamicSharedMemorySize, 131072);

    char* ws = (char*)d_ws;
    auto alloc = [&](size_t bytes) { char* p = ws; ws += (bytes + 255) & ~(size_t)255; return p; };
    float* x    = (float*)alloc((size_t)kSeq * kDModel * 4);
    float* xi   = (float*)alloc((size_t)kSeq * kDInner * 4);
    float* proj = (float*)alloc((size_t)kSeq * kPLd * 4);
    float* scanP  = (float*)alloc((size_t)kNCH * kDN * 4);
    float* scanS  = (float*)alloc((size_t)kNCH * kDN * 4);
    float* partsXZ = (float*)alloc((size_t)kSplitIn * kSeq * 2 * kDInner * 4);
    float* partsP  = (float*)alloc((size_t)24 * kSeq * kPLd * 4);
    float* partsO  = (float*)alloc((size_t)kSplitOut * kSeq * kDModel * 4);
    __hip_bfloat16* h_bf   = (__hip_bfloat16*)alloc((size_t)kSeq * kDModel * 2);
    __hip_bfloat16* h2     = (__hip_bfloat16*)alloc((size_t)kSeq * K3m * 2);
    __hip_bfloat16* xi2    = (__hip_bfloat16*)alloc((size_t)kSeq * K3i * 2);
    __hip_bfloat16* g2     = (__hip_bfloat16*)alloc((size_t)kSeq * K2i * 2);
    __hip_bfloat16* emb_bf = (__hip_bfloat16*)alloc((size_t)kVocab * kDModel * 2);
    __hip_bfloat16* inw2   = (__hip_bfloat16*)alloc((size_t)kL * 2 * kDInner * K3m * 2);
    __hip_bfloat16* outw2  = (__hip_bfloat16*)alloc((size_t)kL * kDModel * K2i * 2);
    __hip_bfloat16* xw2    = (__hip_bfloat16*)alloc((size_t)kL * kPB * K3i * 2);

    f2b_kernel<<<4096, 256, 0, stream>>>(embedding, emb_bf, kVocab * kDModel);
    dup2_kernel<<<(kL * kDModel * kDInner / 4 + 255) / 256, 256, 0, stream>>>(
        out_proj_w, outw2, kL * kDModel, kDInner);
    split3_kernel<<<(kL * 2 * kDInner * kDModel / 4 + 255) / 256, 256, 0, stream>>>(
        in_proj_w, kL * 2 * kDInner, kDModel, inw2);
    split3x_kernel<<<(kL * kPB * kDInner / 4 + 255) / 256, 256, 0, stream>>>(
        x_proj_w, xw2);

    embed_rms_kernel<<<kSeq, 256, 0, stream>>>(tokens, embedding, norm_w, x, h2);

    for (int i = 0; i < kL; ++i) {
        mfma_gemm<128, 128, kSplitIn><<<dim3(kSeq / 128, 2 * kDInner / 128, kSplitIn), 256, 0, stream>>>(
            h2, K3m, inw2 + (size_t)i * 2 * kDInner * K3m, K3m,
            partsXZ, 2 * kDInner, 2 * kDInner, K3m, (size_t)kSeq * 2 * kDInner);

        conv_silu_kernel<<<dim3(kSeq, kDInner / 256), 256, 0, stream>>>(
            partsXZ, (size_t)kSeq * 2 * kDInner,
            conv_w + (size_t)i * kDInner * kDConv, conv_b + (size_t)i * kDInner,
            xi, xi2);

        mfma_gemm<128, 128, 24><<<dim3(kSeq / 128, 1, 24), 256, 0, stream>>>(
            xi2, K3i, xw2 + (size_t)i * kPB * K3i, K3i,
            partsP, kPLd, kPLd, K3i, (size_t)kSeq * kPLd);
        reduce_parts<24><<<(kSeq * kPLd / 4 + 255) / 256, 256, 0, stream>>>(
            partsP, (size_t)kSeq * kPLd, proj, kSeq * kPLd);

        const float* A_l  = A_log + (size_t)i * kDInner * kDState;
        const float* dtw  = dt_proj_w + (size_t)i * kDInner * kDtRank;
        const float* dtb  = dt_proj_b + (size_t)i * kDInner;
        scan_part1<<<dim3(kDInner / 16, kNCH), 256, 0, stream>>>(
            xi, proj, A_l, dtw, dtb, scanP, scanS);
        scan_part2<<<dim3(kDInner / 16, kNCH), 256, 0, stream>>>(
            xi, proj, A_l, dtw, dtb, D_skip + (size_t)i * kDInner,
            scanP, scanS, partsXZ, (size_t)kSeq * 2 * kDInner, g2);

        mfma_gemm<128, 128, kSplitOut><<<dim3(kSeq / 128, kDModel / 128, kSplitOut), 256, 0, stream>>>(
            g2, K2i, outw2 + (size_t)i * kDModel * K2i, K2i,
            partsO, kDModel, kDModel, K2i, (size_t)kSeq * kDModel);

        if (i + 1 < kL) {
            reduce_rms_kernel<false><<<kSeq, 256, 0, stream>>>(
                partsO, (size_t)kSeq * kDModel, norm_w + (size_t)(i + 1) * kDModel, x, h2);
        } else {
            reduce_rms_kernel<true><<<kSeq, 256, 0, stream>>>(
                partsO, (size_t)kSeq * kDModel, final_norm_w, x, h_bf);
        }
    }

    // out = h_bf @ embedding^T   (1024 x 32000, K=768) — 256^2 deep pipeline
    vocab_gemm<<<dim3(kSeq / 256, kVocab / 256), 512, 131072, stream>>>(
        h_bf, emb_bf, out);
}